// Round 4
// baseline (1191.874 us; speedup 1.0000x reference)
//
#include <hip/hip_runtime.h>
#include <math.h>

#define BB     4096
#define NN     32
#define EE     64
#define INDIM  74
#define HH     256
#define GCR    5
#define M1     1024
#define M2     512
#define FDIM   258
#define ADDD   2

typedef __attribute__((ext_vector_type(8))) _Float16 half8_t;
typedef __attribute__((ext_vector_type(4))) float float4_t;

#define MF16(a, b, c) __builtin_amdgcn_mfma_f32_16x16x32_f16((a), (b), (c), 0, 0, 0)
#define LO_SCALE 1024.0f
#define LO_INV   (1.0f / 1024.0f)

// ---- ws layout (bytes) ----
#define WS_F      0               // F [4096][258] f32
#define WS_WQK    4227072         // Wqk fp32 [256][256]
#define WS_TVEC   4489216         // tvec fp32 [256]
#define WS_PK     4490240         // packed fp16 hi/lo fragments (same element counts as before)
// packed offsets in _Float16 units from PK base:
#define PK_WIN_HI 0
#define PK_WIN_LO 24576
#define PK_G_BASE 49152
#define PK_G_STRIDE 131072
#define PK_WQK_HI 1359872
#define PK_WQK_LO (1359872 + 65536)

union H4 { unsigned long long u; _Float16 h[4]; };

// ---------------------------------------------------------------------------
// Prep 1: Wqk = Wq @ Wk^T (fp32), tvec = Wk @ bq
// ---------------------------------------------------------------------------
__global__ void prep1_kernel(const float* __restrict__ Wq, const float* __restrict__ Wk,
                             const float* __restrict__ bq,
                             float* __restrict__ wqkf, float* __restrict__ tvec) {
  const int i = blockIdx.x, j = threadIdx.x;
  if (i < 256) {
    __shared__ float qrow[256];
    qrow[j] = Wq[i * 256 + j];
    __syncthreads();
    float s = 0.f;
    for (int c = 0; c < 256; ++c) s = fmaf(qrow[c], Wk[j * 256 + c], s);
    wqkf[i * 256 + j] = s;
  } else {
    float s = 0.f;
    for (int c = 0; c < 256; ++c) s = fmaf(Wk[j * 256 + c], bq[c], s);
    tvec[j] = s;
  }
}

// ---------------------------------------------------------------------------
// Prep 2: pack weights into MFMA B-fragment order, fp16 hi + (lo * 2^10).
// chunk: local = (nt*KS + ks)*64 + lane; elem i:
//   k = ks*32 + (lane>>4)*8 + i ; j = nt*16 + (lane&15) ; src = W[k*256+j]
// ---------------------------------------------------------------------------
template<int KS, int KREAL>
__device__ __forceinline__ void pack_one(const float* __restrict__ S,
                                         _Float16* __restrict__ hi,
                                         _Float16* __restrict__ lo, int local) {
  const int l = local & 63;
  const int nk = local >> 6;
  const int ks = nk % KS;
  const int nt = nk / KS;
  const int j = nt * 16 + (l & 15);
  const int kbase = ks * 32 + (l >> 4) * 8;
  half8_t h8, l8;
  #pragma unroll
  for (int i = 0; i < 8; ++i) {
    const int k = kbase + i;
    const float v = (k < KREAL) ? S[k * 256 + j] : 0.f;
    const _Float16 hb = (_Float16)v;
    h8[i] = hb;
    l8[i] = (_Float16)((v - (float)hb) * LO_SCALE);
  }
  *(half8_t*)(hi + (size_t)local * 8) = h8;
  *(half8_t*)(lo + (size_t)local * 8) = l8;
}

__global__ void prep2_kernel(const float* __restrict__ W_in,
                             const float* __restrict__ W_g1, const float* __restrict__ W_g2,
                             const float* __restrict__ wqkf, _Float16* __restrict__ pk) {
  const int cid = blockIdx.x * 256 + threadIdx.x;
  if (cid < 3072) {
    pack_one<3, 74>(W_in, pk + PK_WIN_HI, pk + PK_WIN_LO, cid);
  } else {
    const int m = (cid - 3072) >> 13;               // 0..10
    const int local = (cid - 3072) & 8191;
    _Float16* hi; const float* S;
    if (m < 10) {
      hi = pk + PK_G_BASE + (size_t)m * PK_G_STRIDE;
      S = (m < 5) ? (W_g1 + (size_t)m * 65536) : (W_g2 + (size_t)(m - 5) * 65536);
    } else {
      hi = pk + PK_WQK_HI;
      S = wqkf;
    }
    pack_one<8, 256>(S, hi, hi + 65536, local);
  }
}

// ---------------------------------------------------------------------------
// conv for 2 graphs: T = h@W (W hi/lo, 2 products), h'^T = T^T @ Nmat^T
// (swapped -> b64 row-major writes). T is wave-private (no barriers).
// Hs layout: elem idx = n*256 + (j ^ ((n&7)<<3))  (XOR swizzle, fp16)
// Tb layout: B-frag-linear per phase: jtl*512 + ((m>>3)*16 + jc)*8 + (m&7)
// ---------------------------------------------------------------------------
template<int KS, bool RELU>
__device__ __forceinline__ void conv2(
    _Float16* __restrict__ Hs0, _Float16* __restrict__ Hs1,
    _Float16* __restrict__ Tb0, _Float16* __restrict__ Tb1,
    const _Float16* __restrict__ Whi, const _Float16* __restrict__ Wlo,
    const float* __restrict__ bias,
    const half8_t nmh[2][2], const half8_t nml[2][2],
    int lane, int wv)
{
  const int g4 = lane >> 4, l15 = lane & 15;
  const int sw = (l15 & 7) << 3;
  _Float16* const HsA[2] = {Hs0, Hs1};
  _Float16* const TbA[2] = {Tb0, Tb1};

  float4 b4[2][2];
  #pragma unroll
  for (int p = 0; p < 2; ++p)
    #pragma unroll
    for (int ntl = 0; ntl < 2; ++ntl)
      b4[p][ntl] = *(const float4*)&bias[(p * 8 + wv * 2 + ntl) * 16 + 4 * g4];

  unsigned long long holdu[2][2][2][2];   // [p][gi][ntl][nt2] packed 4x f16

  #pragma unroll
  for (int p = 0; p < 2; ++p) {
    float4_t th[2][2][2], tl[2][2][2];    // [gi][mt][ntl]
    #pragma unroll
    for (int a = 0; a < 2; ++a)
      #pragma unroll
      for (int b = 0; b < 2; ++b)
        #pragma unroll
        for (int c = 0; c < 2; ++c) {
          th[a][b][c] = (float4_t){0.f, 0.f, 0.f, 0.f};
          tl[a][b][c] = (float4_t){0.f, 0.f, 0.f, 0.f};
        }

    for (int ks = 0; ks < KS; ++ks) {
      half8_t wh[2], wl[2];
      #pragma unroll
      for (int ntl = 0; ntl < 2; ++ntl) {
        const int off = (((p * 8 + wv * 2 + ntl) * KS + ks) * 64 + lane) * 8;
        wh[ntl] = *(const half8_t*)(Whi + off);
        wl[ntl] = *(const half8_t*)(Wlo + off);
      }
      const int j0 = ks * 32 + g4 * 8;
      #pragma unroll
      for (int gi = 0; gi < 2; ++gi)
        #pragma unroll
        for (int mt = 0; mt < 2; ++mt) {
          const half8_t ha = *(const half8_t*)(HsA[gi] + ((mt * 16 + l15) * 256 + (j0 ^ sw)));
          #pragma unroll
          for (int ntl = 0; ntl < 2; ++ntl) {
            th[gi][mt][ntl] = MF16(ha, wh[ntl], th[gi][mt][ntl]);
            tl[gi][mt][ntl] = MF16(ha, wl[ntl], tl[gi][mt][ntl]);
          }
        }
    }

    // T write (combine hi + lo/2^10), b64 stores, wave-private tiles
    #pragma unroll
    for (int gi = 0; gi < 2; ++gi)
      #pragma unroll
      for (int mt = 0; mt < 2; ++mt) {
        const int r0 = mt * 16 + 4 * g4;
        #pragma unroll
        for (int ntl = 0; ntl < 2; ++ntl) {
          H4 pk4;
          #pragma unroll
          for (int jj = 0; jj < 4; ++jj)
            pk4.h[jj] = (_Float16)(th[gi][mt][ntl][jj] + tl[gi][mt][ntl][jj] * LO_INV);
          const int idx = (wv * 2 + ntl) * 512 + ((r0 >> 3) * 16 + l15) * 8 + (r0 & 7);
          *(unsigned long long*)(TbA[gi] + idx) = pk4.u;
        }
      }

    // MFMA2 (swapped): h'^T = T^T @ Nmat^T ; same-wave T read (in-order LDS)
    #pragma unroll
    for (int gi = 0; gi < 2; ++gi)
      #pragma unroll
      for (int ntl = 0; ntl < 2; ++ntl) {
        const half8_t ta = *(const half8_t*)(TbA[gi] + (wv * 2 + ntl) * 512 + lane * 8);
        #pragma unroll
        for (int nt2 = 0; nt2 < 2; ++nt2) {
          float4_t dh = MF16(ta, nmh[gi][nt2], ((float4_t){0.f, 0.f, 0.f, 0.f}));
          float4_t dl = MF16(ta, nml[gi][nt2], ((float4_t){0.f, 0.f, 0.f, 0.f}));
          H4 pk4;
          #pragma unroll
          for (int jj = 0; jj < 4; ++jj) {
            float v = dh[jj] + dl[jj] * LO_INV + ((const float*)&b4[p][ntl])[jj];
            if (RELU) v = fmaxf(v, 0.f);
            pk4.h[jj] = (_Float16)v;
          }
          holdu[p][gi][ntl][nt2] = pk4.u;
        }
      }
  }

  __syncthreads();   // all waves' Hs reads (both phases) complete

  #pragma unroll
  for (int p = 0; p < 2; ++p)
    #pragma unroll
    for (int gi = 0; gi < 2; ++gi)
      #pragma unroll
      for (int ntl = 0; ntl < 2; ++ntl) {
        const int j0 = (p * 8 + wv * 2 + ntl) * 16 + 4 * g4;
        #pragma unroll
        for (int nt2 = 0; nt2 < 2; ++nt2) {
          const int n = nt2 * 16 + l15;
          *(unsigned long long*)(HsA[gi] + (n * 256 + (j0 ^ ((n & 7) << 3)))) =
              holdu[p][gi][ntl][nt2];
        }
      }
  __syncthreads();   // new h visible
}

// ---------------------------------------------------------------------------
// GNN kernel: 2 graphs per block.
// LDS: Hs[2][8192] f16 (32KB) + Tb[2][4096] f16 (16KB) + Sb[2][1200] f32 (9.4KB)
// Sb per graph: [0..1056) Nf->S ; inorm@1056 onorm@1088 ; v@1120 ; w@1152
// ---------------------------------------------------------------------------
__global__ __launch_bounds__(256, 2)
void gnn_kernel(const float* __restrict__ x, const float* __restrict__ addf,
                const int* __restrict__ src, const int* __restrict__ dst,
                const float* __restrict__ b_in,
                const float* __restrict__ b_g1, const float* __restrict__ b_g2,
                const float* __restrict__ Wvp, const float* __restrict__ bv,
                const _Float16* __restrict__ pk,
                const float* __restrict__ tvec,
                float* __restrict__ F)
{
  __shared__ __align__(16) _Float16 Hs0[8192];
  __shared__ __align__(16) _Float16 Hs1[8192];
  __shared__ __align__(16) _Float16 Tb0[4096];
  __shared__ __align__(16) _Float16 Tb1[4096];
  __shared__ float Sb0[1200];
  __shared__ float Sb1[1200];

  const int tid = threadIdx.x;
  const int lane = tid & 63;
  const int wv = tid >> 6;
  const int g4 = lane >> 4, l15 = lane & 15;
  const int sw = (l15 & 7) << 3;
  const int ga = blockIdx.x * 2;

  // ---- build Nmat = diag(inorm) . A_adj . diag(onorm) for both graphs ----
  for (int i = tid; i < 2048; i += 256) (i < 1024 ? Sb0 : Sb1)[i & 1023] = 0.f;
  __syncthreads();
  if (tid < 128) {
    const int gi = tid >> 6, e = tid & 63;
    const int es = src[(size_t)(ga + gi) * EE + e];
    const int ed = dst[(size_t)(ga + gi) * EE + e];
    atomicAdd((gi ? Sb1 : Sb0) + ed * 32 + es, 1.0f);
  }
  __syncthreads();
  if (tid < 64) {                       // inorm = rsqrt(row sums)
    const int gi = tid >> 5, n = tid & 31;
    float* Sp = gi ? Sb1 : Sb0;
    float s = 0.f;
    for (int m = 0; m < NN; ++m) s += Sp[n * 32 + m];
    Sp[1056 + n] = 1.f / sqrtf(fmaxf(s, 1.f));
  } else if (tid < 128) {               // onorm = rsqrt(col sums)
    const int gi = (tid - 64) >> 5, n = tid & 31;
    float* Sp = gi ? Sb1 : Sb0;
    float s = 0.f;
    for (int m = 0; m < NN; ++m) s += Sp[m * 32 + n];
    Sp[1088 + n] = 1.f / sqrtf(fmaxf(s, 1.f));
  }
  __syncthreads();
  for (int i = tid; i < 2048; i += 256) {
    float* Sp = (i < 1024) ? Sb0 : Sb1;
    const int idx = i & 1023;
    Sp[idx] *= Sp[1056 + (idx >> 5)] * Sp[1088 + (idx & 31)];
  }
  __syncthreads();

  // Nmat fragments in registers (B'-frag of Nmat^T == Nmat[n][m] lane map)
  half8_t nmh[2][2], nml[2][2];
  #pragma unroll
  for (int gi = 0; gi < 2; ++gi) {
    const float* Sp = gi ? Sb1 : Sb0;
    #pragma unroll
    for (int nt2 = 0; nt2 < 2; ++nt2) {
      #pragma unroll
      for (int i = 0; i < 8; ++i) {
        const float v = Sp[(nt2 * 16 + l15) * 32 + g4 * 8 + i];
        const _Float16 hb = (_Float16)v;
        nmh[gi][nt2][i] = hb;
        nml[gi][nt2][i] = (_Float16)((v - (float)hb) * LO_SCALE);
      }
    }
  }

  // ---- stage x (fp16, cols 74..95 zero) ----
  for (int i = tid; i < 2 * NN * 96; i += 256) {
    const int gi = i / 3072, rem = i - gi * 3072;
    const int r = rem / 96, c = rem - r * 96;
    const float vx = (c < INDIM) ? x[(size_t)(ga + gi) * (NN * INDIM) + r * INDIM + c] : 0.f;
    (gi ? Hs1 : Hs0)[r * 256 + (c ^ ((r & 7) << 3))] = (_Float16)vx;
  }
  __syncthreads();

  // ---- 11 graph convolutions ----
  conv2<3, false>(Hs0, Hs1, Tb0, Tb1, pk + PK_WIN_HI, pk + PK_WIN_LO, b_in,
                  nmh, nml, lane, wv);
  #pragma unroll 1
  for (int L = 0; L < GCR; ++L) {
    const _Float16* h1 = pk + PK_G_BASE + (size_t)L * PK_G_STRIDE;
    conv2<8, true>(Hs0, Hs1, Tb0, Tb1, h1, h1 + 65536, b_g1 + L * HH, nmh, nml, lane, wv);
    const _Float16* h2 = pk + PK_G_BASE + (size_t)(5 + L) * PK_G_STRIDE;
    conv2<8, true>(Hs0, Hs1, Tb0, Tb1, h2, h2 + 65536, b_g2 + L * HH, nmh, nml, lane, wv);
  }

  // ---- attention: u'^T = Wqk^T @ h^T (+tvec) per 128-col phase; S += u'@h^T ----
  {
    const _Float16* Qhi = pk + PK_WQK_HI;
    const _Float16* Qlo = pk + PK_WQK_LO;
    _Float16* const HsA[2] = {Hs0, Hs1};
    _Float16* const TbA[2] = {Tb0, Tb1};
    const int smt = wv >> 1, snt = wv & 1;
    float4_t sacc[2];
    sacc[0] = (float4_t){0.f, 0.f, 0.f, 0.f};
    sacc[1] = (float4_t){0.f, 0.f, 0.f, 0.f};

    #pragma unroll
    for (int p = 0; p < 2; ++p) {
      float4_t uh[2][2][2], ul[2][2][2];   // [gi][ntl][nt2]
      #pragma unroll
      for (int a = 0; a < 2; ++a)
        #pragma unroll
        for (int b = 0; b < 2; ++b)
          #pragma unroll
          for (int c = 0; c < 2; ++c) {
            uh[a][b][c] = (float4_t){0.f, 0.f, 0.f, 0.f};
            ul[a][b][c] = (float4_t){0.f, 0.f, 0.f, 0.f};
          }
      for (int ks = 0; ks < 8; ++ks) {
        half8_t qh[2], ql[2];
        #pragma unroll
        for (int ntl = 0; ntl < 2; ++ntl) {
          const int off = (((p * 8 + wv * 2 + ntl) * 8 + ks) * 64 + lane) * 8;
          qh[ntl] = *(const half8_t*)(Qhi + off);
          ql[ntl] = *(const half8_t*)(Qlo + off);
        }
        const int c0 = ks * 32 + g4 * 8;
        #pragma unroll
        for (int gi = 0; gi < 2; ++gi)
          #pragma unroll
          for (int nt2 = 0; nt2 < 2; ++nt2) {
            const half8_t hb = *(const half8_t*)(HsA[gi] + ((nt2 * 16 + l15) * 256 + (c0 ^ sw)));
            #pragma unroll
            for (int ntl = 0; ntl < 2; ++ntl) {
              uh[gi][ntl][nt2] = MF16(qh[ntl], hb, uh[gi][ntl][nt2]);
              ul[gi][ntl][nt2] = MF16(ql[ntl], hb, ul[gi][ntl][nt2]);
            }
          }
      }
      // write u' slice (row-major [n][128], swizzled), +tvec
      #pragma unroll
      for (int gi = 0; gi < 2; ++gi)
        #pragma unroll
        for (int ntl = 0; ntl < 2; ++ntl) {
          const int dl0 = (wv * 2 + ntl) * 16 + 4 * g4;
          const float4 tv4 = *(const float4*)&tvec[p * 128 + dl0];
          #pragma unroll
          for (int nt2 = 0; nt2 < 2; ++nt2) {
            const int n = nt2 * 16 + l15;
            H4 pk4;
            #pragma unroll
            for (int jj = 0; jj < 4; ++jj)
              pk4.h[jj] = (_Float16)(uh[gi][ntl][nt2][jj] + ul[gi][ntl][nt2][jj] * LO_INV +
                                     ((const float*)&tv4)[jj]);
            *(unsigned long long*)(TbA[gi] + (n * 128 + (dl0 ^ ((n & 7) << 3)))) = pk4.u;
          }
        }
      __syncthreads();
      // S partial over this phase's 128 d-columns
      #pragma unroll
      for (int gi = 0; gi < 2; ++gi)
        #pragma unroll
        for (int ksl = 0; ksl < 4; ++ksl) {
          const int d0 = ksl * 32 + g4 * 8;
          const half8_t ua = *(const half8_t*)(TbA[gi] + ((smt * 16 + l15) * 128 + (d0 ^ sw)));
          const half8_t hb = *(const half8_t*)(HsA[gi] + ((snt * 16 + l15) * 256 + (((p * 128) + d0) ^ sw)));
          sacc[gi] = MF16(ua, hb, sacc[gi]);
        }
      __syncthreads();
    }
    // write S
    #pragma unroll
    for (int gi = 0; gi < 2; ++gi) {
      float* Sp = gi ? Sb1 : Sb0;
      #pragma unroll
      for (int jj = 0; jj < 4; ++jj)
        Sp[(smt * 16 + 4 * g4 + jj) * 33 + snt * 16 + l15] = sacc[gi][jj];
    }
  }

  // ---- v[m] = h[m].Wv + bv  (2 graphs x 32 rows x 4 lanes) ----
  {
    const int gi = tid >> 7, m = (tid >> 2) & 31, q = tid & 3;
    const _Float16* Hp = gi ? Hs1 : Hs0;
    float s = 0.f;
    const int c0 = q * 64;
    for (int cc = 0; cc < 64; ++cc) {
      const int c = c0 + cc;
      s = fmaf((float)Hp[m * 256 + (c ^ ((m & 7) << 3))], Wvp[c], s);
    }
    s += __shfl_xor(s, 1);
    s += __shfl_xor(s, 2);
    if (q == 0) (gi ? Sb1 : Sb0)[1120 + m] = s + bv[0];
  }
  __syncthreads();

  // ---- row softmax fused with w = attn @ v ----
  if (tid < 64) {
    const int gi = tid >> 5, n = tid & 31;
    float* Sp = gi ? Sb1 : Sb0;
    float mx = -1e30f;
    #pragma unroll 1
    for (int m = 0; m < NN; ++m) mx = fmaxf(mx, Sp[n * 33 + m]);
    float se = 0.f, sv = 0.f;
    #pragma unroll 1
    for (int m = 0; m < NN; ++m) {
      const float e = expf(Sp[n * 33 + m] - mx);
      se += e;
      sv = fmaf(e, Sp[1120 + m], sv);
    }
    Sp[1152 + n] = sv / se;
  }
  __syncthreads();

  // ---- feats = h^T @ w ----
  {
    const int gi = tid >> 7, j = tid & 127;
    const _Float16* Hp = gi ? Hs1 : Hs0;
    const float* Sp = gi ? Sb1 : Sb0;
    float f0 = 0.f, f1 = 0.f;
    #pragma unroll
    for (int m = 0; m < NN; ++m) {
      const float w = Sp[1152 + m];
      const int swm = (m & 7) << 3;
      f0 = fmaf((float)Hp[m * 256 + (j ^ swm)], w, f0);
      f1 = fmaf((float)Hp[m * 256 + ((j + 128) ^ swm)], w, f1);
    }
    F[(size_t)(ga + gi) * FDIM + j] = f0;
    F[(size_t)(ga + gi) * FDIM + j + 128] = f1;
    if (tid < 4) {
      const int gg = tid >> 1;
      F[(size_t)(ga + gg) * FDIM + HH + (tid & 1)] = addf[(size_t)(ga + gg) * ADDD + (tid & 1)];
    }
  }
}

// ---------------------------------------------------------------------------
// Kernel 2: batched MLP (unchanged)
// ---------------------------------------------------------------------------
#define MR 8
__global__ __launch_bounds__(256, 2)
void mlp_kernel(const float* __restrict__ F,
                const float* __restrict__ W1, const float* __restrict__ b1,
                const float* __restrict__ W2, const float* __restrict__ b2,
                const float* __restrict__ W3, const float* __restrict__ b3,
                float* __restrict__ out)
{
  __shared__ float sm[MR * M1];
  const int tid = threadIdx.x;
  const int r0 = blockIdx.x * MR;

  for (int idx = tid; idx < MR * FDIM; idx += 256) {
    const int r = idx / FDIM, c = idx - r * FDIM;
    sm[r * 260 + c] = F[(size_t)(r0 + r) * FDIM + c];
  }
  __syncthreads();

  float a1[4][MR];
  #pragma unroll
  for (int qg = 0; qg < 4; ++qg)
    #pragma unroll
    for (int r = 0; r < MR; ++r) a1[qg][r] = 0.f;
  for (int i = 0; i < FDIM; ++i) {
    float w[4];
    #pragma unroll
    for (int qg = 0; qg < 4; ++qg) w[qg] = W1[(size_t)i * M1 + tid + 256 * qg];
    #pragma unroll
    for (int r = 0; r < MR; ++r) {
      const float fv = sm[r * 260 + i];
      #pragma unroll
      for (int qg = 0; qg < 4; ++qg) a1[qg][r] = fmaf(fv, w[qg], a1[qg][r]);
    }
  }
  __syncthreads();
  #pragma unroll
  for (int qg = 0; qg < 4; ++qg) {
    const float bb = b1[tid + 256 * qg];
    #pragma unroll
    for (int r = 0; r < MR; ++r) {
      const float z = a1[qg][r] + bb;
      sm[r * M1 + tid + 256 * qg] = fmaxf(z, 0.01f * z);
    }
  }
  __syncthreads();

  float a2[2][MR];
  #pragma unroll
  for (int qg = 0; qg < 2; ++qg)
    #pragma unroll
    for (int r = 0; r < MR; ++r) a2[qg][r] = 0.f;
  for (int i = 0; i < M1; ++i) {
    float w[2];
    #pragma unroll
    for (int qg = 0; qg < 2; ++qg) w[qg] = W2[(size_t)i * M2 + tid + 256 * qg];
    #pragma unroll
    for (int r = 0; r < MR; ++r) {
      const float zv = sm[r * M1 + i];
      #pragma unroll
      for (int qg = 0; qg < 2; ++qg) a2[qg][r] = fmaf(zv, w[qg], a2[qg][r]);
    }
  }
  __syncthreads();
  #pragma unroll
  for (int qg = 0; qg < 2; ++qg) {
    const float bb = b2[tid + 256 * qg];
    #pragma unroll
    for (int r = 0; r < MR; ++r) {
      const float z = a2[qg][r] + bb;
      sm[r * M2 + tid + 256 * qg] = fmaxf(z, 0.01f * z);
    }
  }
  __syncthreads();

  const int lane = tid & 63, wid = tid >> 6;
  float wreg[8];
  #pragma unroll
  for (int q = 0; q < 8; ++q) wreg[q] = W3[lane + 64 * q];
  #pragma unroll
  for (int rr = 0; rr < 2; ++rr) {
    const int r = wid * 2 + rr;
    float s = 0.f;
    #pragma unroll
    for (int q = 0; q < 8; ++q) s = fmaf(sm[r * M2 + lane + 64 * q], wreg[q], s);
    #pragma unroll
    for (int off = 32; off; off >>= 1) s += __shfl_down(s, off);
    if (lane == 0) out[r0 + r] = s + b3[0];
  }
}

// ---------------------------------------------------------------------------
extern "C" void kernel_launch(void* const* d_in, const int* in_sizes, int n_in,
                              void* d_out, int out_size, void* d_ws, size_t ws_size,
                              hipStream_t stream) {
  (void)in_sizes; (void)n_in; (void)out_size; (void)ws_size;
  const float* x    = (const float*)d_in[0];
  const float* addf = (const float*)d_in[1];
  const int*   src  = (const int*)d_in[2];
  const int*   dst  = (const int*)d_in[3];
  const float* W_in = (const float*)d_in[4];
  const float* b_in = (const float*)d_in[5];
  const float* W_g1 = (const float*)d_in[6];
  const float* b_g1 = (const float*)d_in[7];
  const float* W_g2 = (const float*)d_in[8];
  const float* b_g2 = (const float*)d_in[9];
  const float* Wq   = (const float*)d_in[10];
  const float* bq   = (const float*)d_in[11];
  const float* Wk   = (const float*)d_in[12];
  // d_in[13] = bk : cancels in softmax (row-constant), unused
  const float* Wv   = (const float*)d_in[14];
  const float* bv   = (const float*)d_in[15];
  const float* W1   = (const float*)d_in[16];
  const float* b1   = (const float*)d_in[17];
  const float* W2   = (const float*)d_in[18];
  const float* b2   = (const float*)d_in[19];
  const float* W3   = (const float*)d_in[20];
  const float* b3   = (const float*)d_in[21];
  float* out = (float*)d_out;

  float* F        = (float*)d_ws;
  float* wqkf     = (float*)((char*)d_ws + WS_WQK);
  float* tvec     = (float*)((char*)d_ws + WS_TVEC);
  _Float16* pk    = (_Float16*)((char*)d_ws + WS_PK);

  prep1_kernel<<<dim3(257), dim3(256), 0, stream>>>(Wq, Wk, bq, wqkf, tvec);
  prep2_kernel<<<dim3(364), dim3(256), 0, stream>>>(W_in, W_g1, W_g2, wqkf, pk);
  gnn_kernel<<<dim3(BB / 2), dim3(256), 0, stream>>>(
      x, addf, src, dst, b_in, b_g1, b_g2, Wv, bv, pk, tvec, F);
  mlp_kernel<<<dim3(BB / MR), dim3(256), 0, stream>>>(
      F, W1, b1, W2, b2, W3, b3, out);
}

// Round 7
// 842.076 us; speedup vs baseline: 1.4154x; 1.4154x over previous
//
#include <hip/hip_runtime.h>
#include <math.h>

#define BB     4096
#define NN     32
#define EE     64
#define INDIM  74
#define HH     256
#define GCR    5
#define M1     1024
#define M2     512
#define FDIM   258
#define ADDD   2

typedef __attribute__((ext_vector_type(8))) _Float16 half8_t;
typedef __attribute__((ext_vector_type(4))) float float4_t;

#define MF16(a, b, c) __builtin_amdgcn_mfma_f32_16x16x32_f16((a), (b), (c), 0, 0, 0)
#define LO_SCALE 1024.0f
#define LO_INV   (1.0f / 1024.0f)

// ---- ws layout (bytes) ----
#define WS_F      0               // F [4096][258] f32
#define WS_WQK    4227072         // Wqk fp32 [256][256]
#define WS_TVEC   4489216         // tvec fp32 [256]
#define WS_PK     4490240         // packed fp16 hi/lo fragments
// packed offsets in _Float16 units from PK base:
#define PK_WIN_HI 0
#define PK_WIN_LO 24576
#define PK_G_BASE 49152
#define PK_G_STRIDE 131072
#define PK_WQK_HI 1359872
#define PK_WQK_LO (1359872 + 65536)

union H4 { unsigned long long u; _Float16 h[4]; };

// ---------------------------------------------------------------------------
// Prep 1: Wqk = Wq @ Wk^T (fp32), tvec = Wk @ bq
// ---------------------------------------------------------------------------
__global__ void prep1_kernel(const float* __restrict__ Wq, const float* __restrict__ Wk,
                             const float* __restrict__ bq,
                             float* __restrict__ wqkf, float* __restrict__ tvec) {
  const int i = blockIdx.x, j = threadIdx.x;
  if (i < 256) {
    __shared__ float qrow[256];
    qrow[j] = Wq[i * 256 + j];
    __syncthreads();
    float s = 0.f;
    for (int c = 0; c < 256; ++c) s = fmaf(qrow[c], Wk[j * 256 + c], s);
    wqkf[i * 256 + j] = s;
  } else {
    float s = 0.f;
    for (int c = 0; c < 256; ++c) s = fmaf(Wk[j * 256 + c], bq[c], s);
    tvec[j] = s;
  }
}

// ---------------------------------------------------------------------------
// Prep 2: pack weights into MFMA B-fragment order, fp16 hi + (lo * 2^10).
// chunk: local = (nt*KS + ks)*64 + lane; elem i:
//   k = ks*32 + (lane>>4)*8 + i ; j = nt*16 + (lane&15) ; src = W[k*256+j]
// ---------------------------------------------------------------------------
template<int KS, int KREAL>
__device__ __forceinline__ void pack_one(const float* __restrict__ S,
                                         _Float16* __restrict__ hi,
                                         _Float16* __restrict__ lo, int local) {
  const int l = local & 63;
  const int nk = local >> 6;
  const int ks = nk % KS;
  const int nt = nk / KS;
  const int j = nt * 16 + (l & 15);
  const int kbase = ks * 32 + (l >> 4) * 8;
  half8_t h8, l8;
  #pragma unroll
  for (int i = 0; i < 8; ++i) {
    const int k = kbase + i;
    const float v = (k < KREAL) ? S[k * 256 + j] : 0.f;
    const _Float16 hb = (_Float16)v;
    h8[i] = hb;
    l8[i] = (_Float16)((v - (float)hb) * LO_SCALE);
  }
  *(half8_t*)(hi + (size_t)local * 8) = h8;
  *(half8_t*)(lo + (size_t)local * 8) = l8;
}

__global__ void prep2_kernel(const float* __restrict__ W_in,
                             const float* __restrict__ W_g1, const float* __restrict__ W_g2,
                             const float* __restrict__ wqkf, _Float16* __restrict__ pk) {
  const int cid = blockIdx.x * 256 + threadIdx.x;
  if (cid < 3072) {
    pack_one<3, 74>(W_in, pk + PK_WIN_HI, pk + PK_WIN_LO, cid);
  } else {
    const int m = (cid - 3072) >> 13;               // 0..10
    const int local = (cid - 3072) & 8191;
    _Float16* hi; const float* S;
    if (m < 10) {
      hi = pk + PK_G_BASE + (size_t)m * PK_G_STRIDE;
      S = (m < 5) ? (W_g1 + (size_t)m * 65536) : (W_g2 + (size_t)(m - 5) * 65536);
    } else {
      hi = pk + PK_WQK_HI;
      S = wqkf;
    }
    pack_one<8, 256>(S, hi, hi + 65536, local);
  }
}

// ---------------------------------------------------------------------------
// conv for 2 graphs, 8 waves (512 threads). Wave owns ONE nt (16 cols)/phase:
//   MFMA1: T = h@W   (acc th/tl[gi][mt] = 32 VGPR; W frags shared across gi)
//   MFMA2: h'^T = T^T @ Nmat^T (T wave-private; Nmat B-frags from NmF LDS)
// 2 barriers per conv (around the in-place H overwrite).
// Hs layout: n*256 + (j ^ ((n&7)<<3)). T layout: wv*512 + ((k>>3)*16+c)*8 + (k&7)
// ---------------------------------------------------------------------------
template<int KS, bool RELU>
__device__ __forceinline__ void conv2x(
    _Float16* Hs, _Float16* Tb, const _Float16* NmF,
    const _Float16* __restrict__ Whi, const _Float16* __restrict__ Wlo,
    const float* __restrict__ bias,
    int lane, int wv)
{
  const int g4 = lane >> 4, l15 = lane & 15;
  const int sw = (l15 & 7) << 3;

  unsigned long long hold[2][2][2];   // [p][gi][nt2] packed 4x f16

  #pragma unroll
  for (int p = 0; p < 2; ++p) {
    const int nt = p * 8 + wv;        // 8 waves x 2 phases = all 16 col-tiles

    // ---- MFMA1: T(:, nt*16..+15) = h @ W ----
    float4_t th[2][2], tl[2][2];
    #pragma unroll
    for (int a = 0; a < 2; ++a)
      #pragma unroll
      for (int b = 0; b < 2; ++b) {
        th[a][b] = (float4_t){0.f, 0.f, 0.f, 0.f};
        tl[a][b] = (float4_t){0.f, 0.f, 0.f, 0.f};
      }

    #pragma unroll
    for (int ks = 0; ks < KS; ++ks) {
      const int off = ((nt * KS + ks) * 64 + lane) * 8;
      const half8_t wh = *(const half8_t*)(Whi + off);
      const half8_t wl = *(const half8_t*)(Wlo + off);
      const int j0 = ks * 32 + g4 * 8;
      #pragma unroll
      for (int gi = 0; gi < 2; ++gi)
        #pragma unroll
        for (int mt = 0; mt < 2; ++mt) {
          const half8_t ha = *(const half8_t*)(Hs + (gi << 13) + ((mt * 16 + l15) * 256 + (j0 ^ sw)));
          th[gi][mt] = MF16(ha, wh, th[gi][mt]);
          tl[gi][mt] = MF16(ha, wl, tl[gi][mt]);
        }
    }

    // ---- T store (combine hi + lo*2^-10), wave-private region ----
    #pragma unroll
    for (int gi = 0; gi < 2; ++gi)
      #pragma unroll
      for (int mt = 0; mt < 2; ++mt) {
        const int r0 = mt * 16 + 4 * g4;
        H4 pk4;
        #pragma unroll
        for (int jj = 0; jj < 4; ++jj)
          pk4.h[jj] = (_Float16)(th[gi][mt][jj] + tl[gi][mt][jj] * LO_INV);
        const int idx = wv * 512 + ((r0 >> 3) * 16 + l15) * 8 + (r0 & 7);
        *(unsigned long long*)(Tb + (gi << 12) + idx) = pk4.u;
      }

    // ---- MFMA2: h'^T = T^T @ Nmat^T (B-frags from NmF LDS) ----
    const float4 b4 = *(const float4*)&bias[nt * 16 + 4 * g4];
    #pragma unroll
    for (int gi = 0; gi < 2; ++gi) {
      const half8_t ta = *(const half8_t*)(Tb + (gi << 12) + wv * 512 + lane * 8);
      #pragma unroll
      for (int nt2 = 0; nt2 < 2; ++nt2) {
        const int nmo = ((gi * 2 + nt2) * 64 + lane) * 8;
        const half8_t nmh = *(const half8_t*)(NmF + nmo);
        const half8_t nml = *(const half8_t*)(NmF + 2048 + nmo);
        const float4_t dh = MF16(ta, nmh, ((float4_t){0.f, 0.f, 0.f, 0.f}));
        const float4_t dl = MF16(ta, nml, ((float4_t){0.f, 0.f, 0.f, 0.f}));
        H4 pk4;
        #pragma unroll
        for (int jj = 0; jj < 4; ++jj) {
          float v = dh[jj] + dl[jj] * LO_INV + ((const float*)&b4)[jj];
          if (RELU) v = fmaxf(v, 0.f);
          pk4.h[jj] = (_Float16)v;
        }
        hold[p][gi][nt2] = pk4.u;
      }
    }
  }

  __syncthreads();   // all waves' Hs reads (both phases) complete

  #pragma unroll
  for (int p = 0; p < 2; ++p) {
    const int j0 = (p * 8 + wv) * 16 + 4 * g4;
    #pragma unroll
    for (int gi = 0; gi < 2; ++gi)
      #pragma unroll
      for (int nt2 = 0; nt2 < 2; ++nt2) {
        const int n = nt2 * 16 + l15;
        *(unsigned long long*)(Hs + (gi << 13) + (n * 256 + (j0 ^ ((n & 7) << 3)))) =
            hold[p][gi][nt2];
      }
  }
  __syncthreads();   // new h visible
}

// ---------------------------------------------------------------------------
// GNN kernel: 2 graphs per block, 512 threads (8 waves).
// LDS: Hs 32KB + Tb 16KB + NmF 8KB + Sb 2x4.6KB = 66.8 KB -> 2 blocks/CU.
// Sb per graph: [0..1056) Nf(setup)->S ; inorm@1056 onorm@1088 ; v@1120 ; w@1152
// ---------------------------------------------------------------------------
__global__ __launch_bounds__(512, 4)
void gnn_kernel(const float* __restrict__ x, const float* __restrict__ addf,
                const int* __restrict__ src, const int* __restrict__ dst,
                const float* __restrict__ b_in,
                const float* __restrict__ b_g1, const float* __restrict__ b_g2,
                const float* __restrict__ Wvp, const float* __restrict__ bv,
                const _Float16* __restrict__ pk,
                const float* __restrict__ tvec,
                float* __restrict__ F)
{
  __shared__ __align__(16) _Float16 Hs[2][8192];
  __shared__ __align__(16) _Float16 Tb[2][4096];
  __shared__ __align__(16) _Float16 NmF[4096];
  __shared__ float Sb[2][1184];

  const int tid = threadIdx.x;
  const int lane = tid & 63;
  const int wv = tid >> 6;            // 0..7
  const int g4 = lane >> 4, l15 = lane & 15;
  const int sw = (l15 & 7) << 3;
  const int ga = blockIdx.x * 2;

  // ---- build Nmat = diag(inorm) . A_adj . diag(onorm) for both graphs ----
  for (int i = tid; i < 2048; i += 512) Sb[i >> 10][i & 1023] = 0.f;
  __syncthreads();
  if (tid < 128) {
    const int gi = tid >> 6, e = tid & 63;
    const int es = src[(size_t)(ga + gi) * EE + e];
    const int ed = dst[(size_t)(ga + gi) * EE + e];
    atomicAdd(&Sb[gi][ed * 32 + es], 1.0f);
  }
  __syncthreads();
  if (tid < 64) {                       // inorm = rsqrt(row sums)
    const int gi = tid >> 5, n = tid & 31;
    float s = 0.f;
    for (int m = 0; m < NN; ++m) s += Sb[gi][n * 32 + m];
    Sb[gi][1056 + n] = 1.f / sqrtf(fmaxf(s, 1.f));
  } else if (tid < 128) {               // onorm = rsqrt(col sums)
    const int gi = (tid - 64) >> 5, n = tid & 31;
    float s = 0.f;
    for (int m = 0; m < NN; ++m) s += Sb[gi][m * 32 + n];
    Sb[gi][1088 + n] = 1.f / sqrtf(fmaxf(s, 1.f));
  }
  __syncthreads();
  for (int i = tid; i < 2048; i += 512) {
    const int gi = i >> 10, idx = i & 1023;
    Sb[gi][idx] *= Sb[gi][1056 + (idx >> 5)] * Sb[gi][1088 + (idx & 31)];
  }
  __syncthreads();

  // ---- Nmat B-fragments (hi + lo*2^10) into NmF LDS (wave 0 builds) ----
  if (wv == 0) {
    #pragma unroll
    for (int gi = 0; gi < 2; ++gi) {
      #pragma unroll
      for (int nt2 = 0; nt2 < 2; ++nt2) {
        half8_t h8, l8;
        #pragma unroll
        for (int i = 0; i < 8; ++i) {
          const float v = Sb[gi][(nt2 * 16 + l15) * 32 + g4 * 8 + i];
          const _Float16 hb = (_Float16)v;
          h8[i] = hb;
          l8[i] = (_Float16)((v - (float)hb) * LO_SCALE);
        }
        const int nmo = ((gi * 2 + nt2) * 64 + lane) * 8;
        *(half8_t*)(NmF + nmo) = h8;
        *(half8_t*)(NmF + 2048 + nmo) = l8;
      }
    }
  }

  // ---- stage x (fp16, cols 74..95 zero) ----
  for (int i = tid; i < 2 * NN * 96; i += 512) {
    const int gi = i / 3072, rem = i - gi * 3072;
    const int r = rem / 96, c = rem - r * 96;
    const float vx = (c < INDIM) ? x[(size_t)(ga + gi) * (NN * INDIM) + r * INDIM + c] : 0.f;
    Hs[gi][r * 256 + (c ^ ((r & 7) << 3))] = (_Float16)vx;
  }
  __syncthreads();

  // ---- 11 graph convolutions ----
  conv2x<3, false>(&Hs[0][0], &Tb[0][0], NmF, pk + PK_WIN_HI, pk + PK_WIN_LO, b_in, lane, wv);
  #pragma unroll 1
  for (int L = 0; L < GCR; ++L) {
    const _Float16* h1 = pk + PK_G_BASE + (size_t)L * PK_G_STRIDE;
    conv2x<8, true>(&Hs[0][0], &Tb[0][0], NmF, h1, h1 + 65536, b_g1 + L * HH, lane, wv);
    const _Float16* h2 = pk + PK_G_BASE + (size_t)(5 + L) * PK_G_STRIDE;
    conv2x<8, true>(&Hs[0][0], &Tb[0][0], NmF, h2, h2 + 65536, b_g2 + L * HH, lane, wv);
  }

  // ---- attention ----
  {
    const _Float16* Qhi = pk + PK_WQK_HI;
    const _Float16* Qlo = pk + PK_WQK_LO;
    const int sgi = wv >> 2, smt = (wv >> 1) & 1, snt = wv & 1;   // 8 waves -> 8 tiles
    float4_t sacc = (float4_t){0.f, 0.f, 0.f, 0.f};

    #pragma unroll
    for (int p = 0; p < 2; ++p) {
      const int nt = p * 8 + wv;
      // u' = h@Wqk for this wave's 16 cols
      float4_t uh[2][2], ul[2][2];
      #pragma unroll
      for (int a = 0; a < 2; ++a)
        #pragma unroll
        for (int b = 0; b < 2; ++b) {
          uh[a][b] = (float4_t){0.f, 0.f, 0.f, 0.f};
          ul[a][b] = (float4_t){0.f, 0.f, 0.f, 0.f};
        }
      #pragma unroll
      for (int ks = 0; ks < 8; ++ks) {
        const int off = ((nt * 8 + ks) * 64 + lane) * 8;
        const half8_t qh = *(const half8_t*)(Qhi + off);
        const half8_t ql = *(const half8_t*)(Qlo + off);
        const int j0 = ks * 32 + g4 * 8;
        #pragma unroll
        for (int gi = 0; gi < 2; ++gi)
          #pragma unroll
          for (int mt = 0; mt < 2; ++mt) {
            const half8_t ha = *(const half8_t*)(&Hs[gi][(mt * 16 + l15) * 256 + (j0 ^ sw)]);
            uh[gi][mt] = MF16(ha, qh, uh[gi][mt]);
            ul[gi][mt] = MF16(ha, ql, ul[gi][mt]);
          }
      }
      // write u' slice [n][128] swizzled into Tb (+tvec); col fixed per lane
      const float tv = tvec[nt * 16 + l15];
      const int cl = wv * 16 + l15;
      #pragma unroll
      for (int gi = 0; gi < 2; ++gi)
        #pragma unroll
        for (int mt = 0; mt < 2; ++mt)
          #pragma unroll
          for (int jj = 0; jj < 4; ++jj) {
            const int n = mt * 16 + 4 * g4 + jj;
            Tb[gi][n * 128 + (cl ^ ((n & 7) << 3))] =
                (_Float16)(uh[gi][mt][jj] + ul[gi][mt][jj] * LO_INV + tv);
          }
      __syncthreads();
      // S partial: wave -> (sgi, smt, snt)
      #pragma unroll
      for (int ksl = 0; ksl < 4; ++ksl) {
        const int kl = ksl * 32 + g4 * 8;
        const half8_t ua = *(const half8_t*)(&Tb[sgi][(smt * 16 + l15) * 128 + (kl ^ sw)]);
        const half8_t hb = *(const half8_t*)(&Hs[sgi][(snt * 16 + l15) * 256 + ((p * 128 + kl) ^ sw)]);
        sacc = MF16(ua, hb, sacc);
      }
      __syncthreads();
    }
    // S write (each wave owns a distinct (sgi, smt, snt) tile)
    #pragma unroll
    for (int jj = 0; jj < 4; ++jj)
      Sb[sgi][(smt * 16 + 4 * g4 + jj) * 33 + snt * 16 + l15] = sacc[jj];
  }

  // ---- v[m] = h[m].Wv + bv  (2 graphs x 32 rows x 8 lanes) ----
  {
    const int gi = tid >> 8, m = (tid >> 3) & 31, q = tid & 7;
    float s = 0.f;
    const int c0 = q * 32;
    for (int cc = 0; cc < 32; ++cc) {
      const int c = c0 + cc;
      s = fmaf((float)Hs[gi][m * 256 + (c ^ ((m & 7) << 3))], Wvp[c], s);
    }
    s += __shfl_xor(s, 1);
    s += __shfl_xor(s, 2);
    s += __shfl_xor(s, 4);
    if (q == 0) Sb[gi][1120 + m] = s + bv[0];
  }
  __syncthreads();

  // ---- row softmax fused with w = attn @ v ----
  if (tid < 64) {
    const int gi = tid >> 5, n = tid & 31;
    float mx = -1e30f;
    #pragma unroll 1
    for (int m = 0; m < NN; ++m) mx = fmaxf(mx, Sb[gi][n * 33 + m]);
    float se = 0.f, sv = 0.f;
    #pragma unroll 1
    for (int m = 0; m < NN; ++m) {
      const float e = expf(Sb[gi][n * 33 + m] - mx);
      se += e;
      sv = fmaf(e, Sb[gi][1120 + m], sv);
    }
    Sb[gi][1152 + n] = sv / se;
  }
  __syncthreads();

  // ---- feats = h^T @ w  (512 threads: one column each) ----
  {
    const int gi = tid >> 8, j = tid & 255;
    float f0 = 0.f;
    #pragma unroll
    for (int m = 0; m < NN; ++m) {
      const float w = Sb[gi][1152 + m];
      f0 = fmaf((float)Hs[gi][m * 256 + (j ^ ((m & 7) << 3))], w, f0);
    }
    F[(size_t)(ga + gi) * FDIM + j] = f0;
    if (tid < 4) {
      const int gg = tid >> 1;
      F[(size_t)(ga + gg) * FDIM + HH + (tid & 1)] = addf[(size_t)(ga + gg) * ADDD + (tid & 1)];
    }
  }
}

// ---------------------------------------------------------------------------
// Kernel 2: batched MLP (unchanged)
// ---------------------------------------------------------------------------
#define MR 8
__global__ __launch_bounds__(256, 2)
void mlp_kernel(const float* __restrict__ F,
                const float* __restrict__ W1, const float* __restrict__ b1,
                const float* __restrict__ W2, const float* __restrict__ b2,
                const float* __restrict__ W3, const float* __restrict__ b3,
                float* __restrict__ out)
{
  __shared__ float sm[MR * M1];
  const int tid = threadIdx.x;
  const int r0 = blockIdx.x * MR;

  for (int idx = tid; idx < MR * FDIM; idx += 256) {
    const int r = idx / FDIM, c = idx - r * FDIM;
    sm[r * 260 + c] = F[(size_t)(r0 + r) * FDIM + c];
  }
  __syncthreads();

  float a1[4][MR];
  #pragma unroll
  for (int qg = 0; qg < 4; ++qg)
    #pragma unroll
    for (int r = 0; r < MR; ++r) a1[qg][r] = 0.f;
  for (int i = 0; i < FDIM; ++i) {
    float w[4];
    #pragma unroll
    for (int qg = 0; qg < 4; ++qg) w[qg] = W1[(size_t)i * M1 + tid + 256 * qg];
    #pragma unroll
    for (int r = 0; r < MR; ++r) {
      const float fv = sm[r * 260 + i];
      #pragma unroll
      for (int qg = 0; qg < 4; ++qg) a1[qg][r] = fmaf(fv, w[qg], a1[qg][r]);
    }
  }
  __syncthreads();
  #pragma unroll
  for (int qg = 0; qg < 4; ++qg) {
    const float bb = b1[tid + 256 * qg];
    #pragma unroll
    for (int r = 0; r < MR; ++r) {
      const float z = a1[qg][r] + bb;
      sm[r * M1 + tid + 256 * qg] = fmaxf(z, 0.01f * z);
    }
  }
  __syncthreads();

  float a2[2][MR];
  #pragma unroll
  for (int qg = 0; qg < 2; ++qg)
    #pragma unroll
    for (int r = 0; r < MR; ++r) a2[qg][r] = 0.f;
  for (int i = 0; i < M1; ++i) {
    float w[2];
    #pragma unroll
    for (int qg = 0; qg < 2; ++qg) w[qg] = W2[(size_t)i * M2 + tid + 256 * qg];
    #pragma unroll
    for (int r = 0; r < MR; ++r) {
      const float zv = sm[r * M1 + i];
      #pragma unroll
      for (int qg = 0; qg < 2; ++qg) a2[qg][r] = fmaf(zv, w[qg], a2[qg][r]);
    }
  }
  __syncthreads();
  #pragma unroll
  for (int qg = 0; qg < 2; ++qg) {
    const float bb = b2[tid + 256 * qg];
    #pragma unroll
    for (int r = 0; r < MR; ++r) {
      const float z = a2[qg][r] + bb;
      sm[r * M2 + tid + 256 * qg] = fmaxf(z, 0.01f * z);
    }
  }
  __syncthreads();

  const int lane = tid & 63, wid = tid >> 6;
  float wreg[8];
  #pragma unroll
  for (int q = 0; q < 8; ++q) wreg[q] = W3[lane + 64 * q];
  #pragma unroll
  for (int rr = 0; rr < 2; ++rr) {
    const int r = wid * 2 + rr;
    float s = 0.f;
    #pragma unroll
    for (int q = 0; q < 8; ++q) s = fmaf(sm[r * M2 + lane + 64 * q], wreg[q], s);
    #pragma unroll
    for (int off = 32; off; off >>= 1) s += __shfl_down(s, off);
    if (lane == 0) out[r0 + r] = s + b3[0];
  }
}

// ---------------------------------------------------------------------------
extern "C" void kernel_launch(void* const* d_in, const int* in_sizes, int n_in,
                              void* d_out, int out_size, void* d_ws, size_t ws_size,
                              hipStream_t stream) {
  (void)in_sizes; (void)n_in; (void)out_size; (void)ws_size;
  const float* x    = (const float*)d_in[0];
  const float* addf = (const float*)d_in[1];
  const int*   src  = (const int*)d_in[2];
  const int*   dst  = (const int*)d_in[3];
  const float* W_in = (const float*)d_in[4];
  const float* b_in = (const float*)d_in[5];
  const float* W_g1 = (const float*)d_in[6];
  const float* b_g1 = (const float*)d_in[7];
  const float* W_g2 = (const float*)d_in[8];
  const float* b_g2 = (const float*)d_in[9];
  const float* Wq   = (const float*)d_in[10];
  const float* bq   = (const float*)d_in[11];
  const float* Wk   = (const float*)d_in[12];
  // d_in[13] = bk : cancels in softmax (row-constant), unused
  const float* Wv   = (const float*)d_in[14];
  const float* bv   = (const float*)d_in[15];
  const float* W1   = (const float*)d_in[16];
  const float* b1   = (const float*)d_in[17];
  const float* W2   = (const float*)d_in[18];
  const float* b2   = (const float*)d_in[19];
  const float* W3   = (const float*)d_in[20];
  const float* b3   = (const float*)d_in[21];
  float* out = (float*)d_out;

  float* F        = (float*)d_ws;
  float* wqkf     = (float*)((char*)d_ws + WS_WQK);
  float* tvec     = (float*)((char*)d_ws + WS_TVEC);
  _Float16* pk    = (_Float16*)((char*)d_ws + WS_PK);

  prep1_kernel<<<dim3(257), dim3(256), 0, stream>>>(Wq, Wk, bq, wqkf, tvec);
  prep2_kernel<<<dim3(364), dim3(256), 0, stream>>>(W_in, W_g1, W_g2, wqkf, pk);
  gnn_kernel<<<dim3(BB / 2), dim3(512), 0, stream>>>(
      x, addf, src, dst, b_in, b_g1, b_g2, Wv, bv, pk, tvec, F);
  mlp_kernel<<<dim3(BB / MR), dim3(256), 0, stream>>>(
      F, W1, b1, W2, b2, W3, b3, out);
}

// Round 8
// 746.074 us; speedup vs baseline: 1.5975x; 1.1287x over previous
//
#include <hip/hip_runtime.h>
#include <math.h>

#define BB     4096
#define NN     32
#define EE     64
#define INDIM  74
#define HH     256
#define GCR    5
#define M1     1024
#define M2     512
#define FDIM   258
#define ADDD   2

typedef __attribute__((ext_vector_type(8))) _Float16 half8_t;
typedef __attribute__((ext_vector_type(4))) float float4_t;

#define MF16(a, b, c) __builtin_amdgcn_mfma_f32_16x16x32_f16((a), (b), (c), 0, 0, 0)
#define LO_SCALE 1024.0f
#define LO_INV   (1.0f / 1024.0f)

// ---- ws layout (bytes) ----
#define WS_F      0               // F [4096][258] f32
#define WS_WQK    4227072         // Wqk fp32 [256][256]
#define WS_TVEC   4489216         // tvec fp32 [256]
#define WS_PK     4490240         // packed fp16 hi/lo fragments
// packed offsets in _Float16 units from PK base:
#define PK_WIN_HI 0
#define PK_WIN_LO 24576
#define PK_G_BASE 49152
#define PK_G_STRIDE 131072
#define PK_WQK_HI 1359872
#define PK_WQK_LO (1359872 + 65536)

union H4 { unsigned long long u; _Float16 h[4]; };

// ---------------------------------------------------------------------------
// Prep 1: Wqk = Wq @ Wk^T (fp32), tvec = Wk @ bq
// ---------------------------------------------------------------------------
__global__ void prep1_kernel(const float* __restrict__ Wq, const float* __restrict__ Wk,
                             const float* __restrict__ bq,
                             float* __restrict__ wqkf, float* __restrict__ tvec) {
  const int i = blockIdx.x, j = threadIdx.x;
  if (i < 256) {
    __shared__ float qrow[256];
    qrow[j] = Wq[i * 256 + j];
    __syncthreads();
    float s = 0.f;
    for (int c = 0; c < 256; ++c) s = fmaf(qrow[c], Wk[j * 256 + c], s);
    wqkf[i * 256 + j] = s;
  } else {
    float s = 0.f;
    for (int c = 0; c < 256; ++c) s = fmaf(Wk[j * 256 + c], bq[c], s);
    tvec[j] = s;
  }
}

// ---------------------------------------------------------------------------
// Prep 2: pack weights into MFMA B-fragment order, fp16 hi + (lo * 2^10).
// chunk: local = (nt*KS + ks)*64 + lane; elem i:
//   k = ks*32 + (lane>>4)*8 + i ; j = nt*16 + (lane&15) ; src = W[k*256+j]
// ---------------------------------------------------------------------------
template<int KS, int KREAL>
__device__ __forceinline__ void pack_one(const float* __restrict__ S,
                                         _Float16* __restrict__ hi,
                                         _Float16* __restrict__ lo, int local) {
  const int l = local & 63;
  const int nk = local >> 6;
  const int ks = nk % KS;
  const int nt = nk / KS;
  const int j = nt * 16 + (l & 15);
  const int kbase = ks * 32 + (l >> 4) * 8;
  half8_t h8, l8;
  #pragma unroll
  for (int i = 0; i < 8; ++i) {
    const int k = kbase + i;
    const float v = (k < KREAL) ? S[k * 256 + j] : 0.f;
    const _Float16 hb = (_Float16)v;
    h8[i] = hb;
    l8[i] = (_Float16)((v - (float)hb) * LO_SCALE);
  }
  *(half8_t*)(hi + (size_t)local * 8) = h8;
  *(half8_t*)(lo + (size_t)local * 8) = l8;
}

__global__ void prep2_kernel(const float* __restrict__ W_in,
                             const float* __restrict__ W_g1, const float* __restrict__ W_g2,
                             const float* __restrict__ wqkf, _Float16* __restrict__ pk) {
  const int cid = blockIdx.x * 256 + threadIdx.x;
  if (cid < 3072) {
    pack_one<3, 74>(W_in, pk + PK_WIN_HI, pk + PK_WIN_LO, cid);
  } else {
    const int m = (cid - 3072) >> 13;               // 0..10
    const int local = (cid - 3072) & 8191;
    _Float16* hi; const float* S;
    if (m < 10) {
      hi = pk + PK_G_BASE + (size_t)m * PK_G_STRIDE;
      S = (m < 5) ? (W_g1 + (size_t)m * 65536) : (W_g2 + (size_t)(m - 5) * 65536);
    } else {
      hi = pk + PK_WQK_HI;
      S = wqkf;
    }
    pack_one<8, 256>(S, hi, hi + 65536, local);
  }
}

// ---------------------------------------------------------------------------
// conv for 2 graphs, 8 waves. Low-register schedule:
//   phase0: MFMA1 -> Tstore -> MFMA2 -> hold0 (4 u64 only)
//   phase1: MFMA1 (old H) ; barrier ; write hold0 ; Tstore ; MFMA2 -> H direct
// 2 barriers/conv. Hs layout: n*256 + (j ^ ((n&7)<<3)).
// T layout: wv*512 + ((k>>3)*16+c)*8 + (k&7), wave-private.
// ---------------------------------------------------------------------------
template<int KS, bool RELU>
__device__ __forceinline__ void conv2x(
    _Float16* Hs, _Float16* Tb, const _Float16* NmF,
    const _Float16* __restrict__ Whi, const _Float16* __restrict__ Wlo,
    const float* __restrict__ bias,
    int lane, int wv)
{
  const int g4 = lane >> 4, l15 = lane & 15;
  const int sw = (l15 & 7) << 3;

  float4_t th[2][2], tl[2][2];
  unsigned long long hold0[2][2];

  // ================= phase 0 =================
  #pragma unroll
  for (int a = 0; a < 2; ++a)
    #pragma unroll
    for (int b = 0; b < 2; ++b) {
      th[a][b] = (float4_t){0.f, 0.f, 0.f, 0.f};
      tl[a][b] = (float4_t){0.f, 0.f, 0.f, 0.f};
    }
  #pragma unroll
  for (int ks = 0; ks < KS; ++ks) {
    const int off = ((wv * KS + ks) * 64 + lane) * 8;
    const half8_t wh = *(const half8_t*)(Whi + off);
    const half8_t wl = *(const half8_t*)(Wlo + off);
    const int j0 = ks * 32 + g4 * 8;
    #pragma unroll
    for (int gi = 0; gi < 2; ++gi)
      #pragma unroll
      for (int mt = 0; mt < 2; ++mt) {
        const half8_t ha = *(const half8_t*)(Hs + (gi << 13) + ((mt * 16 + l15) * 256 + (j0 ^ sw)));
        th[gi][mt] = MF16(ha, wh, th[gi][mt]);
        tl[gi][mt] = MF16(ha, wl, tl[gi][mt]);
      }
  }
  #pragma unroll
  for (int gi = 0; gi < 2; ++gi)
    #pragma unroll
    for (int mt = 0; mt < 2; ++mt) {
      const int r0 = mt * 16 + 4 * g4;
      H4 pk4;
      #pragma unroll
      for (int jj = 0; jj < 4; ++jj)
        pk4.h[jj] = (_Float16)(th[gi][mt][jj] + tl[gi][mt][jj] * LO_INV);
      const int idx = wv * 512 + ((r0 >> 3) * 16 + l15) * 8 + (r0 & 7);
      *(unsigned long long*)(Tb + (gi << 12) + idx) = pk4.u;
    }
  {
    const float4 b4 = *(const float4*)&bias[wv * 16 + 4 * g4];
    #pragma unroll
    for (int gi = 0; gi < 2; ++gi) {
      const half8_t ta = *(const half8_t*)(Tb + (gi << 12) + wv * 512 + lane * 8);
      #pragma unroll
      for (int nt2 = 0; nt2 < 2; ++nt2) {
        const int nmo = ((gi * 2 + nt2) * 64 + lane) * 8;
        const half8_t nmh = *(const half8_t*)(NmF + nmo);
        const half8_t nml = *(const half8_t*)(NmF + 2048 + nmo);
        const float4_t dh = MF16(ta, nmh, ((float4_t){0.f, 0.f, 0.f, 0.f}));
        const float4_t dl = MF16(ta, nml, ((float4_t){0.f, 0.f, 0.f, 0.f}));
        H4 pk4;
        #pragma unroll
        for (int jj = 0; jj < 4; ++jj) {
          float v = dh[jj] + dl[jj] * LO_INV + ((const float*)&b4)[jj];
          if (RELU) v = fmaxf(v, 0.f);
          pk4.h[jj] = (_Float16)v;
        }
        hold0[gi][nt2] = pk4.u;
      }
    }
  }

  // ================= phase 1: MFMA1 only (old H) =================
  #pragma unroll
  for (int a = 0; a < 2; ++a)
    #pragma unroll
    for (int b = 0; b < 2; ++b) {
      th[a][b] = (float4_t){0.f, 0.f, 0.f, 0.f};
      tl[a][b] = (float4_t){0.f, 0.f, 0.f, 0.f};
    }
  #pragma unroll
  for (int ks = 0; ks < KS; ++ks) {
    const int off = (((8 + wv) * KS + ks) * 64 + lane) * 8;
    const half8_t wh = *(const half8_t*)(Whi + off);
    const half8_t wl = *(const half8_t*)(Wlo + off);
    const int j0 = ks * 32 + g4 * 8;
    #pragma unroll
    for (int gi = 0; gi < 2; ++gi)
      #pragma unroll
      for (int mt = 0; mt < 2; ++mt) {
        const half8_t ha = *(const half8_t*)(Hs + (gi << 13) + ((mt * 16 + l15) * 256 + (j0 ^ sw)));
        th[gi][mt] = MF16(ha, wh, th[gi][mt]);
        tl[gi][mt] = MF16(ha, wl, tl[gi][mt]);
      }
  }

  __syncthreads();   // ALL waves' H reads (both phases) complete

  // write phase-0 results
  {
    const int j0 = wv * 16 + 4 * g4;
    #pragma unroll
    for (int gi = 0; gi < 2; ++gi)
      #pragma unroll
      for (int nt2 = 0; nt2 < 2; ++nt2) {
        const int n = nt2 * 16 + l15;
        *(unsigned long long*)(Hs + (gi << 13) + (n * 256 + (j0 ^ ((n & 7) << 3)))) =
            hold0[gi][nt2];
      }
  }
  // phase-1 T store + MFMA2, write h' directly
  #pragma unroll
  for (int gi = 0; gi < 2; ++gi)
    #pragma unroll
    for (int mt = 0; mt < 2; ++mt) {
      const int r0 = mt * 16 + 4 * g4;
      H4 pk4;
      #pragma unroll
      for (int jj = 0; jj < 4; ++jj)
        pk4.h[jj] = (_Float16)(th[gi][mt][jj] + tl[gi][mt][jj] * LO_INV);
      const int idx = wv * 512 + ((r0 >> 3) * 16 + l15) * 8 + (r0 & 7);
      *(unsigned long long*)(Tb + (gi << 12) + idx) = pk4.u;
    }
  {
    const float4 b4 = *(const float4*)&bias[(8 + wv) * 16 + 4 * g4];
    const int j0 = (8 + wv) * 16 + 4 * g4;
    #pragma unroll
    for (int gi = 0; gi < 2; ++gi) {
      const half8_t ta = *(const half8_t*)(Tb + (gi << 12) + wv * 512 + lane * 8);
      #pragma unroll
      for (int nt2 = 0; nt2 < 2; ++nt2) {
        const int nmo = ((gi * 2 + nt2) * 64 + lane) * 8;
        const half8_t nmh = *(const half8_t*)(NmF + nmo);
        const half8_t nml = *(const half8_t*)(NmF + 2048 + nmo);
        const float4_t dh = MF16(ta, nmh, ((float4_t){0.f, 0.f, 0.f, 0.f}));
        const float4_t dl = MF16(ta, nml, ((float4_t){0.f, 0.f, 0.f, 0.f}));
        H4 pk4;
        #pragma unroll
        for (int jj = 0; jj < 4; ++jj) {
          float v = dh[jj] + dl[jj] * LO_INV + ((const float*)&b4)[jj];
          if (RELU) v = fmaxf(v, 0.f);
          pk4.h[jj] = (_Float16)v;
        }
        const int n = nt2 * 16 + l15;
        *(unsigned long long*)(Hs + (gi << 13) + (n * 256 + (j0 ^ ((n & 7) << 3)))) = pk4.u;
      }
    }
  }
  __syncthreads();   // new h visible
}

// ---------------------------------------------------------------------------
// GNN kernel: 2 graphs per block, 512 threads (8 waves).
// LDS: Hs 32KB + Tb 16KB + NmF 8KB + Sb 2x4.6KB = 65.5 KB -> 2 blocks/CU.
// Sb per graph: [0..1056) Nf(setup)->S ; inorm@1056 onorm@1088 ; v@1120 ; w@1152
// ---------------------------------------------------------------------------
__global__ __launch_bounds__(512, 4)
void gnn_kernel(const float* __restrict__ x, const float* __restrict__ addf,
                const int* __restrict__ src, const int* __restrict__ dst,
                const float* __restrict__ b_in,
                const float* __restrict__ b_g1, const float* __restrict__ b_g2,
                const float* __restrict__ Wvp, const float* __restrict__ bv,
                const _Float16* __restrict__ pk,
                const float* __restrict__ tvec,
                float* __restrict__ F)
{
  __shared__ __align__(16) _Float16 Hs[2][8192];
  __shared__ __align__(16) _Float16 Tb[2][4096];
  __shared__ __align__(16) _Float16 NmF[4096];
  __shared__ float Sb[2][1184];

  const int tid = threadIdx.x;
  const int lane = tid & 63;
  const int wv = tid >> 6;            // 0..7
  const int g4 = lane >> 4, l15 = lane & 15;
  const int sw = (l15 & 7) << 3;
  const int ga = blockIdx.x * 2;

  // ---- build Nmat = diag(inorm) . A_adj . diag(onorm) for both graphs ----
  for (int i = tid; i < 2048; i += 512) Sb[i >> 10][i & 1023] = 0.f;
  __syncthreads();
  if (tid < 128) {
    const int gi = tid >> 6, e = tid & 63;
    const int es = src[(size_t)(ga + gi) * EE + e];
    const int ed = dst[(size_t)(ga + gi) * EE + e];
    atomicAdd(&Sb[gi][ed * 32 + es], 1.0f);
  }
  __syncthreads();
  if (tid < 64) {                       // inorm = rsqrt(row sums)
    const int gi = tid >> 5, n = tid & 31;
    float s = 0.f;
    for (int m = 0; m < NN; ++m) s += Sb[gi][n * 32 + m];
    Sb[gi][1056 + n] = 1.f / sqrtf(fmaxf(s, 1.f));
  } else if (tid < 128) {               // onorm = rsqrt(col sums)
    const int gi = (tid - 64) >> 5, n = tid & 31;
    float s = 0.f;
    for (int m = 0; m < NN; ++m) s += Sb[gi][m * 32 + n];
    Sb[gi][1088 + n] = 1.f / sqrtf(fmaxf(s, 1.f));
  }
  __syncthreads();
  for (int i = tid; i < 2048; i += 512) {
    const int gi = i >> 10, idx = i & 1023;
    Sb[gi][idx] *= Sb[gi][1056 + (idx >> 5)] * Sb[gi][1088 + (idx & 31)];
  }
  __syncthreads();

  // ---- Nmat B-fragments (hi + lo*2^10) into NmF LDS (wave 0 builds) ----
  if (wv == 0) {
    #pragma unroll
    for (int gi = 0; gi < 2; ++gi) {
      #pragma unroll
      for (int nt2 = 0; nt2 < 2; ++nt2) {
        half8_t h8, l8;
        #pragma unroll
        for (int i = 0; i < 8; ++i) {
          const float v = Sb[gi][(nt2 * 16 + l15) * 32 + g4 * 8 + i];
          const _Float16 hb = (_Float16)v;
          h8[i] = hb;
          l8[i] = (_Float16)((v - (float)hb) * LO_SCALE);
        }
        const int nmo = ((gi * 2 + nt2) * 64 + lane) * 8;
        *(half8_t*)(NmF + nmo) = h8;
        *(half8_t*)(NmF + 2048 + nmo) = l8;
      }
    }
  }

  // ---- stage x (fp16, cols 74..95 zero) ----
  for (int i = tid; i < 2 * NN * 96; i += 512) {
    const int gi = i / 3072, rem = i - gi * 3072;
    const int r = rem / 96, c = rem - r * 96;
    const float vx = (c < INDIM) ? x[(size_t)(ga + gi) * (NN * INDIM) + r * INDIM + c] : 0.f;
    Hs[gi][r * 256 + (c ^ ((r & 7) << 3))] = (_Float16)vx;
  }
  __syncthreads();

  // ---- 11 graph convolutions ----
  conv2x<3, false>(&Hs[0][0], &Tb[0][0], NmF, pk + PK_WIN_HI, pk + PK_WIN_LO, b_in, lane, wv);
  #pragma unroll 1
  for (int L = 0; L < GCR; ++L) {
    const _Float16* h1 = pk + PK_G_BASE + (size_t)L * PK_G_STRIDE;
    conv2x<8, true>(&Hs[0][0], &Tb[0][0], NmF, h1, h1 + 65536, b_g1 + L * HH, lane, wv);
    const _Float16* h2 = pk + PK_G_BASE + (size_t)(5 + L) * PK_G_STRIDE;
    conv2x<8, true>(&Hs[0][0], &Tb[0][0], NmF, h2, h2 + 65536, b_g2 + L * HH, lane, wv);
  }

  // ---- attention ----
  {
    const _Float16* Qhi = pk + PK_WQK_HI;
    const _Float16* Qlo = pk + PK_WQK_LO;
    const int sgi = wv >> 2, smt = (wv >> 1) & 1, snt = wv & 1;   // 8 waves -> 8 tiles
    float4_t sacc = (float4_t){0.f, 0.f, 0.f, 0.f};

    #pragma unroll
    for (int p = 0; p < 2; ++p) {
      const int nt = p * 8 + wv;
      // u' = h@Wqk for this wave's 16 cols
      float4_t uh[2][2], ul[2][2];
      #pragma unroll
      for (int a = 0; a < 2; ++a)
        #pragma unroll
        for (int b = 0; b < 2; ++b) {
          uh[a][b] = (float4_t){0.f, 0.f, 0.f, 0.f};
          ul[a][b] = (float4_t){0.f, 0.f, 0.f, 0.f};
        }
      #pragma unroll
      for (int ks = 0; ks < 8; ++ks) {
        const int off = ((nt * 8 + ks) * 64 + lane) * 8;
        const half8_t qh = *(const half8_t*)(Qhi + off);
        const half8_t ql = *(const half8_t*)(Qlo + off);
        const int j0 = ks * 32 + g4 * 8;
        #pragma unroll
        for (int gi = 0; gi < 2; ++gi)
          #pragma unroll
          for (int mt = 0; mt < 2; ++mt) {
            const half8_t ha = *(const half8_t*)(&Hs[gi][(mt * 16 + l15) * 256 + (j0 ^ sw)]);
            uh[gi][mt] = MF16(ha, qh, uh[gi][mt]);
            ul[gi][mt] = MF16(ha, ql, ul[gi][mt]);
          }
      }
      // write u' slice [n][128] swizzled into Tb (+tvec); col fixed per lane
      const float tv = tvec[nt * 16 + l15];
      const int cl = wv * 16 + l15;
      #pragma unroll
      for (int gi = 0; gi < 2; ++gi)
        #pragma unroll
        for (int mt = 0; mt < 2; ++mt)
          #pragma unroll
          for (int jj = 0; jj < 4; ++jj) {
            const int n = mt * 16 + 4 * g4 + jj;
            Tb[gi][n * 128 + (cl ^ ((n & 7) << 3))] =
                (_Float16)(uh[gi][mt][jj] + ul[gi][mt][jj] * LO_INV + tv);
          }
      __syncthreads();
      // S partial: wave -> (sgi, smt, snt)
      #pragma unroll
      for (int ksl = 0; ksl < 4; ++ksl) {
        const int kl = ksl * 32 + g4 * 8;
        const half8_t ua = *(const half8_t*)(&Tb[sgi][(smt * 16 + l15) * 128 + (kl ^ sw)]);
        const half8_t hb = *(const half8_t*)(&Hs[sgi][(snt * 16 + l15) * 256 + ((p * 128 + kl) ^ sw)]);
        sacc = MF16(ua, hb, sacc);
      }
      __syncthreads();
    }
    // S write (each wave owns a distinct (sgi, smt, snt) tile)
    #pragma unroll
    for (int jj = 0; jj < 4; ++jj)
      Sb[sgi][(smt * 16 + 4 * g4 + jj) * 33 + snt * 16 + l15] = sacc[jj];
  }

  // ---- v[m] = h[m].Wv + bv  (2 graphs x 32 rows x 8 lanes) ----
  {
    const int gi = tid >> 8, m = (tid >> 3) & 31, q = tid & 7;
    float s = 0.f;
    const int c0 = q * 32;
    for (int cc = 0; cc < 32; ++cc) {
      const int c = c0 + cc;
      s = fmaf((float)Hs[gi][m * 256 + (c ^ ((m & 7) << 3))], Wvp[c], s);
    }
    s += __shfl_xor(s, 1);
    s += __shfl_xor(s, 2);
    s += __shfl_xor(s, 4);
    if (q == 0) Sb[gi][1120 + m] = s + bv[0];
  }
  __syncthreads();

  // ---- row softmax fused with w = attn @ v ----
  if (tid < 64) {
    const int gi = tid >> 5, n = tid & 31;
    float mx = -1e30f;
    #pragma unroll 1
    for (int m = 0; m < NN; ++m) mx = fmaxf(mx, Sb[gi][n * 33 + m]);
    float se = 0.f, sv = 0.f;
    #pragma unroll 1
    for (int m = 0; m < NN; ++m) {
      const float e = expf(Sb[gi][n * 33 + m] - mx);
      se += e;
      sv = fmaf(e, Sb[gi][1120 + m], sv);
    }
    Sb[gi][1152 + n] = sv / se;
  }
  __syncthreads();

  // ---- feats = h^T @ w  (512 threads: one column each) ----
  {
    const int gi = tid >> 8, j = tid & 255;
    float f0 = 0.f;
    #pragma unroll
    for (int m = 0; m < NN; ++m) {
      const float w = Sb[gi][1152 + m];
      f0 = fmaf((float)Hs[gi][m * 256 + (j ^ ((m & 7) << 3))], w, f0);
    }
    F[(size_t)(ga + gi) * FDIM + j] = f0;
    if (tid < 4) {
      const int gg = tid >> 1;
      F[(size_t)(ga + gg) * FDIM + HH + (tid & 1)] = addf[(size_t)(ga + gg) * ADDD + (tid & 1)];
    }
  }
}

// ---------------------------------------------------------------------------
// Kernel 2: batched MLP (unchanged)
// ---------------------------------------------------------------------------
#define MR 8
__global__ __launch_bounds__(256, 2)
void mlp_kernel(const float* __restrict__ F,
                const float* __restrict__ W1, const float* __restrict__ b1,
                const float* __restrict__ W2, const float* __restrict__ b2,
                const float* __restrict__ W3, const float* __restrict__ b3,
                float* __restrict__ out)
{
  __shared__ float sm[MR * M1];
  const int tid = threadIdx.x;
  const int r0 = blockIdx.x * MR;

  for (int idx = tid; idx < MR * FDIM; idx += 256) {
    const int r = idx / FDIM, c = idx - r * FDIM;
    sm[r * 260 + c] = F[(size_t)(r0 + r) * FDIM + c];
  }
  __syncthreads();

  float a1[4][MR];
  #pragma unroll
  for (int qg = 0; qg < 4; ++qg)
    #pragma unroll
    for (int r = 0; r < MR; ++r) a1[qg][r] = 0.f;
  for (int i = 0; i < FDIM; ++i) {
    float w[4];
    #pragma unroll
    for (int qg = 0; qg < 4; ++qg) w[qg] = W1[(size_t)i * M1 + tid + 256 * qg];
    #pragma unroll
    for (int r = 0; r < MR; ++r) {
      const float fv = sm[r * 260 + i];
      #pragma unroll
      for (int qg = 0; qg < 4; ++qg) a1[qg][r] = fmaf(fv, w[qg], a1[qg][r]);
    }
  }
  __syncthreads();
  #pragma unroll
  for (int qg = 0; qg < 4; ++qg) {
    const float bb = b1[tid + 256 * qg];
    #pragma unroll
    for (int r = 0; r < MR; ++r) {
      const float z = a1[qg][r] + bb;
      sm[r * M1 + tid + 256 * qg] = fmaxf(z, 0.01f * z);
    }
  }
  __syncthreads();

  float a2[2][MR];
  #pragma unroll
  for (int qg = 0; qg < 2; ++qg)
    #pragma unroll
    for (int r = 0; r < MR; ++r) a2[qg][r] = 0.f;
  for (int i = 0; i < M1; ++i) {
    float w[2];
    #pragma unroll
    for (int qg = 0; qg < 2; ++qg) w[qg] = W2[(size_t)i * M2 + tid + 256 * qg];
    #pragma unroll
    for (int r = 0; r < MR; ++r) {
      const float zv = sm[r * M1 + i];
      #pragma unroll
      for (int qg = 0; qg < 2; ++qg) a2[qg][r] = fmaf(zv, w[qg], a2[qg][r]);
    }
  }
  __syncthreads();
  #pragma unroll
  for (int qg = 0; qg < 2; ++qg) {
    const float bb = b2[tid + 256 * qg];
    #pragma unroll
    for (int r = 0; r < MR; ++r) {
      const float z = a2[qg][r] + bb;
      sm[r * M2 + tid + 256 * qg] = fmaxf(z, 0.01f * z);
    }
  }
  __syncthreads();

  const int lane = tid & 63, wid = tid >> 6;
  float wreg[8];
  #pragma unroll
  for (int q = 0; q < 8; ++q) wreg[q] = W3[lane + 64 * q];
  #pragma unroll
  for (int rr = 0; rr < 2; ++rr) {
    const int r = wid * 2 + rr;
    float s = 0.f;
    #pragma unroll
    for (int q = 0; q < 8; ++q) s = fmaf(sm[r * M2 + lane + 64 * q], wreg[q], s);
    #pragma unroll
    for (int off = 32; off; off >>= 1) s += __shfl_down(s, off);
    if (lane == 0) out[r0 + r] = s + b3[0];
  }
}

// ---------------------------------------------------------------------------
extern "C" void kernel_launch(void* const* d_in, const int* in_sizes, int n_in,
                              void* d_out, int out_size, void* d_ws, size_t ws_size,
                              hipStream_t stream) {
  (void)in_sizes; (void)n_in; (void)out_size; (void)ws_size;
  const float* x    = (const float*)d_in[0];
  const float* addf = (const float*)d_in[1];
  const int*   src  = (const int*)d_in[2];
  const int*   dst  = (const int*)d_in[3];
  const float* W_in = (const float*)d_in[4];
  const float* b_in = (const float*)d_in[5];
  const float* W_g1 = (const float*)d_in[6];
  const float* b_g1 = (const float*)d_in[7];
  const float* W_g2 = (const float*)d_in[8];
  const float* b_g2 = (const float*)d_in[9];
  const float* Wq   = (const float*)d_in[10];
  const float* bq   = (const float*)d_in[11];
  const float* Wk   = (const float*)d_in[12];
  // d_in[13] = bk : cancels in softmax (row-constant), unused
  const float* Wv   = (const float*)d_in[14];
  const float* bv   = (const float*)d_in[15];
  const float* W1   = (const float*)d_in[16];
  const float* b1   = (const float*)d_in[17];
  const float* W2   = (const float*)d_in[18];
  const float* b2   = (const float*)d_in[19];
  const float* W3   = (const float*)d_in[20];
  const float* b3   = (const float*)d_in[21];
  float* out = (float*)d_out;

  float* F        = (float*)d_ws;
  float* wqkf     = (float*)((char*)d_ws + WS_WQK);
  float* tvec     = (float*)((char*)d_ws + WS_TVEC);
  _Float16* pk    = (_Float16*)((char*)d_ws + WS_PK);

  prep1_kernel<<<dim3(257), dim3(256), 0, stream>>>(Wq, Wk, bq, wqkf, tvec);
  prep2_kernel<<<dim3(364), dim3(256), 0, stream>>>(W_in, W_g1, W_g2, wqkf, pk);
  gnn_kernel<<<dim3(BB / 2), dim3(512), 0, stream>>>(
      x, addf, src, dst, b_in, b_g1, b_g2, Wv, bv, pk, tvec, F);
  mlp_kernel<<<dim3(BB / MR), dim3(256), 0, stream>>>(
      F, W1, b1, W2, b2, W3, b3, out);
}

// Round 9
// 668.927 us; speedup vs baseline: 1.7818x; 1.1153x over previous
//
#include <hip/hip_runtime.h>
#include <math.h>

#define BB     4096
#define NN     32
#define EE     64
#define INDIM  74
#define HH     256
#define GCR    5
#define M1     1024
#define M2     512
#define FDIM   258
#define ADDD   2

typedef __attribute__((ext_vector_type(8))) _Float16 half8_t;
typedef __attribute__((ext_vector_type(4))) float float4_t;

#define MF16(a, b, c) __builtin_amdgcn_mfma_f32_16x16x32_f16((a), (b), (c), 0, 0, 0)
#define LO_SCALE 1024.0f
#define LO_INV   (1.0f / 1024.0f)

// ---- ws layout (bytes) ----
#define WS_F      0               // F [4096][258] f32
#define WS_WQK    4227072         // Wqk fp32 [256][256]
#define WS_TVEC   4489216         // tvec fp32 [256]
#define WS_PK     4490240         // packed fp16 hi/lo fragments
// packed offsets in _Float16 units from PK base:
#define PK_WIN_HI 0
#define PK_WIN_LO 24576
#define PK_G_BASE 49152
#define PK_G_STRIDE 131072
#define PK_WQK_HI 1359872
#define PK_WQK_LO (1359872 + 65536)

union H4 { unsigned long long u; _Float16 h[4]; };

// ---------------------------------------------------------------------------
// Prep 1: Wqk = Wq @ Wk^T (fp32), tvec = Wk @ bq
// ---------------------------------------------------------------------------
__global__ void prep1_kernel(const float* __restrict__ Wq, const float* __restrict__ Wk,
                             const float* __restrict__ bq,
                             float* __restrict__ wqkf, float* __restrict__ tvec) {
  const int i = blockIdx.x, j = threadIdx.x;
  if (i < 256) {
    __shared__ float qrow[256];
    qrow[j] = Wq[i * 256 + j];
    __syncthreads();
    float s = 0.f;
    for (int c = 0; c < 256; ++c) s = fmaf(qrow[c], Wk[j * 256 + c], s);
    wqkf[i * 256 + j] = s;
  } else {
    float s = 0.f;
    for (int c = 0; c < 256; ++c) s = fmaf(Wk[j * 256 + c], bq[c], s);
    tvec[j] = s;
  }
}

// ---------------------------------------------------------------------------
// Prep 2: pack weights into MFMA B-fragment order, fp16 hi + (lo * 2^10).
// chunk: local = (nt*KS + ks)*64 + lane; elem i:
//   k = ks*32 + (lane>>4)*8 + i ; j = nt*16 + (lane&15) ; src = W[k*256+j]
// ---------------------------------------------------------------------------
template<int KS, int KREAL>
__device__ __forceinline__ void pack_one(const float* __restrict__ S,
                                         _Float16* __restrict__ hi,
                                         _Float16* __restrict__ lo, int local) {
  const int l = local & 63;
  const int nk = local >> 6;
  const int ks = nk % KS;
  const int nt = nk / KS;
  const int j = nt * 16 + (l & 15);
  const int kbase = ks * 32 + (l >> 4) * 8;
  half8_t h8, l8;
  #pragma unroll
  for (int i = 0; i < 8; ++i) {
    const int k = kbase + i;
    const float v = (k < KREAL) ? S[k * 256 + j] : 0.f;
    const _Float16 hb = (_Float16)v;
    h8[i] = hb;
    l8[i] = (_Float16)((v - (float)hb) * LO_SCALE);
  }
  *(half8_t*)(hi + (size_t)local * 8) = h8;
  *(half8_t*)(lo + (size_t)local * 8) = l8;
}

__global__ void prep2_kernel(const float* __restrict__ W_in,
                             const float* __restrict__ W_g1, const float* __restrict__ W_g2,
                             const float* __restrict__ wqkf, _Float16* __restrict__ pk) {
  const int cid = blockIdx.x * 256 + threadIdx.x;
  if (cid < 3072) {
    pack_one<3, 74>(W_in, pk + PK_WIN_HI, pk + PK_WIN_LO, cid);
  } else {
    const int m = (cid - 3072) >> 13;               // 0..10
    const int local = (cid - 3072) & 8191;
    _Float16* hi; const float* S;
    if (m < 10) {
      hi = pk + PK_G_BASE + (size_t)m * PK_G_STRIDE;
      S = (m < 5) ? (W_g1 + (size_t)m * 65536) : (W_g2 + (size_t)(m - 5) * 65536);
    } else {
      hi = pk + PK_WQK_HI;
      S = wqkf;
    }
    pack_one<8, 256>(S, hi, hi + 65536, local);
  }
}

// ---------------------------------------------------------------------------
// conv for 2 graphs, 8 waves. Low-register schedule:
//   phase0: MFMA1 -> Tstore -> MFMA2 -> hold0 (4 u64 only)
//   phase1: MFMA1 (old H) ; barrier ; write hold0 ; Tstore ; MFMA2 -> H direct
// 2 barriers/conv. Hs layout: n*256 + (j ^ ((n&7)<<3)).
// T layout: wv*512 + ((k>>3)*16+c)*8 + (k&7), wave-private.
// ---------------------------------------------------------------------------
template<int KS, bool RELU>
__device__ __forceinline__ void conv2x(
    _Float16* Hs, _Float16* Tb, const _Float16* NmF,
    const _Float16* __restrict__ Whi, const _Float16* __restrict__ Wlo,
    const float* __restrict__ bias,
    int lane, int wv)
{
  const int g4 = lane >> 4, l15 = lane & 15;
  const int sw = (l15 & 7) << 3;

  float4_t th[2][2], tl[2][2];
  unsigned long long hold0[2][2];

  // ================= phase 0 =================
  #pragma unroll
  for (int a = 0; a < 2; ++a)
    #pragma unroll
    for (int b = 0; b < 2; ++b) {
      th[a][b] = (float4_t){0.f, 0.f, 0.f, 0.f};
      tl[a][b] = (float4_t){0.f, 0.f, 0.f, 0.f};
    }
  #pragma unroll
  for (int ks = 0; ks < KS; ++ks) {
    const int off = ((wv * KS + ks) * 64 + lane) * 8;
    const half8_t wh = *(const half8_t*)(Whi + off);
    const half8_t wl = *(const half8_t*)(Wlo + off);
    const int j0 = ks * 32 + g4 * 8;
    #pragma unroll
    for (int gi = 0; gi < 2; ++gi)
      #pragma unroll
      for (int mt = 0; mt < 2; ++mt) {
        const half8_t ha = *(const half8_t*)(Hs + (gi << 13) + ((mt * 16 + l15) * 256 + (j0 ^ sw)));
        th[gi][mt] = MF16(ha, wh, th[gi][mt]);
        tl[gi][mt] = MF16(ha, wl, tl[gi][mt]);
      }
  }
  #pragma unroll
  for (int gi = 0; gi < 2; ++gi)
    #pragma unroll
    for (int mt = 0; mt < 2; ++mt) {
      const int r0 = mt * 16 + 4 * g4;
      H4 pk4;
      #pragma unroll
      for (int jj = 0; jj < 4; ++jj)
        pk4.h[jj] = (_Float16)(th[gi][mt][jj] + tl[gi][mt][jj] * LO_INV);
      const int idx = wv * 512 + ((r0 >> 3) * 16 + l15) * 8 + (r0 & 7);
      *(unsigned long long*)(Tb + (gi << 12) + idx) = pk4.u;
    }
  {
    const float4 b4 = *(const float4*)&bias[wv * 16 + 4 * g4];
    #pragma unroll
    for (int gi = 0; gi < 2; ++gi) {
      const half8_t ta = *(const half8_t*)(Tb + (gi << 12) + wv * 512 + lane * 8);
      #pragma unroll
      for (int nt2 = 0; nt2 < 2; ++nt2) {
        const int nmo = ((gi * 2 + nt2) * 64 + lane) * 8;
        const half8_t nmh = *(const half8_t*)(NmF + nmo);
        const half8_t nml = *(const half8_t*)(NmF + 2048 + nmo);
        const float4_t dh = MF16(ta, nmh, ((float4_t){0.f, 0.f, 0.f, 0.f}));
        const float4_t dl = MF16(ta, nml, ((float4_t){0.f, 0.f, 0.f, 0.f}));
        H4 pk4;
        #pragma unroll
        for (int jj = 0; jj < 4; ++jj) {
          float v = dh[jj] + dl[jj] * LO_INV + ((const float*)&b4)[jj];
          if (RELU) v = fmaxf(v, 0.f);
          pk4.h[jj] = (_Float16)v;
        }
        hold0[gi][nt2] = pk4.u;
      }
    }
  }

  // ================= phase 1: MFMA1 only (old H) =================
  #pragma unroll
  for (int a = 0; a < 2; ++a)
    #pragma unroll
    for (int b = 0; b < 2; ++b) {
      th[a][b] = (float4_t){0.f, 0.f, 0.f, 0.f};
      tl[a][b] = (float4_t){0.f, 0.f, 0.f, 0.f};
    }
  #pragma unroll
  for (int ks = 0; ks < KS; ++ks) {
    const int off = (((8 + wv) * KS + ks) * 64 + lane) * 8;
    const half8_t wh = *(const half8_t*)(Whi + off);
    const half8_t wl = *(const half8_t*)(Wlo + off);
    const int j0 = ks * 32 + g4 * 8;
    #pragma unroll
    for (int gi = 0; gi < 2; ++gi)
      #pragma unroll
      for (int mt = 0; mt < 2; ++mt) {
        const half8_t ha = *(const half8_t*)(Hs + (gi << 13) + ((mt * 16 + l15) * 256 + (j0 ^ sw)));
        th[gi][mt] = MF16(ha, wh, th[gi][mt]);
        tl[gi][mt] = MF16(ha, wl, tl[gi][mt]);
      }
  }

  __syncthreads();   // ALL waves' H reads (both phases) complete

  // write phase-0 results
  {
    const int j0 = wv * 16 + 4 * g4;
    #pragma unroll
    for (int gi = 0; gi < 2; ++gi)
      #pragma unroll
      for (int nt2 = 0; nt2 < 2; ++nt2) {
        const int n = nt2 * 16 + l15;
        *(unsigned long long*)(Hs + (gi << 13) + (n * 256 + (j0 ^ ((n & 7) << 3)))) =
            hold0[gi][nt2];
      }
  }
  // phase-1 T store + MFMA2, write h' directly
  #pragma unroll
  for (int gi = 0; gi < 2; ++gi)
    #pragma unroll
    for (int mt = 0; mt < 2; ++mt) {
      const int r0 = mt * 16 + 4 * g4;
      H4 pk4;
      #pragma unroll
      for (int jj = 0; jj < 4; ++jj)
        pk4.h[jj] = (_Float16)(th[gi][mt][jj] + tl[gi][mt][jj] * LO_INV);
      const int idx = wv * 512 + ((r0 >> 3) * 16 + l15) * 8 + (r0 & 7);
      *(unsigned long long*)(Tb + (gi << 12) + idx) = pk4.u;
    }
  {
    const float4 b4 = *(const float4*)&bias[(8 + wv) * 16 + 4 * g4];
    const int j0 = (8 + wv) * 16 + 4 * g4;
    #pragma unroll
    for (int gi = 0; gi < 2; ++gi) {
      const half8_t ta = *(const half8_t*)(Tb + (gi << 12) + wv * 512 + lane * 8);
      #pragma unroll
      for (int nt2 = 0; nt2 < 2; ++nt2) {
        const int nmo = ((gi * 2 + nt2) * 64 + lane) * 8;
        const half8_t nmh = *(const half8_t*)(NmF + nmo);
        const half8_t nml = *(const half8_t*)(NmF + 2048 + nmo);
        const float4_t dh = MF16(ta, nmh, ((float4_t){0.f, 0.f, 0.f, 0.f}));
        const float4_t dl = MF16(ta, nml, ((float4_t){0.f, 0.f, 0.f, 0.f}));
        H4 pk4;
        #pragma unroll
        for (int jj = 0; jj < 4; ++jj) {
          float v = dh[jj] + dl[jj] * LO_INV + ((const float*)&b4)[jj];
          if (RELU) v = fmaxf(v, 0.f);
          pk4.h[jj] = (_Float16)v;
        }
        const int n = nt2 * 16 + l15;
        *(unsigned long long*)(Hs + (gi << 13) + (n * 256 + (j0 ^ ((n & 7) << 3)))) = pk4.u;
      }
    }
  }
  __syncthreads();   // new h visible
}

// ---------------------------------------------------------------------------
// GNN kernel: 2 graphs per block, 512 threads (8 waves).
// LDS: Hs 32KB + Tb 16KB + NmF 8KB + Sb 2x4.6KB = 65.5 KB -> 2 blocks/CU
// (LDS-bound). launch_bounds min-waves relaxed to 2/EU so the register
// allocator is NOT clamped to 64 arch VGPRs (rounds 7/8: 300-600MB scratch).
// ---------------------------------------------------------------------------
__global__ __launch_bounds__(512, 2)
void gnn_kernel(const float* __restrict__ x, const float* __restrict__ addf,
                const int* __restrict__ src, const int* __restrict__ dst,
                const float* __restrict__ b_in,
                const float* __restrict__ b_g1, const float* __restrict__ b_g2,
                const float* __restrict__ Wvp, const float* __restrict__ bv,
                const _Float16* __restrict__ pk,
                const float* __restrict__ tvec,
                float* __restrict__ F)
{
  __shared__ __align__(16) _Float16 Hs[2][8192];
  __shared__ __align__(16) _Float16 Tb[2][4096];
  __shared__ __align__(16) _Float16 NmF[4096];
  __shared__ float Sb[2][1184];

  const int tid = threadIdx.x;
  const int lane = tid & 63;
  const int wv = tid >> 6;            // 0..7
  const int g4 = lane >> 4, l15 = lane & 15;
  const int sw = (l15 & 7) << 3;
  const int ga = blockIdx.x * 2;

  // ---- build Nmat = diag(inorm) . A_adj . diag(onorm) for both graphs ----
  for (int i = tid; i < 2048; i += 512) Sb[i >> 10][i & 1023] = 0.f;
  __syncthreads();
  if (tid < 128) {
    const int gi = tid >> 6, e = tid & 63;
    const int es = src[(size_t)(ga + gi) * EE + e];
    const int ed = dst[(size_t)(ga + gi) * EE + e];
    atomicAdd(&Sb[gi][ed * 32 + es], 1.0f);
  }
  __syncthreads();
  if (tid < 64) {                       // inorm = rsqrt(row sums)
    const int gi = tid >> 5, n = tid & 31;
    float s = 0.f;
    for (int m = 0; m < NN; ++m) s += Sb[gi][n * 32 + m];
    Sb[gi][1056 + n] = 1.f / sqrtf(fmaxf(s, 1.f));
  } else if (tid < 128) {               // onorm = rsqrt(col sums)
    const int gi = (tid - 64) >> 5, n = tid & 31;
    float s = 0.f;
    for (int m = 0; m < NN; ++m) s += Sb[gi][m * 32 + n];
    Sb[gi][1088 + n] = 1.f / sqrtf(fmaxf(s, 1.f));
  }
  __syncthreads();
  for (int i = tid; i < 2048; i += 512) {
    const int gi = i >> 10, idx = i & 1023;
    Sb[gi][idx] *= Sb[gi][1056 + (idx >> 5)] * Sb[gi][1088 + (idx & 31)];
  }
  __syncthreads();

  // ---- Nmat B-fragments (hi + lo*2^10) into NmF LDS (wave 0 builds) ----
  if (wv == 0) {
    #pragma unroll
    for (int gi = 0; gi < 2; ++gi) {
      #pragma unroll
      for (int nt2 = 0; nt2 < 2; ++nt2) {
        half8_t h8, l8;
        #pragma unroll
        for (int i = 0; i < 8; ++i) {
          const float v = Sb[gi][(nt2 * 16 + l15) * 32 + g4 * 8 + i];
          const _Float16 hb = (_Float16)v;
          h8[i] = hb;
          l8[i] = (_Float16)((v - (float)hb) * LO_SCALE);
        }
        const int nmo = ((gi * 2 + nt2) * 64 + lane) * 8;
        *(half8_t*)(NmF + nmo) = h8;
        *(half8_t*)(NmF + 2048 + nmo) = l8;
      }
    }
  }

  // ---- stage x (fp16, cols 74..95 zero) ----
  for (int i = tid; i < 2 * NN * 96; i += 512) {
    const int gi = i / 3072, rem = i - gi * 3072;
    const int r = rem / 96, c = rem - r * 96;
    const float vx = (c < INDIM) ? x[(size_t)(ga + gi) * (NN * INDIM) + r * INDIM + c] : 0.f;
    Hs[gi][r * 256 + (c ^ ((r & 7) << 3))] = (_Float16)vx;
  }
  __syncthreads();

  // ---- 11 graph convolutions ----
  conv2x<3, false>(&Hs[0][0], &Tb[0][0], NmF, pk + PK_WIN_HI, pk + PK_WIN_LO, b_in, lane, wv);
  #pragma unroll 1
  for (int L = 0; L < GCR; ++L) {
    const _Float16* h1 = pk + PK_G_BASE + (size_t)L * PK_G_STRIDE;
    conv2x<8, true>(&Hs[0][0], &Tb[0][0], NmF, h1, h1 + 65536, b_g1 + L * HH, lane, wv);
    const _Float16* h2 = pk + PK_G_BASE + (size_t)(5 + L) * PK_G_STRIDE;
    conv2x<8, true>(&Hs[0][0], &Tb[0][0], NmF, h2, h2 + 65536, b_g2 + L * HH, lane, wv);
  }

  // ---- attention ----
  {
    const _Float16* Qhi = pk + PK_WQK_HI;
    const _Float16* Qlo = pk + PK_WQK_LO;
    const int sgi = wv >> 2, smt = (wv >> 1) & 1, snt = wv & 1;   // 8 waves -> 8 tiles
    float4_t sacc = (float4_t){0.f, 0.f, 0.f, 0.f};

    #pragma unroll
    for (int p = 0; p < 2; ++p) {
      const int nt = p * 8 + wv;
      // u' = h@Wqk for this wave's 16 cols
      float4_t uh[2][2], ul[2][2];
      #pragma unroll
      for (int a = 0; a < 2; ++a)
        #pragma unroll
        for (int b = 0; b < 2; ++b) {
          uh[a][b] = (float4_t){0.f, 0.f, 0.f, 0.f};
          ul[a][b] = (float4_t){0.f, 0.f, 0.f, 0.f};
        }
      #pragma unroll
      for (int ks = 0; ks < 8; ++ks) {
        const int off = ((nt * 8 + ks) * 64 + lane) * 8;
        const half8_t qh = *(const half8_t*)(Qhi + off);
        const half8_t ql = *(const half8_t*)(Qlo + off);
        const int j0 = ks * 32 + g4 * 8;
        #pragma unroll
        for (int gi = 0; gi < 2; ++gi)
          #pragma unroll
          for (int mt = 0; mt < 2; ++mt) {
            const half8_t ha = *(const half8_t*)(&Hs[gi][(mt * 16 + l15) * 256 + (j0 ^ sw)]);
            uh[gi][mt] = MF16(ha, qh, uh[gi][mt]);
            ul[gi][mt] = MF16(ha, ql, ul[gi][mt]);
          }
      }
      // write u' slice [n][128] swizzled into Tb (+tvec); col fixed per lane
      const float tv = tvec[nt * 16 + l15];
      const int cl = wv * 16 + l15;
      #pragma unroll
      for (int gi = 0; gi < 2; ++gi)
        #pragma unroll
        for (int mt = 0; mt < 2; ++mt)
          #pragma unroll
          for (int jj = 0; jj < 4; ++jj) {
            const int n = mt * 16 + 4 * g4 + jj;
            Tb[gi][n * 128 + (cl ^ ((n & 7) << 3))] =
                (_Float16)(uh[gi][mt][jj] + ul[gi][mt][jj] * LO_INV + tv);
          }
      __syncthreads();
      // S partial: wave -> (sgi, smt, snt)
      #pragma unroll
      for (int ksl = 0; ksl < 4; ++ksl) {
        const int kl = ksl * 32 + g4 * 8;
        const half8_t ua = *(const half8_t*)(&Tb[sgi][(smt * 16 + l15) * 128 + (kl ^ sw)]);
        const half8_t hb = *(const half8_t*)(&Hs[sgi][(snt * 16 + l15) * 256 + ((p * 128 + kl) ^ sw)]);
        sacc = MF16(ua, hb, sacc);
      }
      __syncthreads();
    }
    // S write (each wave owns a distinct (sgi, smt, snt) tile)
    #pragma unroll
    for (int jj = 0; jj < 4; ++jj)
      Sb[sgi][(smt * 16 + 4 * g4 + jj) * 33 + snt * 16 + l15] = sacc[jj];
  }

  // ---- v[m] = h[m].Wv + bv  (2 graphs x 32 rows x 8 lanes) ----
  {
    const int gi = tid >> 8, m = (tid >> 3) & 31, q = tid & 7;
    float s = 0.f;
    const int c0 = q * 32;
    for (int cc = 0; cc < 32; ++cc) {
      const int c = c0 + cc;
      s = fmaf((float)Hs[gi][m * 256 + (c ^ ((m & 7) << 3))], Wvp[c], s);
    }
    s += __shfl_xor(s, 1);
    s += __shfl_xor(s, 2);
    s += __shfl_xor(s, 4);
    if (q == 0) Sb[gi][1120 + m] = s + bv[0];
  }
  __syncthreads();

  // ---- row softmax fused with w = attn @ v ----
  if (tid < 64) {
    const int gi = tid >> 5, n = tid & 31;
    float mx = -1e30f;
    #pragma unroll 1
    for (int m = 0; m < NN; ++m) mx = fmaxf(mx, Sb[gi][n * 33 + m]);
    float se = 0.f, sv = 0.f;
    #pragma unroll 1
    for (int m = 0; m < NN; ++m) {
      const float e = expf(Sb[gi][n * 33 + m] - mx);
      se += e;
      sv = fmaf(e, Sb[gi][1120 + m], sv);
    }
    Sb[gi][1152 + n] = sv / se;
  }
  __syncthreads();

  // ---- feats = h^T @ w  (512 threads: one column each) ----
  {
    const int gi = tid >> 8, j = tid & 255;
    float f0 = 0.f;
    #pragma unroll
    for (int m = 0; m < NN; ++m) {
      const float w = Sb[gi][1152 + m];
      f0 = fmaf((float)Hs[gi][m * 256 + (j ^ ((m & 7) << 3))], w, f0);
    }
    F[(size_t)(ga + gi) * FDIM + j] = f0;
    if (tid < 4) {
      const int gg = tid >> 1;
      F[(size_t)(ga + gg) * FDIM + HH + (tid & 1)] = addf[(size_t)(ga + gg) * ADDD + (tid & 1)];
    }
  }
}

// ---------------------------------------------------------------------------
// Kernel 2: batched MLP (unchanged)
// ---------------------------------------------------------------------------
#define MR 8
__global__ __launch_bounds__(256, 2)
void mlp_kernel(const float* __restrict__ F,
                const float* __restrict__ W1, const float* __restrict__ b1,
                const float* __restrict__ W2, const float* __restrict__ b2,
                const float* __restrict__ W3, const float* __restrict__ b3,
                float* __restrict__ out)
{
  __shared__ float sm[MR * M1];
  const int tid = threadIdx.x;
  const int r0 = blockIdx.x * MR;

  for (int idx = tid; idx < MR * FDIM; idx += 256) {
    const int r = idx / FDIM, c = idx - r * FDIM;
    sm[r * 260 + c] = F[(size_t)(r0 + r) * FDIM + c];
  }
  __syncthreads();

  float a1[4][MR];
  #pragma unroll
  for (int qg = 0; qg < 4; ++qg)
    #pragma unroll
    for (int r = 0; r < MR; ++r) a1[qg][r] = 0.f;
  for (int i = 0; i < FDIM; ++i) {
    float w[4];
    #pragma unroll
    for (int qg = 0; qg < 4; ++qg) w[qg] = W1[(size_t)i * M1 + tid + 256 * qg];
    #pragma unroll
    for (int r = 0; r < MR; ++r) {
      const float fv = sm[r * 260 + i];
      #pragma unroll
      for (int qg = 0; qg < 4; ++qg) a1[qg][r] = fmaf(fv, w[qg], a1[qg][r]);
    }
  }
  __syncthreads();
  #pragma unroll
  for (int qg = 0; qg < 4; ++qg) {
    const float bb = b1[tid + 256 * qg];
    #pragma unroll
    for (int r = 0; r < MR; ++r) {
      const float z = a1[qg][r] + bb;
      sm[r * M1 + tid + 256 * qg] = fmaxf(z, 0.01f * z);
    }
  }
  __syncthreads();

  float a2[2][MR];
  #pragma unroll
  for (int qg = 0; qg < 2; ++qg)
    #pragma unroll
    for (int r = 0; r < MR; ++r) a2[qg][r] = 0.f;
  for (int i = 0; i < M1; ++i) {
    float w[2];
    #pragma unroll
    for (int qg = 0; qg < 2; ++qg) w[qg] = W2[(size_t)i * M2 + tid + 256 * qg];
    #pragma unroll
    for (int r = 0; r < MR; ++r) {
      const float zv = sm[r * M1 + i];
      #pragma unroll
      for (int qg = 0; qg < 2; ++qg) a2[qg][r] = fmaf(zv, w[qg], a2[qg][r]);
    }
  }
  __syncthreads();
  #pragma unroll
  for (int qg = 0; qg < 2; ++qg) {
    const float bb = b2[tid + 256 * qg];
    #pragma unroll
    for (int r = 0; r < MR; ++r) {
      const float z = a2[qg][r] + bb;
      sm[r * M2 + tid + 256 * qg] = fmaxf(z, 0.01f * z);
    }
  }
  __syncthreads();

  const int lane = tid & 63, wid = tid >> 6;
  float wreg[8];
  #pragma unroll
  for (int q = 0; q < 8; ++q) wreg[q] = W3[lane + 64 * q];
  #pragma unroll
  for (int rr = 0; rr < 2; ++rr) {
    const int r = wid * 2 + rr;
    float s = 0.f;
    #pragma unroll
    for (int q = 0; q < 8; ++q) s = fmaf(sm[r * M2 + lane + 64 * q], wreg[q], s);
    #pragma unroll
    for (int off = 32; off; off >>= 1) s += __shfl_down(s, off);
    if (lane == 0) out[r0 + r] = s + b3[0];
  }
}

// ---------------------------------------------------------------------------
extern "C" void kernel_launch(void* const* d_in, const int* in_sizes, int n_in,
                              void* d_out, int out_size, void* d_ws, size_t ws_size,
                              hipStream_t stream) {
  (void)in_sizes; (void)n_in; (void)out_size; (void)ws_size;
  const float* x    = (const float*)d_in[0];
  const float* addf = (const float*)d_in[1];
  const int*   src  = (const int*)d_in[2];
  const int*   dst  = (const int*)d_in[3];
  const float* W_in = (const float*)d_in[4];
  const float* b_in = (const float*)d_in[5];
  const float* W_g1 = (const float*)d_in[6];
  const float* b_g1 = (const float*)d_in[7];
  const float* W_g2 = (const float*)d_in[8];
  const float* b_g2 = (const float*)d_in[9];
  const float* Wq   = (const float*)d_in[10];
  const float* bq   = (const float*)d_in[11];
  const float* Wk   = (const float*)d_in[12];
  // d_in[13] = bk : cancels in softmax (row-constant), unused
  const float* Wv   = (const float*)d_in[14];
  const float* bv   = (const float*)d_in[15];
  const float* W1   = (const float*)d_in[16];
  const float* b1   = (const float*)d_in[17];
  const float* W2   = (const float*)d_in[18];
  const float* b2   = (const float*)d_in[19];
  const float* W3   = (const float*)d_in[20];
  const float* b3   = (const float*)d_in[21];
  float* out = (float*)d_out;

  float* F        = (float*)d_ws;
  float* wqkf     = (float*)((char*)d_ws + WS_WQK);
  float* tvec     = (float*)((char*)d_ws + WS_TVEC);
  _Float16* pk    = (_Float16*)((char*)d_ws + WS_PK);

  prep1_kernel<<<dim3(257), dim3(256), 0, stream>>>(Wq, Wk, bq, wqkf, tvec);
  prep2_kernel<<<dim3(364), dim3(256), 0, stream>>>(W_in, W_g1, W_g2, wqkf, pk);
  gnn_kernel<<<dim3(BB / 2), dim3(512), 0, stream>>>(
      x, addf, src, dst, b_in, b_g1, b_g2, Wv, bv, pk, tvec, F);
  mlp_kernel<<<dim3(BB / MR), dim3(256), 0, stream>>>(
      F, W1, b1, W2, b2, W3, b3, out);
}

// Round 10
// 490.480 us; speedup vs baseline: 2.4300x; 1.3638x over previous
//
#include <hip/hip_runtime.h>
#include <math.h>

#define BB     4096
#define NN     32
#define EE     64
#define INDIM  74
#define HH     256
#define GCR    5
#define M1     1024
#define M2     512
#define FDIM   258
#define ADDD   2

typedef __attribute__((ext_vector_type(8))) _Float16 half8_t;
typedef __attribute__((ext_vector_type(4))) float float4_t;

#define MF16(a, b, c) __builtin_amdgcn_mfma_f32_16x16x32_f16((a), (b), (c), 0, 0, 0)
#define LO_SCALE 1024.0f
#define LO_INV   (1.0f / 1024.0f)

// ---- ws layout (bytes) ----
#define WS_F      0               // F [4096][258] f32
#define WS_WQK    4227072         // Wqk fp32 [256][256]
#define WS_TVEC   4489216         // tvec fp32 [256]
#define WS_PK     4490240         // packed fp16 hi/lo fragments (lo now unused for W)
// packed offsets in _Float16 units from PK base:
#define PK_WIN_HI 0
#define PK_WIN_LO 24576
#define PK_G_BASE 49152
#define PK_G_STRIDE 131072
#define PK_WQK_HI 1359872
#define PK_WQK_LO (1359872 + 65536)

union H4 { unsigned long long u; _Float16 h[4]; };

// ---------------------------------------------------------------------------
// Prep 1: Wqk = Wq @ Wk^T (fp32), tvec = Wk @ bq
// ---------------------------------------------------------------------------
__global__ void prep1_kernel(const float* __restrict__ Wq, const float* __restrict__ Wk,
                             const float* __restrict__ bq,
                             float* __restrict__ wqkf, float* __restrict__ tvec) {
  const int i = blockIdx.x, j = threadIdx.x;
  if (i < 256) {
    __shared__ float qrow[256];
    qrow[j] = Wq[i * 256 + j];
    __syncthreads();
    float s = 0.f;
    for (int c = 0; c < 256; ++c) s = fmaf(qrow[c], Wk[j * 256 + c], s);
    wqkf[i * 256 + j] = s;
  } else {
    float s = 0.f;
    for (int c = 0; c < 256; ++c) s = fmaf(Wk[j * 256 + c], bq[c], s);
    tvec[j] = s;
  }
}

// ---------------------------------------------------------------------------
// Prep 2: pack weights into MFMA B-fragment order, fp16 hi + (lo * 2^10).
// (lo halves still produced; GNN kernel reads hi only since round 10.)
// ---------------------------------------------------------------------------
template<int KS, int KREAL>
__device__ __forceinline__ void pack_one(const float* __restrict__ S,
                                         _Float16* __restrict__ hi,
                                         _Float16* __restrict__ lo, int local) {
  const int l = local & 63;
  const int nk = local >> 6;
  const int ks = nk % KS;
  const int nt = nk / KS;
  const int j = nt * 16 + (l & 15);
  const int kbase = ks * 32 + (l >> 4) * 8;
  half8_t h8, l8;
  #pragma unroll
  for (int i = 0; i < 8; ++i) {
    const int k = kbase + i;
    const float v = (k < KREAL) ? S[k * 256 + j] : 0.f;
    const _Float16 hb = (_Float16)v;
    h8[i] = hb;
    l8[i] = (_Float16)((v - (float)hb) * LO_SCALE);
  }
  *(half8_t*)(hi + (size_t)local * 8) = h8;
  *(half8_t*)(lo + (size_t)local * 8) = l8;
}

__global__ void prep2_kernel(const float* __restrict__ W_in,
                             const float* __restrict__ W_g1, const float* __restrict__ W_g2,
                             const float* __restrict__ wqkf, _Float16* __restrict__ pk) {
  const int cid = blockIdx.x * 256 + threadIdx.x;
  if (cid < 3072) {
    pack_one<3, 74>(W_in, pk + PK_WIN_HI, pk + PK_WIN_LO, cid);
  } else {
    const int m = (cid - 3072) >> 13;               // 0..10
    const int local = (cid - 3072) & 8191;
    _Float16* hi; const float* S;
    if (m < 10) {
      hi = pk + PK_G_BASE + (size_t)m * PK_G_STRIDE;
      S = (m < 5) ? (W_g1 + (size_t)m * 65536) : (W_g2 + (size_t)(m - 5) * 65536);
    } else {
      hi = pk + PK_WQK_HI;
      S = wqkf;
    }
    pack_one<8, 256>(S, hi, hi + 65536, local);
  }
}

// ---------------------------------------------------------------------------
// conv for 2 graphs, 8 waves. Single-fp16 W (hi only); Nmat keeps hi/lo.
//   phase0: MFMA1 -> Tstore -> MFMA2 -> hold0 (4 u64)
//   phase1: MFMA1 (old H) ; barrier ; write hold0 ; Tstore ; MFMA2 -> H direct
// 2 barriers/conv. Hs layout: n*256 + (j ^ ((n&7)<<3)).
// T layout: wv*512 + ((k>>3)*16+c)*8 + (k&7), wave-private.
// ---------------------------------------------------------------------------
template<int KS, bool RELU>
__device__ __forceinline__ void conv2x(
    _Float16* Hs, _Float16* Tb, const _Float16* NmF,
    const _Float16* __restrict__ Whi,
    const float* __restrict__ bias,
    int lane, int wv)
{
  const int g4 = lane >> 4, l15 = lane & 15;
  const int sw = (l15 & 7) << 3;

  float4_t th[2][2];
  unsigned long long hold0[2][2];

  // ================= phase 0 =================
  #pragma unroll
  for (int a = 0; a < 2; ++a)
    #pragma unroll
    for (int b = 0; b < 2; ++b)
      th[a][b] = (float4_t){0.f, 0.f, 0.f, 0.f};
  #pragma unroll
  for (int ks = 0; ks < KS; ++ks) {
    const int off = ((wv * KS + ks) * 64 + lane) * 8;
    const half8_t wh = *(const half8_t*)(Whi + off);
    const int j0 = ks * 32 + g4 * 8;
    #pragma unroll
    for (int gi = 0; gi < 2; ++gi)
      #pragma unroll
      for (int mt = 0; mt < 2; ++mt) {
        const half8_t ha = *(const half8_t*)(Hs + (gi << 13) + ((mt * 16 + l15) * 256 + (j0 ^ sw)));
        th[gi][mt] = MF16(ha, wh, th[gi][mt]);
      }
  }
  #pragma unroll
  for (int gi = 0; gi < 2; ++gi)
    #pragma unroll
    for (int mt = 0; mt < 2; ++mt) {
      const int r0 = mt * 16 + 4 * g4;
      H4 pk4;
      #pragma unroll
      for (int jj = 0; jj < 4; ++jj)
        pk4.h[jj] = (_Float16)th[gi][mt][jj];
      const int idx = wv * 512 + ((r0 >> 3) * 16 + l15) * 8 + (r0 & 7);
      *(unsigned long long*)(Tb + (gi << 12) + idx) = pk4.u;
    }
  {
    const float4 b4 = *(const float4*)&bias[wv * 16 + 4 * g4];
    #pragma unroll
    for (int gi = 0; gi < 2; ++gi) {
      const half8_t ta = *(const half8_t*)(Tb + (gi << 12) + wv * 512 + lane * 8);
      #pragma unroll
      for (int nt2 = 0; nt2 < 2; ++nt2) {
        const int nmo = ((gi * 2 + nt2) * 64 + lane) * 8;
        const half8_t nmh = *(const half8_t*)(NmF + nmo);
        const half8_t nml = *(const half8_t*)(NmF + 2048 + nmo);
        const float4_t dh = MF16(ta, nmh, ((float4_t){0.f, 0.f, 0.f, 0.f}));
        const float4_t dl = MF16(ta, nml, ((float4_t){0.f, 0.f, 0.f, 0.f}));
        H4 pk4;
        #pragma unroll
        for (int jj = 0; jj < 4; ++jj) {
          float v = dh[jj] + dl[jj] * LO_INV + ((const float*)&b4)[jj];
          if (RELU) v = fmaxf(v, 0.f);
          pk4.h[jj] = (_Float16)v;
        }
        hold0[gi][nt2] = pk4.u;
      }
    }
  }

  // ================= phase 1: MFMA1 only (old H) =================
  #pragma unroll
  for (int a = 0; a < 2; ++a)
    #pragma unroll
    for (int b = 0; b < 2; ++b)
      th[a][b] = (float4_t){0.f, 0.f, 0.f, 0.f};
  #pragma unroll
  for (int ks = 0; ks < KS; ++ks) {
    const int off = (((8 + wv) * KS + ks) * 64 + lane) * 8;
    const half8_t wh = *(const half8_t*)(Whi + off);
    const int j0 = ks * 32 + g4 * 8;
    #pragma unroll
    for (int gi = 0; gi < 2; ++gi)
      #pragma unroll
      for (int mt = 0; mt < 2; ++mt) {
        const half8_t ha = *(const half8_t*)(Hs + (gi << 13) + ((mt * 16 + l15) * 256 + (j0 ^ sw)));
        th[gi][mt] = MF16(ha, wh, th[gi][mt]);
      }
  }

  __syncthreads();   // ALL waves' H reads (both phases) complete

  // write phase-0 results
  {
    const int j0 = wv * 16 + 4 * g4;
    #pragma unroll
    for (int gi = 0; gi < 2; ++gi)
      #pragma unroll
      for (int nt2 = 0; nt2 < 2; ++nt2) {
        const int n = nt2 * 16 + l15;
        *(unsigned long long*)(Hs + (gi << 13) + (n * 256 + (j0 ^ ((n & 7) << 3)))) =
            hold0[gi][nt2];
      }
  }
  // phase-1 T store + MFMA2, write h' directly
  #pragma unroll
  for (int gi = 0; gi < 2; ++gi)
    #pragma unroll
    for (int mt = 0; mt < 2; ++mt) {
      const int r0 = mt * 16 + 4 * g4;
      H4 pk4;
      #pragma unroll
      for (int jj = 0; jj < 4; ++jj)
        pk4.h[jj] = (_Float16)th[gi][mt][jj];
      const int idx = wv * 512 + ((r0 >> 3) * 16 + l15) * 8 + (r0 & 7);
      *(unsigned long long*)(Tb + (gi << 12) + idx) = pk4.u;
    }
  {
    const float4 b4 = *(const float4*)&bias[(8 + wv) * 16 + 4 * g4];
    const int j0 = (8 + wv) * 16 + 4 * g4;
    #pragma unroll
    for (int gi = 0; gi < 2; ++gi) {
      const half8_t ta = *(const half8_t*)(Tb + (gi << 12) + wv * 512 + lane * 8);
      #pragma unroll
      for (int nt2 = 0; nt2 < 2; ++nt2) {
        const int nmo = ((gi * 2 + nt2) * 64 + lane) * 8;
        const half8_t nmh = *(const half8_t*)(NmF + nmo);
        const half8_t nml = *(const half8_t*)(NmF + 2048 + nmo);
        const float4_t dh = MF16(ta, nmh, ((float4_t){0.f, 0.f, 0.f, 0.f}));
        const float4_t dl = MF16(ta, nml, ((float4_t){0.f, 0.f, 0.f, 0.f}));
        H4 pk4;
        #pragma unroll
        for (int jj = 0; jj < 4; ++jj) {
          float v = dh[jj] + dl[jj] * LO_INV + ((const float*)&b4)[jj];
          if (RELU) v = fmaxf(v, 0.f);
          pk4.h[jj] = (_Float16)v;
        }
        const int n = nt2 * 16 + l15;
        *(unsigned long long*)(Hs + (gi << 13) + (n * 256 + (j0 ^ ((n & 7) << 3)))) = pk4.u;
      }
    }
  }
  __syncthreads();   // new h visible
}

// ---------------------------------------------------------------------------
// GNN kernel: 2 graphs per block, 512 threads (8 waves).
// LDS: Hs 32KB + Tb 16KB + NmF 8KB + Sb 2x4.6KB = 65.5 KB -> 2 blocks/CU
// if total regs/wave <= 128 (round-10 diet: single-fp16 W, th-only acc).
// ---------------------------------------------------------------------------
__global__ __launch_bounds__(512, 2)
void gnn_kernel(const float* __restrict__ x, const float* __restrict__ addf,
                const int* __restrict__ src, const int* __restrict__ dst,
                const float* __restrict__ b_in,
                const float* __restrict__ b_g1, const float* __restrict__ b_g2,
                const float* __restrict__ Wvp, const float* __restrict__ bv,
                const _Float16* __restrict__ pk,
                const float* __restrict__ tvec,
                float* __restrict__ F)
{
  __shared__ __align__(16) _Float16 Hs[2][8192];
  __shared__ __align__(16) _Float16 Tb[2][4096];
  __shared__ __align__(16) _Float16 NmF[4096];
  __shared__ float Sb[2][1184];

  const int tid = threadIdx.x;
  const int lane = tid & 63;
  const int wv = tid >> 6;            // 0..7
  const int g4 = lane >> 4, l15 = lane & 15;
  const int sw = (l15 & 7) << 3;
  const int ga = blockIdx.x * 2;

  // ---- build Nmat = diag(inorm) . A_adj . diag(onorm) for both graphs ----
  for (int i = tid; i < 2048; i += 512) Sb[i >> 10][i & 1023] = 0.f;
  __syncthreads();
  if (tid < 128) {
    const int gi = tid >> 6, e = tid & 63;
    const int es = src[(size_t)(ga + gi) * EE + e];
    const int ed = dst[(size_t)(ga + gi) * EE + e];
    atomicAdd(&Sb[gi][ed * 32 + es], 1.0f);
  }
  __syncthreads();
  if (tid < 64) {                       // inorm = rsqrt(row sums)
    const int gi = tid >> 5, n = tid & 31;
    float s = 0.f;
    for (int m = 0; m < NN; ++m) s += Sb[gi][n * 32 + m];
    Sb[gi][1056 + n] = 1.f / sqrtf(fmaxf(s, 1.f));
  } else if (tid < 128) {               // onorm = rsqrt(col sums)
    const int gi = (tid - 64) >> 5, n = tid & 31;
    float s = 0.f;
    for (int m = 0; m < NN; ++m) s += Sb[gi][m * 32 + n];
    Sb[gi][1088 + n] = 1.f / sqrtf(fmaxf(s, 1.f));
  }
  __syncthreads();
  for (int i = tid; i < 2048; i += 512) {
    const int gi = i >> 10, idx = i & 1023;
    Sb[gi][idx] *= Sb[gi][1056 + (idx >> 5)] * Sb[gi][1088 + (idx & 31)];
  }
  __syncthreads();

  // ---- Nmat B-fragments (hi + lo*2^10) into NmF LDS (wave 0 builds) ----
  if (wv == 0) {
    #pragma unroll
    for (int gi = 0; gi < 2; ++gi) {
      #pragma unroll
      for (int nt2 = 0; nt2 < 2; ++nt2) {
        half8_t h8, l8;
        #pragma unroll
        for (int i = 0; i < 8; ++i) {
          const float v = Sb[gi][(nt2 * 16 + l15) * 32 + g4 * 8 + i];
          const _Float16 hb = (_Float16)v;
          h8[i] = hb;
          l8[i] = (_Float16)((v - (float)hb) * LO_SCALE);
        }
        const int nmo = ((gi * 2 + nt2) * 64 + lane) * 8;
        *(half8_t*)(NmF + nmo) = h8;
        *(half8_t*)(NmF + 2048 + nmo) = l8;
      }
    }
  }

  // ---- stage x (fp16, cols 74..95 zero) ----
  for (int i = tid; i < 2 * NN * 96; i += 512) {
    const int gi = i / 3072, rem = i - gi * 3072;
    const int r = rem / 96, c = rem - r * 96;
    const float vx = (c < INDIM) ? x[(size_t)(ga + gi) * (NN * INDIM) + r * INDIM + c] : 0.f;
    Hs[gi][r * 256 + (c ^ ((r & 7) << 3))] = (_Float16)vx;
  }
  __syncthreads();

  // ---- 11 graph convolutions ----
  conv2x<3, false>(&Hs[0][0], &Tb[0][0], NmF, pk + PK_WIN_HI, b_in, lane, wv);
  #pragma unroll 1
  for (int L = 0; L < GCR; ++L) {
    conv2x<8, true>(&Hs[0][0], &Tb[0][0], NmF,
                    pk + PK_G_BASE + (size_t)L * PK_G_STRIDE, b_g1 + L * HH, lane, wv);
    conv2x<8, true>(&Hs[0][0], &Tb[0][0], NmF,
                    pk + PK_G_BASE + (size_t)(5 + L) * PK_G_STRIDE, b_g2 + L * HH, lane, wv);
  }

  // ---- attention ----
  {
    const _Float16* Qhi = pk + PK_WQK_HI;
    const int sgi = wv >> 2, smt = (wv >> 1) & 1, snt = wv & 1;   // 8 waves -> 8 tiles
    float4_t sacc = (float4_t){0.f, 0.f, 0.f, 0.f};

    #pragma unroll
    for (int p = 0; p < 2; ++p) {
      const int nt = p * 8 + wv;
      // u' = h@Wqk for this wave's 16 cols (single-fp16 Wqk)
      float4_t uh[2][2];
      #pragma unroll
      for (int a = 0; a < 2; ++a)
        #pragma unroll
        for (int b = 0; b < 2; ++b)
          uh[a][b] = (float4_t){0.f, 0.f, 0.f, 0.f};
      #pragma unroll
      for (int ks = 0; ks < 8; ++ks) {
        const int off = ((nt * 8 + ks) * 64 + lane) * 8;
        const half8_t qh = *(const half8_t*)(Qhi + off);
        const int j0 = ks * 32 + g4 * 8;
        #pragma unroll
        for (int gi = 0; gi < 2; ++gi)
          #pragma unroll
          for (int mt = 0; mt < 2; ++mt) {
            const half8_t ha = *(const half8_t*)(&Hs[gi][(mt * 16 + l15) * 256 + (j0 ^ sw)]);
            uh[gi][mt] = MF16(ha, qh, uh[gi][mt]);
          }
      }
      // write u' slice [n][128] swizzled into Tb (+tvec); col fixed per lane
      const float tv = tvec[nt * 16 + l15];
      const int cl = wv * 16 + l15;
      #pragma unroll
      for (int gi = 0; gi < 2; ++gi)
        #pragma unroll
        for (int mt = 0; mt < 2; ++mt)
          #pragma unroll
          for (int jj = 0; jj < 4; ++jj) {
            const int n = mt * 16 + 4 * g4 + jj;
            Tb[gi][n * 128 + (cl ^ ((n & 7) << 3))] =
                (_Float16)(uh[gi][mt][jj] + tv);
          }
      __syncthreads();
      // S partial: wave -> (sgi, smt, snt)
      #pragma unroll
      for (int ksl = 0; ksl < 4; ++ksl) {
        const int kl = ksl * 32 + g4 * 8;
        const half8_t ua = *(const half8_t*)(&Tb[sgi][(smt * 16 + l15) * 128 + (kl ^ sw)]);
        const half8_t hb = *(const half8_t*)(&Hs[sgi][(snt * 16 + l15) * 256 + ((p * 128 + kl) ^ sw)]);
        sacc = MF16(ua, hb, sacc);
      }
      __syncthreads();
    }
    // S write (each wave owns a distinct (sgi, smt, snt) tile)
    #pragma unroll
    for (int jj = 0; jj < 4; ++jj)
      Sb[sgi][(smt * 16 + 4 * g4 + jj) * 33 + snt * 16 + l15] = sacc[jj];
  }

  // ---- v[m] = h[m].Wv + bv  (2 graphs x 32 rows x 8 lanes) ----
  {
    const int gi = tid >> 8, m = (tid >> 3) & 31, q = tid & 7;
    float s = 0.f;
    const int c0 = q * 32;
    for (int cc = 0; cc < 32; ++cc) {
      const int c = c0 + cc;
      s = fmaf((float)Hs[gi][m * 256 + (c ^ ((m & 7) << 3))], Wvp[c], s);
    }
    s += __shfl_xor(s, 1);
    s += __shfl_xor(s, 2);
    s += __shfl_xor(s, 4);
    if (q == 0) Sb[gi][1120 + m] = s + bv[0];
  }
  __syncthreads();

  // ---- row softmax fused with w = attn @ v ----
  if (tid < 64) {
    const int gi = tid >> 5, n = tid & 31;
    float mx = -1e30f;
    #pragma unroll 1
    for (int m = 0; m < NN; ++m) mx = fmaxf(mx, Sb[gi][n * 33 + m]);
    float se = 0.f, sv = 0.f;
    #pragma unroll 1
    for (int m = 0; m < NN; ++m) {
      const float e = expf(Sb[gi][n * 33 + m] - mx);
      se += e;
      sv = fmaf(e, Sb[gi][1120 + m], sv);
    }
    Sb[gi][1152 + n] = sv / se;
  }
  __syncthreads();

  // ---- feats = h^T @ w  (512 threads: one column each) ----
  {
    const int gi = tid >> 8, j = tid & 255;
    float f0 = 0.f;
    #pragma unroll
    for (int m = 0; m < NN; ++m) {
      const float w = Sb[gi][1152 + m];
      f0 = fmaf((float)Hs[gi][m * 256 + (j ^ ((m & 7) << 3))], w, f0);
    }
    F[(size_t)(ga + gi) * FDIM + j] = f0;
    if (tid < 4) {
      const int gg = tid >> 1;
      F[(size_t)(ga + gg) * FDIM + HH + (tid & 1)] = addf[(size_t)(ga + gg) * ADDD + (tid & 1)];
    }
  }
}

// ---------------------------------------------------------------------------
// Kernel 2: batched MLP (unchanged)
// ---------------------------------------------------------------------------
#define MR 8
__global__ __launch_bounds__(256, 2)
void mlp_kernel(const float* __restrict__ F,
                const float* __restrict__ W1, const float* __restrict__ b1,
                const float* __restrict__ W2, const float* __restrict__ b2,
                const float* __restrict__ W3, const float* __restrict__ b3,
                float* __restrict__ out)
{
  __shared__ float sm[MR * M1];
  const int tid = threadIdx.x;
  const int r0 = blockIdx.x * MR;

  for (int idx = tid; idx < MR * FDIM; idx += 256) {
    const int r = idx / FDIM, c = idx - r * FDIM;
    sm[r * 260 + c] = F[(size_t)(r0 + r) * FDIM + c];
  }
  __syncthreads();

  float a1[4][MR];
  #pragma unroll
  for (int qg = 0; qg < 4; ++qg)
    #pragma unroll
    for (int r = 0; r < MR; ++r) a1[qg][r] = 0.f;
  for (int i = 0; i < FDIM; ++i) {
    float w[4];
    #pragma unroll
    for (int qg = 0; qg < 4; ++qg) w[qg] = W1[(size_t)i * M1 + tid + 256 * qg];
    #pragma unroll
    for (int r = 0; r < MR; ++r) {
      const float fv = sm[r * 260 + i];
      #pragma unroll
      for (int qg = 0; qg < 4; ++qg) a1[qg][r] = fmaf(fv, w[qg], a1[qg][r]);
    }
  }
  __syncthreads();
  #pragma unroll
  for (int qg = 0; qg < 4; ++qg) {
    const float bb = b1[tid + 256 * qg];
    #pragma unroll
    for (int r = 0; r < MR; ++r) {
      const float z = a1[qg][r] + bb;
      sm[r * M1 + tid + 256 * qg] = fmaxf(z, 0.01f * z);
    }
  }
  __syncthreads();

  float a2[2][MR];
  #pragma unroll
  for (int qg = 0; qg < 2; ++qg)
    #pragma unroll
    for (int r = 0; r < MR; ++r) a2[qg][r] = 0.f;
  for (int i = 0; i < M1; ++i) {
    float w[2];
    #pragma unroll
    for (int qg = 0; qg < 2; ++qg) w[qg] = W2[(size_t)i * M2 + tid + 256 * qg];
    #pragma unroll
    for (int r = 0; r < MR; ++r) {
      const float zv = sm[r * M1 + i];
      #pragma unroll
      for (int qg = 0; qg < 2; ++qg) a2[qg][r] = fmaf(zv, w[qg], a2[qg][r]);
    }
  }
  __syncthreads();
  #pragma unroll
  for (int qg = 0; qg < 2; ++qg) {
    const float bb = b2[tid + 256 * qg];
    #pragma unroll
    for (int r = 0; r < MR; ++r) {
      const float z = a2[qg][r] + bb;
      sm[r * M2 + tid + 256 * qg] = fmaxf(z, 0.01f * z);
    }
  }
  __syncthreads();

  const int lane = tid & 63, wid = tid >> 6;
  float wreg[8];
  #pragma unroll
  for (int q = 0; q < 8; ++q) wreg[q] = W3[lane + 64 * q];
  #pragma unroll
  for (int rr = 0; rr < 2; ++rr) {
    const int r = wid * 2 + rr;
    float s = 0.f;
    #pragma unroll
    for (int q = 0; q < 8; ++q) s = fmaf(sm[r * M2 + lane + 64 * q], wreg[q], s);
    #pragma unroll
    for (int off = 32; off; off >>= 1) s += __shfl_down(s, off);
    if (lane == 0) out[r0 + r] = s + b3[0];
  }
}

// ---------------------------------------------------------------------------
extern "C" void kernel_launch(void* const* d_in, const int* in_sizes, int n_in,
                              void* d_out, int out_size, void* d_ws, size_t ws_size,
                              hipStream_t stream) {
  (void)in_sizes; (void)n_in; (void)out_size; (void)ws_size;
  const float* x    = (const float*)d_in[0];
  const float* addf = (const float*)d_in[1];
  const int*   src  = (const int*)d_in[2];
  const int*   dst  = (const int*)d_in[3];
  const float* W_in = (const float*)d_in[4];
  const float* b_in = (const float*)d_in[5];
  const float* W_g1 = (const float*)d_in[6];
  const float* b_g1 = (const float*)d_in[7];
  const float* W_g2 = (const float*)d_in[8];
  const float* b_g2 = (const float*)d_in[9];
  const float* Wq   = (const float*)d_in[10];
  const float* bq   = (const float*)d_in[11];
  const float* Wk   = (const float*)d_in[12];
  // d_in[13] = bk : cancels in softmax (row-constant), unused
  const float* Wv   = (const float*)d_in[14];
  const float* bv   = (const float*)d_in[15];
  const float* W1   = (const float*)d_in[16];
  const float* b1   = (const float*)d_in[17];
  const float* W2   = (const float*)d_in[18];
  const float* b2   = (const float*)d_in[19];
  const float* W3   = (const float*)d_in[20];
  const float* b3   = (const float*)d_in[21];
  float* out = (float*)d_out;

  float* F        = (float*)d_ws;
  float* wqkf     = (float*)((char*)d_ws + WS_WQK);
  float* tvec     = (float*)((char*)d_ws + WS_TVEC);
  _Float16* pk    = (_Float16*)((char*)d_ws + WS_PK);

  prep1_kernel<<<dim3(257), dim3(256), 0, stream>>>(Wq, Wk, bq, wqkf, tvec);
  prep2_kernel<<<dim3(364), dim3(256), 0, stream>>>(W_in, W_g1, W_g2, wqkf, pk);
  gnn_kernel<<<dim3(BB / 2), dim3(512), 0, stream>>>(
      x, addf, src, dst, b_in, b_g1, b_g2, Wv, bv, pk, tvec, F);
  mlp_kernel<<<dim3(BB / MR), dim3(256), 0, stream>>>(
      F, W1, b1, W2, b2, W3, b3, out);
}

// Round 11
// 412.136 us; speedup vs baseline: 2.8919x; 1.1901x over previous
//
#include <hip/hip_runtime.h>
#include <math.h>

#define BB     4096
#define NN     32
#define EE     64
#define INDIM  74
#define HH     256
#define GCR    5
#define M1     1024
#define M2     512
#define FDIM   258
#define ADDD   2

typedef __attribute__((ext_vector_type(8))) _Float16 half8_t;
typedef __attribute__((ext_vector_type(4))) float float4_t;

#define MF16(a, b, c) __builtin_amdgcn_mfma_f32_16x16x32_f16((a), (b), (c), 0, 0, 0)
#define LO_SCALE 1024.0f
#define LO_INV   (1.0f / 1024.0f)

// ---- ws layout (bytes) ----
#define WS_F      0               // F [4096][258] f32
#define WS_WQK    4227072         // Wqk fp32 [256][256]
#define WS_TVEC   4489216         // tvec fp32 [256]
#define WS_PK     4490240         // packed fp16 hi/lo fragments (lo unused for W)
// packed offsets in _Float16 units from PK base:
#define PK_WIN_HI 0
#define PK_WIN_LO 24576
#define PK_G_BASE 49152
#define PK_G_STRIDE 131072
#define PK_WQK_HI 1359872
#define PK_WQK_LO (1359872 + 65536)

union H4 { unsigned long long u; _Float16 h[4]; };

// ---------------------------------------------------------------------------
// Prep 1: Wqk = Wq @ Wk^T (fp32), tvec = Wk @ bq
// ---------------------------------------------------------------------------
__global__ void prep1_kernel(const float* __restrict__ Wq, const float* __restrict__ Wk,
                             const float* __restrict__ bq,
                             float* __restrict__ wqkf, float* __restrict__ tvec) {
  const int i = blockIdx.x, j = threadIdx.x;
  if (i < 256) {
    __shared__ float qrow[256];
    qrow[j] = Wq[i * 256 + j];
    __syncthreads();
    float s = 0.f;
    for (int c = 0; c < 256; ++c) s = fmaf(qrow[c], Wk[j * 256 + c], s);
    wqkf[i * 256 + j] = s;
  } else {
    float s = 0.f;
    for (int c = 0; c < 256; ++c) s = fmaf(Wk[j * 256 + c], bq[c], s);
    tvec[j] = s;
  }
}

// ---------------------------------------------------------------------------
// Prep 2: pack weights into MFMA B-fragment order, fp16 hi + (lo * 2^10).
// (lo halves still produced; GNN kernel reads hi only since round 10.)
// ---------------------------------------------------------------------------
template<int KS, int KREAL>
__device__ __forceinline__ void pack_one(const float* __restrict__ S,
                                         _Float16* __restrict__ hi,
                                         _Float16* __restrict__ lo, int local) {
  const int l = local & 63;
  const int nk = local >> 6;
  const int ks = nk % KS;
  const int nt = nk / KS;
  const int j = nt * 16 + (l & 15);
  const int kbase = ks * 32 + (l >> 4) * 8;
  half8_t h8, l8;
  #pragma unroll
  for (int i = 0; i < 8; ++i) {
    const int k = kbase + i;
    const float v = (k < KREAL) ? S[k * 256 + j] : 0.f;
    const _Float16 hb = (_Float16)v;
    h8[i] = hb;
    l8[i] = (_Float16)((v - (float)hb) * LO_SCALE);
  }
  *(half8_t*)(hi + (size_t)local * 8) = h8;
  *(half8_t*)(lo + (size_t)local * 8) = l8;
}

__global__ void prep2_kernel(const float* __restrict__ W_in,
                             const float* __restrict__ W_g1, const float* __restrict__ W_g2,
                             const float* __restrict__ wqkf, _Float16* __restrict__ pk) {
  const int cid = blockIdx.x * 256 + threadIdx.x;
  if (cid < 3072) {
    pack_one<3, 74>(W_in, pk + PK_WIN_HI, pk + PK_WIN_LO, cid);
  } else {
    const int m = (cid - 3072) >> 13;               // 0..10
    const int local = (cid - 3072) & 8191;
    _Float16* hi; const float* S;
    if (m < 10) {
      hi = pk + PK_G_BASE + (size_t)m * PK_G_STRIDE;
      S = (m < 5) ? (W_g1 + (size_t)m * 65536) : (W_g2 + (size_t)(m - 5) * 65536);
    } else {
      hi = pk + PK_WQK_HI;
      S = wqkf;
    }
    pack_one<8, 256>(S, hi, hi + 65536, local);
  }
}

// ---------------------------------------------------------------------------
// conv for 2 graphs, 8 waves. Single-fp16 W (hi only); Nmat keeps hi/lo.
//   phase0: MFMA1 -> Tstore -> MFMA2 -> hold0 (4 u64)
//   phase1: MFMA1 (old H) ; barrier ; write hold0 ; Tstore ; MFMA2 -> H direct
// 2 barriers/conv. Hs layout: n*256 + (j ^ ((n&7)<<3)).
// T layout: wv*512 + ((k>>3)*16+c)*8 + (k&7), wave-private.
// ---------------------------------------------------------------------------
template<int KS, bool RELU>
__device__ __forceinline__ void conv2x(
    _Float16* Hs, _Float16* Tb, const _Float16* NmF,
    const _Float16* __restrict__ Whi,
    const float* __restrict__ bias,
    int lane, int wv)
{
  const int g4 = lane >> 4, l15 = lane & 15;
  const int sw = (l15 & 7) << 3;

  float4_t th[2][2];
  unsigned long long hold0[2][2];

  // ================= phase 0 =================
  #pragma unroll
  for (int a = 0; a < 2; ++a)
    #pragma unroll
    for (int b = 0; b < 2; ++b)
      th[a][b] = (float4_t){0.f, 0.f, 0.f, 0.f};
  #pragma unroll
  for (int ks = 0; ks < KS; ++ks) {
    const int off = ((wv * KS + ks) * 64 + lane) * 8;
    const half8_t wh = *(const half8_t*)(Whi + off);
    const int j0 = ks * 32 + g4 * 8;
    #pragma unroll
    for (int gi = 0; gi < 2; ++gi)
      #pragma unroll
      for (int mt = 0; mt < 2; ++mt) {
        const half8_t ha = *(const half8_t*)(Hs + (gi << 13) + ((mt * 16 + l15) * 256 + (j0 ^ sw)));
        th[gi][mt] = MF16(ha, wh, th[gi][mt]);
      }
  }
  #pragma unroll
  for (int gi = 0; gi < 2; ++gi)
    #pragma unroll
    for (int mt = 0; mt < 2; ++mt) {
      const int r0 = mt * 16 + 4 * g4;
      H4 pk4;
      #pragma unroll
      for (int jj = 0; jj < 4; ++jj)
        pk4.h[jj] = (_Float16)th[gi][mt][jj];
      const int idx = wv * 512 + ((r0 >> 3) * 16 + l15) * 8 + (r0 & 7);
      *(unsigned long long*)(Tb + (gi << 12) + idx) = pk4.u;
    }
  {
    const float4 b4 = *(const float4*)&bias[wv * 16 + 4 * g4];
    #pragma unroll
    for (int gi = 0; gi < 2; ++gi) {
      const half8_t ta = *(const half8_t*)(Tb + (gi << 12) + wv * 512 + lane * 8);
      #pragma unroll
      for (int nt2 = 0; nt2 < 2; ++nt2) {
        const int nmo = ((gi * 2 + nt2) * 64 + lane) * 8;
        const half8_t nmh = *(const half8_t*)(NmF + nmo);
        const half8_t nml = *(const half8_t*)(NmF + 2048 + nmo);
        const float4_t dh = MF16(ta, nmh, ((float4_t){0.f, 0.f, 0.f, 0.f}));
        const float4_t dl = MF16(ta, nml, ((float4_t){0.f, 0.f, 0.f, 0.f}));
        H4 pk4;
        #pragma unroll
        for (int jj = 0; jj < 4; ++jj) {
          float v = dh[jj] + dl[jj] * LO_INV + ((const float*)&b4)[jj];
          if (RELU) v = fmaxf(v, 0.f);
          pk4.h[jj] = (_Float16)v;
        }
        hold0[gi][nt2] = pk4.u;
      }
    }
  }

  // ================= phase 1: MFMA1 only (old H) =================
  #pragma unroll
  for (int a = 0; a < 2; ++a)
    #pragma unroll
    for (int b = 0; b < 2; ++b)
      th[a][b] = (float4_t){0.f, 0.f, 0.f, 0.f};
  #pragma unroll
  for (int ks = 0; ks < KS; ++ks) {
    const int off = (((8 + wv) * KS + ks) * 64 + lane) * 8;
    const half8_t wh = *(const half8_t*)(Whi + off);
    const int j0 = ks * 32 + g4 * 8;
    #pragma unroll
    for (int gi = 0; gi < 2; ++gi)
      #pragma unroll
      for (int mt = 0; mt < 2; ++mt) {
        const half8_t ha = *(const half8_t*)(Hs + (gi << 13) + ((mt * 16 + l15) * 256 + (j0 ^ sw)));
        th[gi][mt] = MF16(ha, wh, th[gi][mt]);
      }
  }

  __syncthreads();   // ALL waves' H reads (both phases) complete

  // write phase-0 results
  {
    const int j0 = wv * 16 + 4 * g4;
    #pragma unroll
    for (int gi = 0; gi < 2; ++gi)
      #pragma unroll
      for (int nt2 = 0; nt2 < 2; ++nt2) {
        const int n = nt2 * 16 + l15;
        *(unsigned long long*)(Hs + (gi << 13) + (n * 256 + (j0 ^ ((n & 7) << 3)))) =
            hold0[gi][nt2];
      }
  }
  // phase-1 T store + MFMA2, write h' directly
  #pragma unroll
  for (int gi = 0; gi < 2; ++gi)
    #pragma unroll
    for (int mt = 0; mt < 2; ++mt) {
      const int r0 = mt * 16 + 4 * g4;
      H4 pk4;
      #pragma unroll
      for (int jj = 0; jj < 4; ++jj)
        pk4.h[jj] = (_Float16)th[gi][mt][jj];
      const int idx = wv * 512 + ((r0 >> 3) * 16 + l15) * 8 + (r0 & 7);
      *(unsigned long long*)(Tb + (gi << 12) + idx) = pk4.u;
    }
  {
    const float4 b4 = *(const float4*)&bias[(8 + wv) * 16 + 4 * g4];
    const int j0 = (8 + wv) * 16 + 4 * g4;
    #pragma unroll
    for (int gi = 0; gi < 2; ++gi) {
      const half8_t ta = *(const half8_t*)(Tb + (gi << 12) + wv * 512 + lane * 8);
      #pragma unroll
      for (int nt2 = 0; nt2 < 2; ++nt2) {
        const int nmo = ((gi * 2 + nt2) * 64 + lane) * 8;
        const half8_t nmh = *(const half8_t*)(NmF + nmo);
        const half8_t nml = *(const half8_t*)(NmF + 2048 + nmo);
        const float4_t dh = MF16(ta, nmh, ((float4_t){0.f, 0.f, 0.f, 0.f}));
        const float4_t dl = MF16(ta, nml, ((float4_t){0.f, 0.f, 0.f, 0.f}));
        H4 pk4;
        #pragma unroll
        for (int jj = 0; jj < 4; ++jj) {
          float v = dh[jj] + dl[jj] * LO_INV + ((const float*)&b4)[jj];
          if (RELU) v = fmaxf(v, 0.f);
          pk4.h[jj] = (_Float16)v;
        }
        const int n = nt2 * 16 + l15;
        *(unsigned long long*)(Hs + (gi << 13) + (n * 256 + (j0 ^ ((n & 7) << 3)))) = pk4.u;
      }
    }
  }
  __syncthreads();   // new h visible
}

// ---------------------------------------------------------------------------
// GNN kernel: 2 graphs per block, 512 threads (8 waves).
// LDS 65.5 KB. __launch_bounds__(512,4): force regs <= 128/wave total so
// TWO blocks co-reside per CU (r10: 80 VGPR+accum > 128 -> 1 block, 23% occ,
// latency-bound). r10 kernel needs ~100-115 regs, so the cap should not
// reintroduce r7/r8's spill (tripwire: WRITE_SIZE).
// ---------------------------------------------------------------------------
__global__ __launch_bounds__(512, 4)
void gnn_kernel(const float* __restrict__ x, const float* __restrict__ addf,
                const int* __restrict__ src, const int* __restrict__ dst,
                const float* __restrict__ b_in,
                const float* __restrict__ b_g1, const float* __restrict__ b_g2,
                const float* __restrict__ Wvp, const float* __restrict__ bv,
                const _Float16* __restrict__ pk,
                const float* __restrict__ tvec,
                float* __restrict__ F)
{
  __shared__ __align__(16) _Float16 Hs[2][8192];
  __shared__ __align__(16) _Float16 Tb[2][4096];
  __shared__ __align__(16) _Float16 NmF[4096];
  __shared__ float Sb[2][1184];

  const int tid = threadIdx.x;
  const int lane = tid & 63;
  const int wv = tid >> 6;            // 0..7
  const int g4 = lane >> 4, l15 = lane & 15;
  const int sw = (l15 & 7) << 3;
  const int ga = blockIdx.x * 2;

  // ---- build Nmat = diag(inorm) . A_adj . diag(onorm) for both graphs ----
  for (int i = tid; i < 2048; i += 512) Sb[i >> 10][i & 1023] = 0.f;
  __syncthreads();
  if (tid < 128) {
    const int gi = tid >> 6, e = tid & 63;
    const int es = src[(size_t)(ga + gi) * EE + e];
    const int ed = dst[(size_t)(ga + gi) * EE + e];
    atomicAdd(&Sb[gi][ed * 32 + es], 1.0f);
  }
  __syncthreads();
  if (tid < 64) {                       // inorm = rsqrt(row sums)
    const int gi = tid >> 5, n = tid & 31;
    float s = 0.f;
    for (int m = 0; m < NN; ++m) s += Sb[gi][n * 32 + m];
    Sb[gi][1056 + n] = 1.f / sqrtf(fmaxf(s, 1.f));
  } else if (tid < 128) {               // onorm = rsqrt(col sums)
    const int gi = (tid - 64) >> 5, n = tid & 31;
    float s = 0.f;
    for (int m = 0; m < NN; ++m) s += Sb[gi][m * 32 + n];
    Sb[gi][1088 + n] = 1.f / sqrtf(fmaxf(s, 1.f));
  }
  __syncthreads();
  for (int i = tid; i < 2048; i += 512) {
    const int gi = i >> 10, idx = i & 1023;
    Sb[gi][idx] *= Sb[gi][1056 + (idx >> 5)] * Sb[gi][1088 + (idx & 31)];
  }
  __syncthreads();

  // ---- Nmat B-fragments (hi + lo*2^10) into NmF LDS (wave 0 builds) ----
  if (wv == 0) {
    #pragma unroll
    for (int gi = 0; gi < 2; ++gi) {
      #pragma unroll
      for (int nt2 = 0; nt2 < 2; ++nt2) {
        half8_t h8, l8;
        #pragma unroll
        for (int i = 0; i < 8; ++i) {
          const float v = Sb[gi][(nt2 * 16 + l15) * 32 + g4 * 8 + i];
          const _Float16 hb = (_Float16)v;
          h8[i] = hb;
          l8[i] = (_Float16)((v - (float)hb) * LO_SCALE);
        }
        const int nmo = ((gi * 2 + nt2) * 64 + lane) * 8;
        *(half8_t*)(NmF + nmo) = h8;
        *(half8_t*)(NmF + 2048 + nmo) = l8;
      }
    }
  }

  // ---- stage x (fp16, cols 74..95 zero) ----
  for (int i = tid; i < 2 * NN * 96; i += 512) {
    const int gi = i / 3072, rem = i - gi * 3072;
    const int r = rem / 96, c = rem - r * 96;
    const float vx = (c < INDIM) ? x[(size_t)(ga + gi) * (NN * INDIM) + r * INDIM + c] : 0.f;
    Hs[gi][r * 256 + (c ^ ((r & 7) << 3))] = (_Float16)vx;
  }
  __syncthreads();

  // ---- 11 graph convolutions ----
  conv2x<3, false>(&Hs[0][0], &Tb[0][0], NmF, pk + PK_WIN_HI, b_in, lane, wv);
  #pragma unroll 1
  for (int L = 0; L < GCR; ++L) {
    conv2x<8, true>(&Hs[0][0], &Tb[0][0], NmF,
                    pk + PK_G_BASE + (size_t)L * PK_G_STRIDE, b_g1 + L * HH, lane, wv);
    conv2x<8, true>(&Hs[0][0], &Tb[0][0], NmF,
                    pk + PK_G_BASE + (size_t)(5 + L) * PK_G_STRIDE, b_g2 + L * HH, lane, wv);
  }

  // ---- attention ----
  {
    const _Float16* Qhi = pk + PK_WQK_HI;
    const int sgi = wv >> 2, smt = (wv >> 1) & 1, snt = wv & 1;   // 8 waves -> 8 tiles
    float4_t sacc = (float4_t){0.f, 0.f, 0.f, 0.f};

    #pragma unroll
    for (int p = 0; p < 2; ++p) {
      const int nt = p * 8 + wv;
      // u' = h@Wqk for this wave's 16 cols (single-fp16 Wqk)
      float4_t uh[2][2];
      #pragma unroll
      for (int a = 0; a < 2; ++a)
        #pragma unroll
        for (int b = 0; b < 2; ++b)
          uh[a][b] = (float4_t){0.f, 0.f, 0.f, 0.f};
      #pragma unroll
      for (int ks = 0; ks < 8; ++ks) {
        const int off = ((nt * 8 + ks) * 64 + lane) * 8;
        const half8_t qh = *(const half8_t*)(Qhi + off);
        const int j0 = ks * 32 + g4 * 8;
        #pragma unroll
        for (int gi = 0; gi < 2; ++gi)
          #pragma unroll
          for (int mt = 0; mt < 2; ++mt) {
            const half8_t ha = *(const half8_t*)(&Hs[gi][(mt * 16 + l15) * 256 + (j0 ^ sw)]);
            uh[gi][mt] = MF16(ha, qh, uh[gi][mt]);
          }
      }
      // write u' slice [n][128] swizzled into Tb (+tvec); col fixed per lane
      const float tv = tvec[nt * 16 + l15];
      const int cl = wv * 16 + l15;
      #pragma unroll
      for (int gi = 0; gi < 2; ++gi)
        #pragma unroll
        for (int mt = 0; mt < 2; ++mt)
          #pragma unroll
          for (int jj = 0; jj < 4; ++jj) {
            const int n = mt * 16 + 4 * g4 + jj;
            Tb[gi][n * 128 + (cl ^ ((n & 7) << 3))] =
                (_Float16)(uh[gi][mt][jj] + tv);
          }
      __syncthreads();
      // S partial: wave -> (sgi, smt, snt)
      #pragma unroll
      for (int ksl = 0; ksl < 4; ++ksl) {
        const int kl = ksl * 32 + g4 * 8;
        const half8_t ua = *(const half8_t*)(&Tb[sgi][(smt * 16 + l15) * 128 + (kl ^ sw)]);
        const half8_t hb = *(const half8_t*)(&Hs[sgi][(snt * 16 + l15) * 256 + ((p * 128 + kl) ^ sw)]);
        sacc = MF16(ua, hb, sacc);
      }
      __syncthreads();
    }
    // S write (each wave owns a distinct (sgi, smt, snt) tile)
    #pragma unroll
    for (int jj = 0; jj < 4; ++jj)
      Sb[sgi][(smt * 16 + 4 * g4 + jj) * 33 + snt * 16 + l15] = sacc[jj];
  }

  // ---- v[m] = h[m].Wv + bv  (2 graphs x 32 rows x 8 lanes) ----
  {
    const int gi = tid >> 8, m = (tid >> 3) & 31, q = tid & 7;
    float s = 0.f;
    const int c0 = q * 32;
    for (int cc = 0; cc < 32; ++cc) {
      const int c = c0 + cc;
      s = fmaf((float)Hs[gi][m * 256 + (c ^ ((m & 7) << 3))], Wvp[c], s);
    }
    s += __shfl_xor(s, 1);
    s += __shfl_xor(s, 2);
    s += __shfl_xor(s, 4);
    if (q == 0) Sb[gi][1120 + m] = s + bv[0];
  }
  __syncthreads();

  // ---- row softmax fused with w = attn @ v ----
  if (tid < 64) {
    const int gi = tid >> 5, n = tid & 31;
    float mx = -1e30f;
    #pragma unroll 1
    for (int m = 0; m < NN; ++m) mx = fmaxf(mx, Sb[gi][n * 33 + m]);
    float se = 0.f, sv = 0.f;
    #pragma unroll 1
    for (int m = 0; m < NN; ++m) {
      const float e = expf(Sb[gi][n * 33 + m] - mx);
      se += e;
      sv = fmaf(e, Sb[gi][1120 + m], sv);
    }
    Sb[gi][1152 + n] = sv / se;
  }
  __syncthreads();

  // ---- feats = h^T @ w  (512 threads: one column each) ----
  {
    const int gi = tid >> 8, j = tid & 255;
    float f0 = 0.f;
    #pragma unroll
    for (int m = 0; m < NN; ++m) {
      const float w = Sb[gi][1152 + m];
      f0 = fmaf((float)Hs[gi][m * 256 + (j ^ ((m & 7) << 3))], w, f0);
    }
    F[(size_t)(ga + gi) * FDIM + j] = f0;
    if (tid < 4) {
      const int gg = tid >> 1;
      F[(size_t)(ga + gg) * FDIM + HH + (tid & 1)] = addf[(size_t)(ga + gg) * ADDD + (tid & 1)];
    }
  }
}

// ---------------------------------------------------------------------------
// Kernel 2: batched MLP (unchanged)
// ---------------------------------------------------------------------------
#define MR 8
__global__ __launch_bounds__(256, 2)
void mlp_kernel(const float* __restrict__ F,
                const float* __restrict__ W1, const float* __restrict__ b1,
                const float* __restrict__ W2, const float* __restrict__ b2,
                const float* __restrict__ W3, const float* __restrict__ b3,
                float* __restrict__ out)
{
  __shared__ float sm[MR * M1];
  const int tid = threadIdx.x;
  const int r0 = blockIdx.x * MR;

  for (int idx = tid; idx < MR * FDIM; idx += 256) {
    const int r = idx / FDIM, c = idx - r * FDIM;
    sm[r * 260 + c] = F[(size_t)(r0 + r) * FDIM + c];
  }
  __syncthreads();

  float a1[4][MR];
  #pragma unroll
  for (int qg = 0; qg < 4; ++qg)
    #pragma unroll
    for (int r = 0; r < MR; ++r) a1[qg][r] = 0.f;
  for (int i = 0; i < FDIM; ++i) {
    float w[4];
    #pragma unroll
    for (int qg = 0; qg < 4; ++qg) w[qg] = W1[(size_t)i * M1 + tid + 256 * qg];
    #pragma unroll
    for (int r = 0; r < MR; ++r) {
      const float fv = sm[r * 260 + i];
      #pragma unroll
      for (int qg = 0; qg < 4; ++qg) a1[qg][r] = fmaf(fv, w[qg], a1[qg][r]);
    }
  }
  __syncthreads();
  #pragma unroll
  for (int qg = 0; qg < 4; ++qg) {
    const float bb = b1[tid + 256 * qg];
    #pragma unroll
    for (int r = 0; r < MR; ++r) {
      const float z = a1[qg][r] + bb;
      sm[r * M1 + tid + 256 * qg] = fmaxf(z, 0.01f * z);
    }
  }
  __syncthreads();

  float a2[2][MR];
  #pragma unroll
  for (int qg = 0; qg < 2; ++qg)
    #pragma unroll
    for (int r = 0; r < MR; ++r) a2[qg][r] = 0.f;
  for (int i = 0; i < M1; ++i) {
    float w[2];
    #pragma unroll
    for (int qg = 0; qg < 2; ++qg) w[qg] = W2[(size_t)i * M2 + tid + 256 * qg];
    #pragma unroll
    for (int r = 0; r < MR; ++r) {
      const float zv = sm[r * M1 + i];
      #pragma unroll
      for (int qg = 0; qg < 2; ++qg) a2[qg][r] = fmaf(zv, w[qg], a2[qg][r]);
    }
  }
  __syncthreads();
  #pragma unroll
  for (int qg = 0; qg < 2; ++qg) {
    const float bb = b2[tid + 256 * qg];
    #pragma unroll
    for (int r = 0; r < MR; ++r) {
      const float z = a2[qg][r] + bb;
      sm[r * M2 + tid + 256 * qg] = fmaxf(z, 0.01f * z);
    }
  }
  __syncthreads();

  const int lane = tid & 63, wid = tid >> 6;
  float wreg[8];
  #pragma unroll
  for (int q = 0; q < 8; ++q) wreg[q] = W3[lane + 64 * q];
  #pragma unroll
  for (int rr = 0; rr < 2; ++rr) {
    const int r = wid * 2 + rr;
    float s = 0.f;
    #pragma unroll
    for (int q = 0; q < 8; ++q) s = fmaf(sm[r * M2 + lane + 64 * q], wreg[q], s);
    #pragma unroll
    for (int off = 32; off; off >>= 1) s += __shfl_down(s, off);
    if (lane == 0) out[r0 + r] = s + b3[0];
  }
}

// ---------------------------------------------------------------------------
extern "C" void kernel_launch(void* const* d_in, const int* in_sizes, int n_in,
                              void* d_out, int out_size, void* d_ws, size_t ws_size,
                              hipStream_t stream) {
  (void)in_sizes; (void)n_in; (void)out_size; (void)ws_size;
  const float* x    = (const float*)d_in[0];
  const float* addf = (const float*)d_in[1];
  const int*   src  = (const int*)d_in[2];
  const int*   dst  = (const int*)d_in[3];
  const float* W_in = (const float*)d_in[4];
  const float* b_in = (const float*)d_in[5];
  const float* W_g1 = (const float*)d_in[6];
  const float* b_g1 = (const float*)d_in[7];
  const float* W_g2 = (const float*)d_in[8];
  const float* b_g2 = (const float*)d_in[9];
  const float* Wq   = (const float*)d_in[10];
  const float* bq   = (const float*)d_in[11];
  const float* Wk   = (const float*)d_in[12];
  // d_in[13] = bk : cancels in softmax (row-constant), unused
  const float* Wv   = (const float*)d_in[14];
  const float* bv   = (const float*)d_in[15];
  const float* W1   = (const float*)d_in[16];
  const float* b1   = (const float*)d_in[17];
  const float* W2   = (const float*)d_in[18];
  const float* b2   = (const float*)d_in[19];
  const float* W3   = (const float*)d_in[20];
  const float* b3   = (const float*)d_in[21];
  float* out = (float*)d_out;

  float* F        = (float*)d_ws;
  float* wqkf     = (float*)((char*)d_ws + WS_WQK);
  float* tvec     = (float*)((char*)d_ws + WS_TVEC);
  _Float16* pk    = (_Float16*)((char*)d_ws + WS_PK);

  prep1_kernel<<<dim3(257), dim3(256), 0, stream>>>(Wq, Wk, bq, wqkf, tvec);
  prep2_kernel<<<dim3(364), dim3(256), 0, stream>>>(W_in, W_g1, W_g2, wqkf, pk);
  gnn_kernel<<<dim3(BB / 2), dim3(512), 0, stream>>>(
      x, addf, src, dst, b_in, b_g1, b_g2, Wv, bv, pk, tvec, F);
  mlp_kernel<<<dim3(BB / MR), dim3(256), 0, stream>>>(
      F, W1, b1, W2, b2, W3, b3, out);
}

// Round 12
// 285.712 us; speedup vs baseline: 4.1716x; 1.4425x over previous
//
#include <hip/hip_runtime.h>
#include <math.h>

#define BB     4096
#define NN     32
#define EE     64
#define INDIM  74
#define HH     256
#define GCR    5
#define M1     1024
#define M2     512
#define FDIM   258
#define ADDD   2
#define FSTR   288     // Fh row stride (fp16), cols 258..287 zero

typedef __attribute__((ext_vector_type(8))) _Float16 half8_t;
typedef __attribute__((ext_vector_type(4))) float float4_t;

#define MF16(a, b, c) __builtin_amdgcn_mfma_f32_16x16x32_f16((a), (b), (c), 0, 0, 0)
#define LO_SCALE 1024.0f
#define LO_INV   (1.0f / 1024.0f)

// ---- ws layout (bytes) ----
#define WS_FH     0               // Fh fp16 [4096][288] = 2,359,296
#define WS_WQK    4227072         // Wqk fp32 [256][256]
#define WS_TVEC   4489216         // tvec fp32 [256]
#define WS_PK     4490240         // packed fp16 fragments
// offsets in _Float16 units from PK base:
#define PK_WIN_HI 0
#define PK_WIN_LO 24576
#define PK_G_BASE 49152
#define PK_G_STRIDE 131072
#define PK_WQK_HI 1359872
#define PK_WQK_LO (1359872 + 65536)
#define PK_W1P    1490944         // 64nt*9ks*512 = 294,912
#define PK_W2P    1785856         // 32nt*32ks*512 = 524,288 -> end 2,310,144

union H4 { unsigned long long u; _Float16 h[4]; };

// ---------------------------------------------------------------------------
// Prep 1: Wqk = Wq @ Wk^T (fp32), tvec = Wk @ bq
// ---------------------------------------------------------------------------
__global__ void prep1_kernel(const float* __restrict__ Wq, const float* __restrict__ Wk,
                             const float* __restrict__ bq,
                             float* __restrict__ wqkf, float* __restrict__ tvec) {
  const int i = blockIdx.x, j = threadIdx.x;
  if (i < 256) {
    __shared__ float qrow[256];
    qrow[j] = Wq[i * 256 + j];
    __syncthreads();
    float s = 0.f;
    for (int c = 0; c < 256; ++c) s = fmaf(qrow[c], Wk[j * 256 + c], s);
    wqkf[i * 256 + j] = s;
  } else {
    float s = 0.f;
    for (int c = 0; c < 256; ++c) s = fmaf(Wk[j * 256 + c], bq[c], s);
    tvec[j] = s;
  }
}

// ---------------------------------------------------------------------------
// Prep 2: pack GNN weights into MFMA B-frag order, fp16 hi (+lo, unused).
// ---------------------------------------------------------------------------
template<int KS, int KREAL>
__device__ __forceinline__ void pack_one(const float* __restrict__ S,
                                         _Float16* __restrict__ hi,
                                         _Float16* __restrict__ lo, int local) {
  const int l = local & 63;
  const int nk = local >> 6;
  const int ks = nk % KS;
  const int nt = nk / KS;
  const int j = nt * 16 + (l & 15);
  const int kbase = ks * 32 + (l >> 4) * 8;
  half8_t h8, l8;
  #pragma unroll
  for (int i = 0; i < 8; ++i) {
    const int k = kbase + i;
    const float v = (k < KREAL) ? S[k * 256 + j] : 0.f;
    const _Float16 hb = (_Float16)v;
    h8[i] = hb;
    l8[i] = (_Float16)((v - (float)hb) * LO_SCALE);
  }
  *(half8_t*)(hi + (size_t)local * 8) = h8;
  *(half8_t*)(lo + (size_t)local * 8) = l8;
}

__global__ void prep2_kernel(const float* __restrict__ W_in,
                             const float* __restrict__ W_g1, const float* __restrict__ W_g2,
                             const float* __restrict__ wqkf, _Float16* __restrict__ pk) {
  const int cid = blockIdx.x * 256 + threadIdx.x;
  if (cid < 3072) {
    pack_one<3, 74>(W_in, pk + PK_WIN_HI, pk + PK_WIN_LO, cid);
  } else {
    const int m = (cid - 3072) >> 13;               // 0..10
    const int local = (cid - 3072) & 8191;
    _Float16* hi; const float* S;
    if (m < 10) {
      hi = pk + PK_G_BASE + (size_t)m * PK_G_STRIDE;
      S = (m < 5) ? (W_g1 + (size_t)m * 65536) : (W_g2 + (size_t)(m - 5) * 65536);
    } else {
      hi = pk + PK_WQK_HI;
      S = wqkf;
    }
    pack_one<8, 256>(S, hi, hi + 65536, local);
  }
}

// ---------------------------------------------------------------------------
// Prep 3: pack MLP weights (W1 [258][1024], W2 [1024][512]) fp16 A'-frag order.
// ---------------------------------------------------------------------------
template<int KS, int KREAL, int NCOL>
__device__ __forceinline__ void pack_flat(const float* __restrict__ S,
                                          _Float16* __restrict__ dst, int local) {
  const int l = local & 63;
  const int nk = local >> 6;
  const int ks = nk % KS;
  const int nt = nk / KS;
  const int j = nt * 16 + (l & 15);
  const int kbase = ks * 32 + (l >> 4) * 8;
  half8_t h8;
  #pragma unroll
  for (int i = 0; i < 8; ++i) {
    const int k = kbase + i;
    h8[i] = (_Float16)((k < KREAL) ? S[(size_t)k * NCOL + j] : 0.f);
  }
  *(half8_t*)(dst + (size_t)local * 8) = h8;
}

__global__ void prep3_kernel(const float* __restrict__ W1, const float* __restrict__ W2,
                             _Float16* __restrict__ pk) {
  const int cid = blockIdx.x * 256 + threadIdx.x;
  if (cid < 36864) {                               // 64nt * 9ks * 64
    pack_flat<9, 258, 1024>(W1, pk + PK_W1P, cid);
  } else {                                         // 32nt * 32ks * 64
    pack_flat<32, 1024, 512>(W2, pk + PK_W2P, cid - 36864);
  }
}

// ---------------------------------------------------------------------------
// conv for 2 graphs, 8 waves, ZERO cross-barrier register state:
//   MFMA1 both phases -> T tiles (both) into Tb (wave-private)
//   barrier (all H reads done)
//   MFMA2 both phases (T from LDS, Nmat single-fp16 from NmF) -> H direct
//   barrier
// Hs layout: n*256 + (j ^ ((n&7)<<3)). Tb: gi*8192 + nt*512 + frag.
// ---------------------------------------------------------------------------
template<int KS, bool RELU>
__device__ __forceinline__ void conv2x(
    _Float16* Hs, _Float16* Tb, const _Float16* NmF,
    const _Float16* __restrict__ Whi,
    const float* __restrict__ bias,
    int lane, int wv)
{
  const int g4 = lane >> 4, l15 = lane & 15;
  const int sw = (l15 & 7) << 3;

  #pragma unroll
  for (int p = 0; p < 2; ++p) {
    const int nt = p * 8 + wv;
    float4_t th[2][2];
    #pragma unroll
    for (int a = 0; a < 2; ++a)
      #pragma unroll
      for (int b = 0; b < 2; ++b)
        th[a][b] = (float4_t){0.f, 0.f, 0.f, 0.f};
    #pragma unroll
    for (int ks = 0; ks < KS; ++ks) {
      const int off = ((nt * KS + ks) * 64 + lane) * 8;
      const half8_t wh = *(const half8_t*)(Whi + off);
      const int j0 = ks * 32 + g4 * 8;
      #pragma unroll
      for (int gi = 0; gi < 2; ++gi)
        #pragma unroll
        for (int mt = 0; mt < 2; ++mt) {
          const half8_t ha = *(const half8_t*)(Hs + (gi << 13) + ((mt * 16 + l15) * 256 + (j0 ^ sw)));
          th[gi][mt] = MF16(ha, wh, th[gi][mt]);
        }
    }
    #pragma unroll
    for (int gi = 0; gi < 2; ++gi)
      #pragma unroll
      for (int mt = 0; mt < 2; ++mt) {
        const int r0 = mt * 16 + 4 * g4;
        H4 pk4;
        #pragma unroll
        for (int jj = 0; jj < 4; ++jj)
          pk4.h[jj] = (_Float16)th[gi][mt][jj];
        const int idx = nt * 512 + ((r0 >> 3) * 16 + l15) * 8 + (r0 & 7);
        *(unsigned long long*)(Tb + (gi << 13) + idx) = pk4.u;
      }
  }

  __syncthreads();   // ALL waves' H reads (both phases) complete

  #pragma unroll
  for (int p = 0; p < 2; ++p) {
    const int nt = p * 8 + wv;
    const float4 b4 = *(const float4*)&bias[nt * 16 + 4 * g4];
    const int j0 = nt * 16 + 4 * g4;
    #pragma unroll
    for (int gi = 0; gi < 2; ++gi) {
      const half8_t ta = *(const half8_t*)(Tb + (gi << 13) + nt * 512 + lane * 8);
      #pragma unroll
      for (int nt2 = 0; nt2 < 2; ++nt2) {
        const half8_t nmh = *(const half8_t*)(NmF + ((gi * 2 + nt2) * 64 + lane) * 8);
        const float4_t dh = MF16(ta, nmh, ((float4_t){0.f, 0.f, 0.f, 0.f}));
        H4 pk4;
        #pragma unroll
        for (int jj = 0; jj < 4; ++jj) {
          float v = dh[jj] + ((const float*)&b4)[jj];
          if (RELU) v = fmaxf(v, 0.f);
          pk4.h[jj] = (_Float16)v;
        }
        const int n = nt2 * 16 + l15;
        *(unsigned long long*)(Hs + (gi << 13) + (n * 256 + (j0 ^ ((n & 7) << 3)))) = pk4.u;
      }
    }
  }
  __syncthreads();   // new h visible
}

// ---------------------------------------------------------------------------
// GNN kernel: 2 graphs/block, 512 threads. LDS: Hs 32K + Tb 32K + NmF 4K +
// Sb 9.25K = 73.3 KB -> 2 blocks/CU. (512,4) cap; no cross-barrier regs.
// ---------------------------------------------------------------------------
__global__ __launch_bounds__(512, 4)
void gnn_kernel(const float* __restrict__ x, const float* __restrict__ addf,
                const int* __restrict__ src, const int* __restrict__ dst,
                const float* __restrict__ b_in,
                const float* __restrict__ b_g1, const float* __restrict__ b_g2,
                const float* __restrict__ Wvp, const float* __restrict__ bv,
                const _Float16* __restrict__ pk,
                const float* __restrict__ tvec,
                _Float16* __restrict__ Fh)
{
  __shared__ __align__(16) _Float16 Hs[2][8192];
  __shared__ __align__(16) _Float16 Tb[2][8192];
  __shared__ __align__(16) _Float16 NmF[2048];
  __shared__ float Sb[2][1184];

  const int tid = threadIdx.x;
  const int lane = tid & 63;
  const int wv = tid >> 6;            // 0..7
  const int g4 = lane >> 4, l15 = lane & 15;
  const int sw = (l15 & 7) << 3;
  const int ga = blockIdx.x * 2;

  // ---- build Nmat = diag(inorm) . A_adj . diag(onorm) for both graphs ----
  for (int i = tid; i < 2048; i += 512) Sb[i >> 10][i & 1023] = 0.f;
  __syncthreads();
  if (tid < 128) {
    const int gi = tid >> 6, e = tid & 63;
    const int es = src[(size_t)(ga + gi) * EE + e];
    const int ed = dst[(size_t)(ga + gi) * EE + e];
    atomicAdd(&Sb[gi][ed * 32 + es], 1.0f);
  }
  __syncthreads();
  if (tid < 64) {                       // inorm = rsqrt(row sums)
    const int gi = tid >> 5, n = tid & 31;
    float s = 0.f;
    for (int m = 0; m < NN; ++m) s += Sb[gi][n * 32 + m];
    Sb[gi][1056 + n] = 1.f / sqrtf(fmaxf(s, 1.f));
  } else if (tid < 128) {               // onorm = rsqrt(col sums)
    const int gi = (tid - 64) >> 5, n = tid & 31;
    float s = 0.f;
    for (int m = 0; m < NN; ++m) s += Sb[gi][m * 32 + n];
    Sb[gi][1088 + n] = 1.f / sqrtf(fmaxf(s, 1.f));
  }
  __syncthreads();
  for (int i = tid; i < 2048; i += 512) {
    const int gi = i >> 10, idx = i & 1023;
    Sb[gi][idx] *= Sb[gi][1056 + (idx >> 5)] * Sb[gi][1088 + (idx & 31)];
  }
  __syncthreads();

  // ---- Nmat B-fragments (single fp16) into NmF (wave 0 builds) ----
  if (wv == 0) {
    #pragma unroll
    for (int gi = 0; gi < 2; ++gi) {
      #pragma unroll
      for (int nt2 = 0; nt2 < 2; ++nt2) {
        half8_t h8;
        #pragma unroll
        for (int i = 0; i < 8; ++i)
          h8[i] = (_Float16)Sb[gi][(nt2 * 16 + l15) * 32 + g4 * 8 + i];
        *(half8_t*)(NmF + ((gi * 2 + nt2) * 64 + lane) * 8) = h8;
      }
    }
  }

  // ---- stage x (fp16, cols 74..95 zero) ----
  for (int i = tid; i < 2 * NN * 96; i += 512) {
    const int gi = i / 3072, rem = i - gi * 3072;
    const int r = rem / 96, c = rem - r * 96;
    const float vx = (c < INDIM) ? x[(size_t)(ga + gi) * (NN * INDIM) + r * INDIM + c] : 0.f;
    Hs[gi][r * 256 + (c ^ ((r & 7) << 3))] = (_Float16)vx;
  }
  __syncthreads();

  // ---- 11 graph convolutions ----
  conv2x<3, false>(&Hs[0][0], &Tb[0][0], NmF, pk + PK_WIN_HI, b_in, lane, wv);
  #pragma unroll 1
  for (int L = 0; L < GCR; ++L) {
    conv2x<8, true>(&Hs[0][0], &Tb[0][0], NmF,
                    pk + PK_G_BASE + (size_t)L * PK_G_STRIDE, b_g1 + L * HH, lane, wv);
    conv2x<8, true>(&Hs[0][0], &Tb[0][0], NmF,
                    pk + PK_G_BASE + (size_t)(5 + L) * PK_G_STRIDE, b_g2 + L * HH, lane, wv);
  }

  // ---- attention ----
  {
    const _Float16* Qhi = pk + PK_WQK_HI;
    const int sgi = wv >> 2, smt = (wv >> 1) & 1, snt = wv & 1;
    float4_t sacc = (float4_t){0.f, 0.f, 0.f, 0.f};

    #pragma unroll
    for (int p = 0; p < 2; ++p) {
      const int nt = p * 8 + wv;
      float4_t uh[2][2];
      #pragma unroll
      for (int a = 0; a < 2; ++a)
        #pragma unroll
        for (int b = 0; b < 2; ++b)
          uh[a][b] = (float4_t){0.f, 0.f, 0.f, 0.f};
      #pragma unroll
      for (int ks = 0; ks < 8; ++ks) {
        const int off = ((nt * 8 + ks) * 64 + lane) * 8;
        const half8_t qh = *(const half8_t*)(Qhi + off);
        const int j0 = ks * 32 + g4 * 8;
        #pragma unroll
        for (int gi = 0; gi < 2; ++gi)
          #pragma unroll
          for (int mt = 0; mt < 2; ++mt) {
            const half8_t ha = *(const half8_t*)(&Hs[gi][(mt * 16 + l15) * 256 + (j0 ^ sw)]);
            uh[gi][mt] = MF16(ha, qh, uh[gi][mt]);
          }
      }
      const float tv = tvec[nt * 16 + l15];
      const int cl = wv * 16 + l15;
      #pragma unroll
      for (int gi = 0; gi < 2; ++gi)
        #pragma unroll
        for (int mt = 0; mt < 2; ++mt)
          #pragma unroll
          for (int jj = 0; jj < 4; ++jj) {
            const int n = mt * 16 + 4 * g4 + jj;
            Tb[gi][n * 128 + (cl ^ ((n & 7) << 3))] =
                (_Float16)(uh[gi][mt][jj] + tv);
          }
      __syncthreads();
      #pragma unroll
      for (int ksl = 0; ksl < 4; ++ksl) {
        const int kl = ksl * 32 + g4 * 8;
        const half8_t ua = *(const half8_t*)(&Tb[sgi][(smt * 16 + l15) * 128 + (kl ^ sw)]);
        const half8_t hb = *(const half8_t*)(&Hs[sgi][(snt * 16 + l15) * 256 + ((p * 128 + kl) ^ sw)]);
        sacc = MF16(ua, hb, sacc);
      }
      __syncthreads();
    }
    #pragma unroll
    for (int jj = 0; jj < 4; ++jj)
      Sb[sgi][(smt * 16 + 4 * g4 + jj) * 33 + snt * 16 + l15] = sacc[jj];
  }

  // ---- v[m] = h[m].Wv + bv ----
  {
    const int gi = tid >> 8, m = (tid >> 3) & 31, q = tid & 7;
    float s = 0.f;
    const int c0 = q * 32;
    for (int cc = 0; cc < 32; ++cc) {
      const int c = c0 + cc;
      s = fmaf((float)Hs[gi][m * 256 + (c ^ ((m & 7) << 3))], Wvp[c], s);
    }
    s += __shfl_xor(s, 1);
    s += __shfl_xor(s, 2);
    s += __shfl_xor(s, 4);
    if (q == 0) Sb[gi][1120 + m] = s + bv[0];
  }
  __syncthreads();

  // ---- row softmax fused with w = attn @ v ----
  if (tid < 64) {
    const int gi = tid >> 5, n = tid & 31;
    float mx = -1e30f;
    #pragma unroll 1
    for (int m = 0; m < NN; ++m) mx = fmaxf(mx, Sb[gi][n * 33 + m]);
    float se = 0.f, sv = 0.f;
    #pragma unroll 1
    for (int m = 0; m < NN; ++m) {
      const float e = expf(Sb[gi][n * 33 + m] - mx);
      se += e;
      sv = fmaf(e, Sb[gi][1120 + m], sv);
    }
    Sb[gi][1152 + n] = sv / se;
  }
  __syncthreads();

  // ---- feats = h^T @ w  -> Fh fp16 [4096][288] ----
  {
    const int gi = tid >> 8, j = tid & 255;
    float f0 = 0.f;
    #pragma unroll
    for (int m = 0; m < NN; ++m) {
      const float w = Sb[gi][1152 + m];
      f0 = fmaf((float)Hs[gi][m * 256 + (j ^ ((m & 7) << 3))], w, f0);
    }
    Fh[(size_t)(ga + gi) * FSTR + j] = (_Float16)f0;
    if (tid < 64) {
      const int g2 = tid >> 5, c = 256 + (tid & 31);
      Fh[(size_t)(ga + g2) * FSTR + c] =
          (c < FDIM) ? (_Float16)addf[(size_t)(ga + g2) * ADDD + (c - 256)] : (_Float16)0.f;
    }
  }
}

// ---------------------------------------------------------------------------
// Kernel 2: MFMA MLP. 16 rows/block, 512 threads, 256 blocks.
// Swapped form: z^T = W^T @ in^T -> B-frag = row-major activation read,
// C-writes = b64 row stores. LDS: Ft 10K + Z1 32K + Z2 16K = 58 KB.
// ---------------------------------------------------------------------------
__global__ __launch_bounds__(512, 4)
void mlp_kernel(const _Float16* __restrict__ Fh,
                const _Float16* __restrict__ W1p, const float* __restrict__ b1,
                const _Float16* __restrict__ W2p, const float* __restrict__ b2,
                const float* __restrict__ W3, const float* __restrict__ b3,
                float* __restrict__ out)
{
  __shared__ __align__(16) _Float16 Ft[16 * 320];
  __shared__ __align__(16) _Float16 Z1[16 * 1024];
  __shared__ __align__(16) _Float16 Z2[16 * 512];

  const int tid = threadIdx.x, lane = tid & 63, wv = tid >> 6;
  const int g4 = lane >> 4, l15 = lane & 15;
  const int sw = (l15 & 7) << 3;
  const int r0 = blockIdx.x * 16;

  for (int i = tid; i < 16 * FSTR; i += 512) {
    const int r = i / FSTR, c = i - r * FSTR;
    Ft[r * 320 + (c ^ ((r & 7) << 3))] = Fh[(size_t)(r0 + r) * FSTR + c];
  }
  __syncthreads();

  // layer 1: z1^T = W1^T @ Ft^T ; wave owns jt = wv*8 + t (t 0..7)
  {
    float4_t a1[8];
    #pragma unroll
    for (int t = 0; t < 8; ++t) a1[t] = (float4_t){0.f, 0.f, 0.f, 0.f};
    #pragma unroll
    for (int ks = 0; ks < 9; ++ks) {
      const half8_t fb = *(const half8_t*)(Ft + l15 * 320 + ((ks * 32 + g4 * 8) ^ sw));
      #pragma unroll
      for (int t = 0; t < 8; ++t) {
        const int jt = wv * 8 + t;
        const half8_t wf = *(const half8_t*)(W1p + ((size_t)(jt * 9 + ks) * 64 + lane) * 8);
        a1[t] = MF16(wf, fb, a1[t]);
      }
    }
    #pragma unroll
    for (int t = 0; t < 8; ++t) {
      const int j0 = (wv * 8 + t) * 16 + 4 * g4;
      const float4 bb = *(const float4*)&b1[j0];
      H4 pk4;
      #pragma unroll
      for (int jj = 0; jj < 4; ++jj) {
        const float z = a1[t][jj] + ((const float*)&bb)[jj];
        pk4.h[jj] = (_Float16)fmaxf(z, 0.01f * z);
      }
      *(unsigned long long*)(Z1 + l15 * 1024 + (j0 ^ sw)) = pk4.u;
    }
  }
  __syncthreads();

  // layer 2: z2^T = W2^T @ z1^T ; wave owns jt = wv*4 + t (t 0..3)
  {
    float4_t a2[4];
    #pragma unroll
    for (int t = 0; t < 4; ++t) a2[t] = (float4_t){0.f, 0.f, 0.f, 0.f};
    #pragma unroll 4
    for (int ks = 0; ks < 32; ++ks) {
      const half8_t zb = *(const half8_t*)(Z1 + l15 * 1024 + ((ks * 32 + g4 * 8) ^ sw));
      #pragma unroll
      for (int t = 0; t < 4; ++t) {
        const int jt = wv * 4 + t;
        const half8_t wf = *(const half8_t*)(W2p + ((size_t)(jt * 32 + ks) * 64 + lane) * 8);
        a2[t] = MF16(wf, zb, a2[t]);
      }
    }
    #pragma unroll
    for (int t = 0; t < 4; ++t) {
      const int j0 = (wv * 4 + t) * 16 + 4 * g4;
      const float4 bb = *(const float4*)&b2[j0];
      H4 pk4;
      #pragma unroll
      for (int jj = 0; jj < 4; ++jj) {
        const float z = a2[t][jj] + ((const float*)&bb)[jj];
        pk4.h[jj] = (_Float16)fmaxf(z, 0.01f * z);
      }
      *(unsigned long long*)(Z2 + l15 * 512 + (j0 ^ sw)) = pk4.u;
    }
  }
  __syncthreads();

  // layer 3: out = z2 @ W3 + b3  (32 lanes per row)
  {
    const int m = tid >> 5, q = tid & 31;
    const int swm = (m & 7) << 3;
    float s = 0.f;
    #pragma unroll
    for (int h = 0; h < 2; ++h) {
      const int c0 = q * 16 + h * 8;
      const half8_t z8 = *(const half8_t*)(Z2 + m * 512 + (c0 ^ swm));
      #pragma unroll
      for (int i2 = 0; i2 < 8; ++i2)
        s = fmaf((float)z8[i2], W3[c0 + i2], s);
    }
    s += __shfl_xor(s, 1);
    s += __shfl_xor(s, 2);
    s += __shfl_xor(s, 4);
    s += __shfl_xor(s, 8);
    s += __shfl_xor(s, 16);
    if (q == 0) out[r0 + m] = s + b3[0];
  }
}

// ---------------------------------------------------------------------------
extern "C" void kernel_launch(void* const* d_in, const int* in_sizes, int n_in,
                              void* d_out, int out_size, void* d_ws, size_t ws_size,
                              hipStream_t stream) {
  (void)in_sizes; (void)n_in; (void)out_size; (void)ws_size;
  const float* x    = (const float*)d_in[0];
  const float* addf = (const float*)d_in[1];
  const int*   src  = (const int*)d_in[2];
  const int*   dst  = (const int*)d_in[3];
  const float* W_in = (const float*)d_in[4];
  const float* b_in = (const float*)d_in[5];
  const float* W_g1 = (const float*)d_in[6];
  const float* b_g1 = (const float*)d_in[7];
  const float* W_g2 = (const float*)d_in[8];
  const float* b_g2 = (const float*)d_in[9];
  const float* Wq   = (const float*)d_in[10];
  const float* bq   = (const float*)d_in[11];
  const float* Wk   = (const float*)d_in[12];
  // d_in[13] = bk : cancels in softmax (row-constant), unused
  const float* Wv   = (const float*)d_in[14];
  const float* bv   = (const float*)d_in[15];
  const float* W1   = (const float*)d_in[16];
  const float* b1   = (const float*)d_in[17];
  const float* W2   = (const float*)d_in[18];
  const float* b2   = (const float*)d_in[19];
  const float* W3   = (const float*)d_in[20];
  const float* b3   = (const float*)d_in[21];
  float* out = (float*)d_out;

  _Float16* Fh    = (_Float16*)((char*)d_ws + WS_FH);
  float* wqkf     = (float*)((char*)d_ws + WS_WQK);
  float* tvec     = (float*)((char*)d_ws + WS_TVEC);
  _Float16* pk    = (_Float16*)((char*)d_ws + WS_PK);

  prep1_kernel<<<dim3(257), dim3(256), 0, stream>>>(Wq, Wk, bq, wqkf, tvec);
  prep2_kernel<<<dim3(364), dim3(256), 0, stream>>>(W_in, W_g1, W_g2, wqkf, pk);
  prep3_kernel<<<dim3(400), dim3(256), 0, stream>>>(W1, W2, pk);
  gnn_kernel<<<dim3(BB / 2), dim3(512), 0, stream>>>(
      x, addf, src, dst, b_in, b_g1, b_g2, Wv, bv, pk, tvec, Fh);
  mlp_kernel<<<dim3(BB / 16), dim3(512), 0, stream>>>(
      Fh, pk + PK_W1P, b1, pk + PK_W2P, b2, W3, b3, out);
}

// Round 13
// 279.870 us; speedup vs baseline: 4.2587x; 1.0209x over previous
//
#include <hip/hip_runtime.h>
#include <math.h>

#define BB     4096
#define NN     32
#define EE     64
#define INDIM  74
#define HH     256
#define GCR    5
#define M1     1024
#define M2     512
#define FDIM   258
#define ADDD   2
#define FSTR   288     // Fh row stride (fp16), cols 258..287 zero

typedef __attribute__((ext_vector_type(8))) _Float16 half8_t;
typedef __attribute__((ext_vector_type(4))) float float4_t;

#define MF16(a, b, c) __builtin_amdgcn_mfma_f32_16x16x32_f16((a), (b), (c), 0, 0, 0)
#define LO_SCALE 1024.0f
#define LO_INV   (1.0f / 1024.0f)

// ---- ws layout (bytes) ----
#define WS_FH     0               // Fh fp16 [4096][288]
#define WS_WQK    4227072         // Wqk fp32 [256][256]
#define WS_TVEC   4489216         // tvec fp32 [256]
#define WS_PK     4490240         // packed fp16 fragments
// offsets in _Float16 units from PK base:
#define PK_WIN_HI 0
#define PK_WIN_LO 24576
#define PK_G_BASE 49152
#define PK_G_STRIDE 131072
#define PK_WQK_HI 1359872
#define PK_WQK_LO (1359872 + 65536)
#define PK_W1P    1490944
#define PK_W2P    1785856

union H4 { unsigned long long u; _Float16 h[4]; };

// ---------------------------------------------------------------------------
// Prep 1: Wqk = Wq @ Wk^T (fp32), tvec = Wk @ bq
// ---------------------------------------------------------------------------
__global__ void prep1_kernel(const float* __restrict__ Wq, const float* __restrict__ Wk,
                             const float* __restrict__ bq,
                             float* __restrict__ wqkf, float* __restrict__ tvec) {
  const int i = blockIdx.x, j = threadIdx.x;
  if (i < 256) {
    __shared__ float qrow[256];
    qrow[j] = Wq[i * 256 + j];
    __syncthreads();
    float s = 0.f;
    for (int c = 0; c < 256; ++c) s = fmaf(qrow[c], Wk[j * 256 + c], s);
    wqkf[i * 256 + j] = s;
  } else {
    float s = 0.f;
    for (int c = 0; c < 256; ++c) s = fmaf(Wk[j * 256 + c], bq[c], s);
    tvec[j] = s;
  }
}

// ---------------------------------------------------------------------------
// Prep 2: pack GNN weights into MFMA B-frag order, fp16 hi (+lo, unused).
// ---------------------------------------------------------------------------
template<int KS, int KREAL>
__device__ __forceinline__ void pack_one(const float* __restrict__ S,
                                         _Float16* __restrict__ hi,
                                         _Float16* __restrict__ lo, int local) {
  const int l = local & 63;
  const int nk = local >> 6;
  const int ks = nk % KS;
  const int nt = nk / KS;
  const int j = nt * 16 + (l & 15);
  const int kbase = ks * 32 + (l >> 4) * 8;
  half8_t h8, l8;
  #pragma unroll
  for (int i = 0; i < 8; ++i) {
    const int k = kbase + i;
    const float v = (k < KREAL) ? S[k * 256 + j] : 0.f;
    const _Float16 hb = (_Float16)v;
    h8[i] = hb;
    l8[i] = (_Float16)((v - (float)hb) * LO_SCALE);
  }
  *(half8_t*)(hi + (size_t)local * 8) = h8;
  *(half8_t*)(lo + (size_t)local * 8) = l8;
}

__global__ void prep2_kernel(const float* __restrict__ W_in,
                             const float* __restrict__ W_g1, const float* __restrict__ W_g2,
                             const float* __restrict__ wqkf, _Float16* __restrict__ pk) {
  const int cid = blockIdx.x * 256 + threadIdx.x;
  if (cid < 3072) {
    pack_one<3, 74>(W_in, pk + PK_WIN_HI, pk + PK_WIN_LO, cid);
  } else {
    const int m = (cid - 3072) >> 13;               // 0..10
    const int local = (cid - 3072) & 8191;
    _Float16* hi; const float* S;
    if (m < 10) {
      hi = pk + PK_G_BASE + (size_t)m * PK_G_STRIDE;
      S = (m < 5) ? (W_g1 + (size_t)m * 65536) : (W_g2 + (size_t)(m - 5) * 65536);
    } else {
      hi = pk + PK_WQK_HI;
      S = wqkf;
    }
    pack_one<8, 256>(S, hi, hi + 65536, local);
  }
}

// ---------------------------------------------------------------------------
// Prep 3: pack MLP weights (W1 [258][1024], W2 [1024][512]) fp16 A'-frag order.
// ---------------------------------------------------------------------------
template<int KS, int KREAL, int NCOL>
__device__ __forceinline__ void pack_flat(const float* __restrict__ S,
                                          _Float16* __restrict__ dst, int local) {
  const int l = local & 63;
  const int nk = local >> 6;
  const int ks = nk % KS;
  const int nt = nk / KS;
  const int j = nt * 16 + (l & 15);
  const int kbase = ks * 32 + (l >> 4) * 8;
  half8_t h8;
  #pragma unroll
  for (int i = 0; i < 8; ++i) {
    const int k = kbase + i;
    h8[i] = (_Float16)((k < KREAL) ? S[(size_t)k * NCOL + j] : 0.f);
  }
  *(half8_t*)(dst + (size_t)local * 8) = h8;
}

__global__ void prep3_kernel(const float* __restrict__ W1, const float* __restrict__ W2,
                             _Float16* __restrict__ pk) {
  const int cid = blockIdx.x * 256 + threadIdx.x;
  if (cid < 36864) {
    pack_flat<9, 258, 1024>(W1, pk + PK_W1P, cid);
  } else {
    pack_flat<32, 1024, 512>(W2, pk + PK_W2P, cid - 36864);
  }
}

// ---------------------------------------------------------------------------
// conv for 2 graphs, 8 waves, zero cross-barrier register state.
// LDS swizzle widened to 4 row bits: col ^ ((row&15)<<3). With 3 bits all 64
// lanes of a b128 A-read landed in one 16-bank half (2x throughput loss,
// 4.4e7 conflicts r12); 4 bits spread the 16 l15-lanes over all 16 even
// start-banks -> full 32-bank coverage, 8 acc/bank = HW floor.
// Hs layout: n*256 + (j ^ ((n&15)<<3)). Tb: gi*8192 + nt*512 + frag (linear).
// ---------------------------------------------------------------------------
template<int KS, bool RELU>
__device__ __forceinline__ void conv2x(
    _Float16* Hs, _Float16* Tb, const _Float16* NmF,
    const _Float16* __restrict__ Whi,
    const float* __restrict__ bias,
    int lane, int wv)
{
  const int g4 = lane >> 4, l15 = lane & 15;
  const int sw = l15 << 3;            // row&15 == l15 for rows mt*16+l15

  #pragma unroll
  for (int p = 0; p < 2; ++p) {
    const int nt = p * 8 + wv;
    float4_t th[2][2];
    #pragma unroll
    for (int a = 0; a < 2; ++a)
      #pragma unroll
      for (int b = 0; b < 2; ++b)
        th[a][b] = (float4_t){0.f, 0.f, 0.f, 0.f};
    #pragma unroll
    for (int ks = 0; ks < KS; ++ks) {
      const int off = ((nt * KS + ks) * 64 + lane) * 8;
      const half8_t wh = *(const half8_t*)(Whi + off);
      const int j0 = ks * 32 + g4 * 8;
      #pragma unroll
      for (int gi = 0; gi < 2; ++gi)
        #pragma unroll
        for (int mt = 0; mt < 2; ++mt) {
          const half8_t ha = *(const half8_t*)(Hs + (gi << 13) + ((mt * 16 + l15) * 256 + (j0 ^ sw)));
          th[gi][mt] = MF16(ha, wh, th[gi][mt]);
        }
    }
    #pragma unroll
    for (int gi = 0; gi < 2; ++gi)
      #pragma unroll
      for (int mt = 0; mt < 2; ++mt) {
        const int r0 = mt * 16 + 4 * g4;
        H4 pk4;
        #pragma unroll
        for (int jj = 0; jj < 4; ++jj)
          pk4.h[jj] = (_Float16)th[gi][mt][jj];
        const int idx = nt * 512 + ((r0 >> 3) * 16 + l15) * 8 + (r0 & 7);
        *(unsigned long long*)(Tb + (gi << 13) + idx) = pk4.u;
      }
  }

  __syncthreads();   // ALL waves' H reads (both phases) complete

  #pragma unroll
  for (int p = 0; p < 2; ++p) {
    const int nt = p * 8 + wv;
    const float4 b4 = *(const float4*)&bias[nt * 16 + 4 * g4];
    const int j0 = nt * 16 + 4 * g4;
    #pragma unroll
    for (int gi = 0; gi < 2; ++gi) {
      const half8_t ta = *(const half8_t*)(Tb + (gi << 13) + nt * 512 + lane * 8);
      #pragma unroll
      for (int nt2 = 0; nt2 < 2; ++nt2) {
        const half8_t nmh = *(const half8_t*)(NmF + ((gi * 2 + nt2) * 64 + lane) * 8);
        const float4_t dh = MF16(ta, nmh, ((float4_t){0.f, 0.f, 0.f, 0.f}));
        H4 pk4;
        #pragma unroll
        for (int jj = 0; jj < 4; ++jj) {
          float v = dh[jj] + ((const float*)&b4)[jj];
          if (RELU) v = fmaxf(v, 0.f);
          pk4.h[jj] = (_Float16)v;
        }
        const int n = nt2 * 16 + l15;
        *(unsigned long long*)(Hs + (gi << 13) + (n * 256 + (j0 ^ ((n & 15) << 3)))) = pk4.u;
      }
    }
  }
  __syncthreads();   // new h visible
}

// ---------------------------------------------------------------------------
// GNN kernel: 2 graphs/block, 512 threads. LDS 77.5 KB -> 2 blocks/CU.
// ---------------------------------------------------------------------------
__global__ __launch_bounds__(512, 4)
void gnn_kernel(const float* __restrict__ x, const float* __restrict__ addf,
                const int* __restrict__ src, const int* __restrict__ dst,
                const float* __restrict__ b_in,
                const float* __restrict__ b_g1, const float* __restrict__ b_g2,
                const float* __restrict__ Wvp, const float* __restrict__ bv,
                const _Float16* __restrict__ pk,
                const float* __restrict__ tvec,
                _Float16* __restrict__ Fh)
{
  __shared__ __align__(16) _Float16 Hs[2][8192];
  __shared__ __align__(16) _Float16 Tb[2][8192];
  __shared__ __align__(16) _Float16 NmF[2048];
  __shared__ float Sb[2][1184];

  const int tid = threadIdx.x;
  const int lane = tid & 63;
  const int wv = tid >> 6;            // 0..7
  const int g4 = lane >> 4, l15 = lane & 15;
  const int sw = l15 << 3;
  const int ga = blockIdx.x * 2;

  // ---- build Nmat = diag(inorm) . A_adj . diag(onorm) for both graphs ----
  for (int i = tid; i < 2048; i += 512) Sb[i >> 10][i & 1023] = 0.f;
  __syncthreads();
  if (tid < 128) {
    const int gi = tid >> 6, e = tid & 63;
    const int es = src[(size_t)(ga + gi) * EE + e];
    const int ed = dst[(size_t)(ga + gi) * EE + e];
    atomicAdd(&Sb[gi][ed * 32 + es], 1.0f);
  }
  __syncthreads();
  if (tid < 64) {                       // inorm = rsqrt(row sums)
    const int gi = tid >> 5, n = tid & 31;
    float s = 0.f;
    for (int m = 0; m < NN; ++m) s += Sb[gi][n * 32 + m];
    Sb[gi][1056 + n] = 1.f / sqrtf(fmaxf(s, 1.f));
  } else if (tid < 128) {               // onorm = rsqrt(col sums)
    const int gi = (tid - 64) >> 5, n = tid & 31;
    float s = 0.f;
    for (int m = 0; m < NN; ++m) s += Sb[gi][m * 32 + n];
    Sb[gi][1088 + n] = 1.f / sqrtf(fmaxf(s, 1.f));
  }
  __syncthreads();
  for (int i = tid; i < 2048; i += 512) {
    const int gi = i >> 10, idx = i & 1023;
    Sb[gi][idx] *= Sb[gi][1056 + (idx >> 5)] * Sb[gi][1088 + (idx & 31)];
  }
  __syncthreads();

  // ---- Nmat B-fragments (single fp16) into NmF (wave 0 builds) ----
  if (wv == 0) {
    #pragma unroll
    for (int gi = 0; gi < 2; ++gi) {
      #pragma unroll
      for (int nt2 = 0; nt2 < 2; ++nt2) {
        half8_t h8;
        #pragma unroll
        for (int i = 0; i < 8; ++i)
          h8[i] = (_Float16)Sb[gi][(nt2 * 16 + l15) * 32 + g4 * 8 + i];
        *(half8_t*)(NmF + ((gi * 2 + nt2) * 64 + lane) * 8) = h8;
      }
    }
  }

  // ---- stage x (fp16, cols 74..95 zero) ----
  for (int i = tid; i < 2 * NN * 96; i += 512) {
    const int gi = i / 3072, rem = i - gi * 3072;
    const int r = rem / 96, c = rem - r * 96;
    const float vx = (c < INDIM) ? x[(size_t)(ga + gi) * (NN * INDIM) + r * INDIM + c] : 0.f;
    Hs[gi][r * 256 + (c ^ ((r & 15) << 3))] = (_Float16)vx;
  }
  __syncthreads();

  // ---- 11 graph convolutions ----
  conv2x<3, false>(&Hs[0][0], &Tb[0][0], NmF, pk + PK_WIN_HI, b_in, lane, wv);
  #pragma unroll 1
  for (int L = 0; L < GCR; ++L) {
    conv2x<8, true>(&Hs[0][0], &Tb[0][0], NmF,
                    pk + PK_G_BASE + (size_t)L * PK_G_STRIDE, b_g1 + L * HH, lane, wv);
    conv2x<8, true>(&Hs[0][0], &Tb[0][0], NmF,
                    pk + PK_G_BASE + (size_t)(5 + L) * PK_G_STRIDE, b_g2 + L * HH, lane, wv);
  }

  // ---- attention ----
  {
    const _Float16* Qhi = pk + PK_WQK_HI;
    const int sgi = wv >> 2, smt = (wv >> 1) & 1, snt = wv & 1;
    float4_t sacc = (float4_t){0.f, 0.f, 0.f, 0.f};

    #pragma unroll
    for (int p = 0; p < 2; ++p) {
      const int nt = p * 8 + wv;
      float4_t uh[2][2];
      #pragma unroll
      for (int a = 0; a < 2; ++a)
        #pragma unroll
        for (int b = 0; b < 2; ++b)
          uh[a][b] = (float4_t){0.f, 0.f, 0.f, 0.f};
      #pragma unroll
      for (int ks = 0; ks < 8; ++ks) {
        const int off = ((nt * 8 + ks) * 64 + lane) * 8;
        const half8_t qh = *(const half8_t*)(Qhi + off);
        const int j0 = ks * 32 + g4 * 8;
        #pragma unroll
        for (int gi = 0; gi < 2; ++gi)
          #pragma unroll
          for (int mt = 0; mt < 2; ++mt) {
            const half8_t ha = *(const half8_t*)(&Hs[gi][(mt * 16 + l15) * 256 + (j0 ^ sw)]);
            uh[gi][mt] = MF16(ha, qh, uh[gi][mt]);
          }
      }
      const float tv = tvec[nt * 16 + l15];
      const int cl = wv * 16 + l15;
      #pragma unroll
      for (int gi = 0; gi < 2; ++gi)
        #pragma unroll
        for (int mt = 0; mt < 2; ++mt)
          #pragma unroll
          for (int jj = 0; jj < 4; ++jj) {
            const int n = mt * 16 + 4 * g4 + jj;
            Tb[gi][n * 128 + (cl ^ ((n & 15) << 3))] =
                (_Float16)(uh[gi][mt][jj] + tv);
          }
      __syncthreads();
      #pragma unroll
      for (int ksl = 0; ksl < 4; ++ksl) {
        const int kl = ksl * 32 + g4 * 8;
        const half8_t ua = *(const half8_t*)(&Tb[sgi][(smt * 16 + l15) * 128 + (kl ^ sw)]);
        const half8_t hb = *(const half8_t*)(&Hs[sgi][(snt * 16 + l15) * 256 + ((p * 128 + kl) ^ sw)]);
        sacc = MF16(ua, hb, sacc);
      }
      __syncthreads();
    }
    #pragma unroll
    for (int jj = 0; jj < 4; ++jj)
      Sb[sgi][(smt * 16 + 4 * g4 + jj) * 33 + snt * 16 + l15] = sacc[jj];
  }

  // ---- v[m] = h[m].Wv + bv ----
  {
    const int gi = tid >> 8, m = (tid >> 3) & 31, q = tid & 7;
    float s = 0.f;
    const int c0 = q * 32;
    for (int cc = 0; cc < 32; ++cc) {
      const int c = c0 + cc;
      s = fmaf((float)Hs[gi][m * 256 + (c ^ ((m & 15) << 3))], Wvp[c], s);
    }
    s += __shfl_xor(s, 1);
    s += __shfl_xor(s, 2);
    s += __shfl_xor(s, 4);
    if (q == 0) Sb[gi][1120 + m] = s + bv[0];
  }
  __syncthreads();

  // ---- row softmax fused with w = attn @ v ----
  if (tid < 64) {
    const int gi = tid >> 5, n = tid & 31;
    float mx = -1e30f;
    #pragma unroll 1
    for (int m = 0; m < NN; ++m) mx = fmaxf(mx, Sb[gi][n * 33 + m]);
    float se = 0.f, sv = 0.f;
    #pragma unroll 1
    for (int m = 0; m < NN; ++m) {
      const float e = expf(Sb[gi][n * 33 + m] - mx);
      se += e;
      sv = fmaf(e, Sb[gi][1120 + m], sv);
    }
    Sb[gi][1152 + n] = sv / se;
  }
  __syncthreads();

  // ---- feats = h^T @ w  -> Fh fp16 [4096][288] ----
  {
    const int gi = tid >> 8, j = tid & 255;
    float f0 = 0.f;
    #pragma unroll
    for (int m = 0; m < NN; ++m) {
      const float w = Sb[gi][1152 + m];
      f0 = fmaf((float)Hs[gi][m * 256 + (j ^ ((m & 15) << 3))], w, f0);
    }
    Fh[(size_t)(ga + gi) * FSTR + j] = (_Float16)f0;
    if (tid < 64) {
      const int g2 = tid >> 5, c = 256 + (tid & 31);
      Fh[(size_t)(ga + g2) * FSTR + c] =
          (c < FDIM) ? (_Float16)addf[(size_t)(ga + g2) * ADDD + (c - 256)] : (_Float16)0.f;
    }
  }
}

// ---------------------------------------------------------------------------
// Kernel 2: MFMA MLP (unchanged from r12 — ~6 µs).
// ---------------------------------------------------------------------------
__global__ __launch_bounds__(512, 4)
void mlp_kernel(const _Float16* __restrict__ Fh,
                const _Float16* __restrict__ W1p, const float* __restrict__ b1,
                const _Float16* __restrict__ W2p, const float* __restrict__ b2,
                const float* __restrict__ W3, const float* __restrict__ b3,
                float* __restrict__ out)
{
  __shared__ __align__(16) _Float16 Ft[16 * 320];
  __shared__ __align__(16) _Float16 Z1[16 * 1024];
  __shared__ __align__(16) _Float16 Z2[16 * 512];

  const int tid = threadIdx.x, lane = tid & 63, wv = tid >> 6;
  const int g4 = lane >> 4, l15 = lane & 15;
  const int sw = (l15 & 7) << 3;
  const int r0 = blockIdx.x * 16;

  for (int i = tid; i < 16 * FSTR; i += 512) {
    const int r = i / FSTR, c = i - r * FSTR;
    Ft[r * 320 + (c ^ ((r & 7) << 3))] = Fh[(size_t)(r0 + r) * FSTR + c];
  }
  __syncthreads();

  // layer 1: z1^T = W1^T @ Ft^T
  {
    float4_t a1[8];
    #pragma unroll
    for (int t = 0; t < 8; ++t) a1[t] = (float4_t){0.f, 0.f, 0.f, 0.f};
    #pragma unroll
    for (int ks = 0; ks < 9; ++ks) {
      const half8_t fb = *(const half8_t*)(Ft + l15 * 320 + ((ks * 32 + g4 * 8) ^ sw));
      #pragma unroll
      for (int t = 0; t < 8; ++t) {
        const int jt = wv * 8 + t;
        const half8_t wf = *(const half8_t*)(W1p + ((size_t)(jt * 9 + ks) * 64 + lane) * 8);
        a1[t] = MF16(wf, fb, a1[t]);
      }
    }
    #pragma unroll
    for (int t = 0; t < 8; ++t) {
      const int j0 = (wv * 8 + t) * 16 + 4 * g4;
      const float4 bb = *(const float4*)&b1[j0];
      H4 pk4;
      #pragma unroll
      for (int jj = 0; jj < 4; ++jj) {
        const float z = a1[t][jj] + ((const float*)&bb)[jj];
        pk4.h[jj] = (_Float16)fmaxf(z, 0.01f * z);
      }
      *(unsigned long long*)(Z1 + l15 * 1024 + (j0 ^ sw)) = pk4.u;
    }
  }
  __syncthreads();

  // layer 2: z2^T = W2^T @ z1^T
  {
    float4_t a2[4];
    #pragma unroll
    for (int t = 0; t < 4; ++t) a2[t] = (float4_t){0.f, 0.f, 0.f, 0.f};
    #pragma unroll 4
    for (int ks = 0; ks < 32; ++ks) {
      const half8_t zb = *(const half8_t*)(Z1 + l15 * 1024 + ((ks * 32 + g4 * 8) ^ sw));
      #pragma unroll
      for (int t = 0; t < 4; ++t) {
        const int jt = wv * 4 + t;
        const half8_t wf = *(const half8_t*)(W2p + ((size_t)(jt * 32 + ks) * 64 + lane) * 8);
        a2[t] = MF16(wf, zb, a2[t]);
      }
    }
    #pragma unroll
    for (int t = 0; t < 4; ++t) {
      const int j0 = (wv * 4 + t) * 16 + 4 * g4;
      const float4 bb = *(const float4*)&b2[j0];
      H4 pk4;
      #pragma unroll
      for (int jj = 0; jj < 4; ++jj) {
        const float z = a2[t][jj] + ((const float*)&bb)[jj];
        pk4.h[jj] = (_Float16)fmaxf(z, 0.01f * z);
      }
      *(unsigned long long*)(Z2 + l15 * 512 + (j0 ^ sw)) = pk4.u;
    }
  }
  __syncthreads();

  // layer 3: out = z2 @ W3 + b3
  {
    const int m = tid >> 5, q = tid & 31;
    const int swm = (m & 7) << 3;
    float s = 0.f;
    #pragma unroll
    for (int h = 0; h < 2; ++h) {
      const int c0 = q * 16 + h * 8;
      const half8_t z8 = *(const half8_t*)(Z2 + m * 512 + (c0 ^ swm));
      #pragma unroll
      for (int i2 = 0; i2 < 8; ++i2)
        s = fmaf((float)z8[i2], W3[c0 + i2], s);
    }
    s += __shfl_xor(s, 1);
    s += __shfl_xor(s, 2);
    s += __shfl_xor(s, 4);
    s += __shfl_xor(s, 8);
    s += __shfl_xor(s, 16);
    if (q == 0) out[r0 + m] = s + b3[0];
  }
}

// ---------------------------------------------------------------------------
extern "C" void kernel_launch(void* const* d_in, const int* in_sizes, int n_in,
                              void* d_out, int out_size, void* d_ws, size_t ws_size,
                              hipStream_t stream) {
  (void)in_sizes; (void)n_in; (void)out_size; (void)ws_size;
  const float* x    = (const float*)d_in[0];
  const float* addf = (const float*)d_in[1];
  const int*   src  = (const int*)d_in[2];
  const int*   dst  = (const int*)d_in[3];
  const float* W_in = (const float*)d_in[4];
  const float* b_in = (const float*)d_in[5];
  const float* W_g1 = (const float*)d_in[6];
  const float* b_g1 = (const float*)d_in[7];
  const float* W_g2 = (const float*)d_in[8];
  const float* b_g2 = (const float*)d_in[9];
  const float* Wq   = (const float*)d_in[10];
  const float* bq   = (const float*)d_in[11];
  const float* Wk   = (const float*)d_in[12];
  // d_in[13] = bk : cancels in softmax (row-constant), unused
  const float* Wv   = (const float*)d_in[14];
  const float* bv   = (const float*)d_in[15];
  const float* W1   = (const float*)d_in[16];
  const float* b1   = (const float*)d_in[17];
  const float* W2   = (const float*)d_in[18];
  const float* b2   = (const float*)d_in[19];
  const float* W3   = (const float*)d_in[20];
  const float* b3   = (const float*)d_in[21];
  float* out = (float*)d_out;

  _Float16* Fh    = (_Float16*)((char*)d_ws + WS_FH);
  float* wqkf     = (float*)((char*)d_ws + WS_WQK);
  float* tvec     = (float*)((char*)d_ws + WS_TVEC);
  _Float16* pk    = (_Float16*)((char*)d_ws + WS_PK);

  prep1_kernel<<<dim3(257), dim3(256), 0, stream>>>(Wq, Wk, bq, wqkf, tvec);
  prep2_kernel<<<dim3(364), dim3(256), 0, stream>>>(W_in, W_g1, W_g2, wqkf, pk);
  prep3_kernel<<<dim3(400), dim3(256), 0, stream>>>(W1, W2, pk);
  gnn_kernel<<<dim3(BB / 2), dim3(512), 0, stream>>>(
      x, addf, src, dst, b_in, b_g1, b_g2, Wv, bv, pk, tvec, Fh);
  mlp_kernel<<<dim3(BB / 16), dim3(512), 0, stream>>>(
      Fh, pk + PK_W1P, b1, pk + PK_W2P, b2, W3, b3, out);
}